// Round 5
// baseline (2566.069 us; speedup 1.0000x reference)
//
#include <hip/hip_runtime.h>
#include <stdint.h>

typedef unsigned long long u64;
typedef unsigned int u32;
typedef unsigned short ushort_t;

#define FI __device__ __forceinline__

static constexpr float BN_EPS_F = 1e-5f;
static constexpr int E0 = 200000;
static constexpr int T1 = 1500, T2 = 750, T3 = 375;
static constexpr int CAND_CAP = 4096;
static constexpr int NB_KEEP = (E0 + 1023) / 1024;

typedef __attribute__((ext_vector_type(8))) short short8;
typedef __attribute__((ext_vector_type(4))) float f32x4;

FI int iclampi(int v, int lo, int hi) { return v < lo ? lo : (v > hi ? hi : v); }

FI ushort_t f2b(float f) {
  u32 u = __float_as_uint(f);
  u32 r = (u + 0x7FFFu + ((u >> 16) & 1u)) >> 16;
  return (ushort_t)r;
}

FI int nearest_keep(const int* __restrict__ keep, int K, int idx) {
  int lo = 0, hi = K;
  while (lo < hi) { int mid = (lo + hi) >> 1; if (keep[mid] < idx) lo = mid + 1; else hi = mid; }
  int l = lo - 1; l = l < 0 ? 0 : (l > K - 1 ? K - 1 : l);
  int r = lo;     r = r < 0 ? 0 : (r > K - 1 ? K - 1 : r);
  int dl = idx - keep[l]; dl = dl < 0 ? -dl : dl;
  int dr = idx - keep[r]; dr = dr < 0 ? -dr : dr;
  return (dl <= dr) ? l : r;
}

FI int bsearch_eq(const int* __restrict__ keep, int K, int v) {
  int lo = 0, hi = K;
  while (lo < hi) { int mid = (lo + hi) >> 1; if (keep[mid] < v) lo = mid + 1; else hi = mid; }
  if (lo < K && keep[lo] == v) return lo;
  return -1;
}

// ---------------------------------------------------------------------------
// Generic fp32 mesh-conv for mid layers (split-K, 4-wave blocks).
// ---------------------------------------------------------------------------
template<int C, int Cout, int BR, int BC, int KT, int TR, int TC, int KSPLIT,
         bool FUSE_STATS>
__global__ __launch_bounds__((BR / TR) * (BC / TC))
void conv_kernel(const float* __restrict__ X,
                 const int* __restrict__ nb, int E,
                 const float* __restrict__ W,
                 float* __restrict__ H, float* __restrict__ stats)
{
  constexpr int NTH = (BR / TR) * (BC / TC);
  constexpr int VK = 5 * KT;
  constexpr int KC = C / KSPLIT;
  static_assert(KC % KT == 0, "KC % KT");

  const int row0 = blockIdx.x * BR;
  const int col0 = blockIdx.y * BC;
  const int c_begin = (KSPLIT > 1) ? (int)blockIdx.z * KC : 0;

  __shared__ float As[VK][BR];
  __shared__ float Bs[VK][BC];
  __shared__ int rowsS[5][BR];
  __shared__ float red[FUSE_STATS ? 2 * (BR / TR) * BC : 1];

  const int tid = threadIdx.x;

  for (int q = tid; q < BR; q += NTH) {
    int r = row0 + q;
    int rr[5];
    if (r < E) {
      rr[0] = r;
      #pragma unroll
      for (int j = 0; j < 4; j++) {
        int v = nb[(size_t)r * 4 + j];
        rr[1 + j] = iclampi(v, 0, E - 1);
      }
    } else {
      #pragma unroll
      for (int j = 0; j < 5; j++) rr[j] = -1;
    }
    #pragma unroll
    for (int j = 0; j < 5; j++) rowsS[j][q] = rr[j];
  }

  float acc[TR][TC];
  #pragma unroll
  for (int i = 0; i < TR; i++)
    #pragma unroll
    for (int j = 0; j < TC; j++) acc[i][j] = 0.f;

  const int tr = tid / (BC / TC);
  const int tc = tid % (BC / TC);
  const int rA = tr * TR;
  const int cB = tc * TC;

  for (int c0 = c_begin; c0 < c_begin + KC; c0 += KT) {
    __syncthreads();
    for (int q = tid; q < VK * (BC / 4); q += NTH) {
      int kk = q / (BC / 4);
      int c4 = q % (BC / 4);
      int p = kk / KT, t = kk % KT;
      float4 wv = *(const float4*)&W[(size_t)(p * C + c0 + t) * Cout + col0 + c4 * 4];
      *(float4*)&Bs[kk][c4 * 4] = wv;
    }
    for (int q = tid; q < BR * KT; q += NTH) {
      int t = q % KT, rq = q / KT;
      int c = c0 + t;
      float s0 = 0.f, a1 = 0.f, a2 = 0.f, a3 = 0.f, a4 = 0.f;
      if (rowsS[0][rq] >= 0) {
        float v0, v1, v2, v3;
        s0 = X[(size_t)rowsS[0][rq] * C + c];
        v0 = X[(size_t)rowsS[1][rq] * C + c];
        v1 = X[(size_t)rowsS[2][rq] * C + c];
        v2 = X[(size_t)rowsS[3][rq] * C + c];
        v3 = X[(size_t)rowsS[4][rq] * C + c];
        a1 = fminf(v0, v1); a2 = fmaxf(v0, v1);
        a3 = fminf(v2, v3); a4 = fmaxf(v2, v3);
      }
      As[0 * KT + t][rq] = s0;
      As[1 * KT + t][rq] = a1;
      As[2 * KT + t][rq] = a2;
      As[3 * KT + t][rq] = a3;
      As[4 * KT + t][rq] = a4;
    }
    __syncthreads();

    for (int kk = 0; kk < VK; kk++) {
      float a[TR], b[TC];
      #pragma unroll
      for (int i = 0; i < TR; i++) a[i] = As[kk][rA + i];
      #pragma unroll
      for (int j = 0; j < TC; j++) b[j] = Bs[kk][cB + j];
      #pragma unroll
      for (int i = 0; i < TR; i++)
        #pragma unroll
        for (int j = 0; j < TC; j++)
          acc[i][j] = fmaf(a[i], b[j], acc[i][j]);
    }
  }

  #pragma unroll
  for (int i = 0; i < TR; i++) {
    int r = row0 + rA + i;
    if (r < E) {
      if constexpr (KSPLIT > 1) {
        #pragma unroll
        for (int j = 0; j < TC; j++)
          atomicAdd(&H[(size_t)r * Cout + col0 + cB + j], acc[i][j]);
      } else {
        #pragma unroll
        for (int j = 0; j < TC; j += 4) {
          float4 v = make_float4(acc[i][j], acc[i][j + 1], acc[i][j + 2], acc[i][j + 3]);
          *(float4*)&H[(size_t)r * Cout + col0 + cB + j] = v;
        }
      }
    }
  }

  if constexpr (FUSE_STATS) {
    float s[TC], q2[TC];
    #pragma unroll
    for (int j = 0; j < TC; j++) { s[j] = 0.f; q2[j] = 0.f; }
    #pragma unroll
    for (int i = 0; i < TR; i++) {
      int r = row0 + rA + i;
      if (r < E) {
        #pragma unroll
        for (int j = 0; j < TC; j++) { float v = acc[i][j]; s[j] += v; q2[j] += v * v; }
      }
    }
    __syncthreads();
    float* redS = &red[0];
    float* redQ = &red[(BR / TR) * BC];
    #pragma unroll
    for (int j = 0; j < TC; j++) {
      redS[tr * BC + cB + j] = s[j];
      redQ[tr * BC + cB + j] = q2[j];
    }
    __syncthreads();
    for (int col = tid; col < BC; col += NTH) {
      float ts = 0.f, tq = 0.f;
      for (int g = 0; g < BR / TR; g++) { ts += redS[g * BC + col]; tq += redQ[g * BC + col]; }
      atomicAdd(&stats[col0 + col], ts);
      atomicAdd(&stats[Cout + col0 + col], tq);
    }
  }
}

// ---------------------------------------------------------------------------
// Dedicated e1 conv (C=5, Cout=64): vectorized row gathers (float4+float per
// neighbor), whole W in LDS, fused stats.
// ---------------------------------------------------------------------------
__global__ __launch_bounds__(256)
void e1_conv_kernel(const float* __restrict__ X, const int* __restrict__ nb,
                    const float* __restrict__ W,
                    float* __restrict__ H, float* __restrict__ stats)
{
  __shared__ float As[25][128];
  __shared__ float Bs[25][64];
  __shared__ float red[2 * 32 * 64];

  const int tid = threadIdx.x;
  const int row0 = (int)blockIdx.x * 128;

  if (tid < 128) {
    int r = row0 + tid; if (r > E0 - 1) r = E0 - 1;
    int rs[5];
    rs[0] = r;
    #pragma unroll
    for (int j = 0; j < 4; j++) rs[1 + j] = iclampi((int)nb[(size_t)r * 4 + j], 0, E0 - 1);
    float v[5][5];
    #pragma unroll
    for (int j = 0; j < 5; j++) {
      const float* src = &X[(size_t)rs[j] * 5];
      float4 a = *(const float4*)src;
      v[j][0] = a.x; v[j][1] = a.y; v[j][2] = a.z; v[j][3] = a.w;
      v[j][4] = src[4];
    }
    #pragma unroll
    for (int c = 0; c < 5; c++) {
      As[0 * 5 + c][tid] = v[0][c];
      As[1 * 5 + c][tid] = fminf(v[1][c], v[2][c]);
      As[2 * 5 + c][tid] = fmaxf(v[1][c], v[2][c]);
      As[3 * 5 + c][tid] = fminf(v[3][c], v[4][c]);
      As[4 * 5 + c][tid] = fmaxf(v[3][c], v[4][c]);
    }
  } else {
    for (int q = tid - 128; q < 25 * 16; q += 128) {
      int k = q / 16, c4 = q % 16;
      float4 wv = *(const float4*)&W[(size_t)k * 64 + c4 * 4];
      *(float4*)&Bs[k][c4 * 4] = wv;
    }
  }
  __syncthreads();

  const int tr = tid >> 3;       // 0..31
  const int tc = tid & 7;        // 0..7
  const int rA = tr * 4;
  const int cB = tc * 8;

  float acc[4][8];
  #pragma unroll
  for (int i = 0; i < 4; i++)
    #pragma unroll
    for (int j = 0; j < 8; j++) acc[i][j] = 0.f;

  for (int k = 0; k < 25; k++) {
    float a[4], b[8];
    #pragma unroll
    for (int i = 0; i < 4; i++) a[i] = As[k][rA + i];
    #pragma unroll
    for (int j = 0; j < 8; j++) b[j] = Bs[k][cB + j];
    #pragma unroll
    for (int i = 0; i < 4; i++)
      #pragma unroll
      for (int j = 0; j < 8; j++)
        acc[i][j] = fmaf(a[i], b[j], acc[i][j]);
  }

  float s[8], q2[8];
  #pragma unroll
  for (int j = 0; j < 8; j++) { s[j] = 0.f; q2[j] = 0.f; }
  #pragma unroll
  for (int i = 0; i < 4; i++) {
    int r = row0 + rA + i;
    if (r < E0) {
      #pragma unroll
      for (int j = 0; j < 8; j += 4) {
        float4 v = make_float4(acc[i][j], acc[i][j + 1], acc[i][j + 2], acc[i][j + 3]);
        *(float4*)&H[(size_t)r * 64 + cB + j] = v;
      }
      #pragma unroll
      for (int j = 0; j < 8; j++) { float v = acc[i][j]; s[j] += v; q2[j] += v * v; }
    }
  }
  __syncthreads();
  float* redS = &red[0];
  float* redQ = &red[32 * 64];
  #pragma unroll
  for (int j = 0; j < 8; j++) {
    redS[tr * 64 + cB + j] = s[j];
    redQ[tr * 64 + cB + j] = q2[j];
  }
  __syncthreads();
  for (int col = tid; col < 64; col += 256) {
    float ts = 0.f, tq = 0.f;
    for (int g = 0; g < 32; g++) { ts += redS[g * 64 + col]; tq += redQ[g * 64 + col]; }
    atomicAdd(&stats[col], ts);
    atomicAdd(&stats[64 + col], tq);
  }
}

// ---------------------------------------------------------------------------
// d1 conv via bf16 MFMA, row-split waves: wave w owns rows [32w,32w+32) x all
// 64 cols. Per (cc,mi): 5 gathers feed 20 MFMAs over 4 independent acc chains.
// ---------------------------------------------------------------------------
__global__ __launch_bounds__(256, 2)
void d1_mfma_kernel(const ushort_t* __restrict__ d2b, const ushort_t* __restrict__ e1b,
                    const int* __restrict__ nn1, const int* __restrict__ nb,
                    const ushort_t* __restrict__ Wt,
                    float* __restrict__ H, float* __restrict__ stats)
{
  __shared__ int rowsD[5][128];
  __shared__ int rowsS[5][128];

  const int tid = threadIdx.x;
  const int lane = tid & 63;
  const int wv = tid >> 6;
  const int l15 = lane & 15;
  const int quad = lane >> 4;
  const int row0 = (int)blockIdx.x * 128;

  if (tid < 128) {
    int r = row0 + tid; if (r > E0 - 1) r = E0 - 1;
    int rs[5];
    rs[0] = r;
    #pragma unroll
    for (int j = 0; j < 4; j++) rs[1 + j] = iclampi((int)nb[(size_t)r * 4 + j], 0, E0 - 1);
    #pragma unroll
    for (int j = 0; j < 5; j++) { rowsS[j][tid] = rs[j]; rowsD[j][tid] = nn1[rs[j]]; }
  }
  __syncthreads();

  f32x4 acc[2][4];
  #pragma unroll
  for (int mi = 0; mi < 2; mi++)
    #pragma unroll
    for (int ni = 0; ni < 4; ni++) acc[mi][ni] = (f32x4){0.f, 0.f, 0.f, 0.f};

  for (int cc = 0; cc < 6; cc++) {
    const bool fromD = cc < 4;
    const ushort_t* __restrict__ src = fromD ? d2b : e1b;
    const int stride = fromD ? 128 : 64;
    const int cbase = (fromD ? cc * 32 : (cc - 4) * 32) + quad * 8;

    short8 a[2][5];
    #pragma unroll
    for (int mi = 0; mi < 2; mi++) {
      int rr = wv * 32 + mi * 16 + l15;
      int r0, r1, r2, r3, r4;
      if (fromD) {
        r0 = rowsD[0][rr]; r1 = rowsD[1][rr]; r2 = rowsD[2][rr];
        r3 = rowsD[3][rr]; r4 = rowsD[4][rr];
      } else {
        r0 = rowsS[0][rr]; r1 = rowsS[1][rr]; r2 = rowsS[2][rr];
        r3 = rowsS[3][rr]; r4 = rowsS[4][rr];
      }
      uint4 v0 = *(const uint4*)&src[(size_t)r0 * stride + cbase];
      uint4 v1 = *(const uint4*)&src[(size_t)r1 * stride + cbase];
      uint4 v2 = *(const uint4*)&src[(size_t)r2 * stride + cbase];
      uint4 v3 = *(const uint4*)&src[(size_t)r3 * stride + cbase];
      uint4 v4 = *(const uint4*)&src[(size_t)r4 * stride + cbase];

      uint4 lo12, hi12, lo34, hi34;
      {
        const ushort_t* pa = (const ushort_t*)&v1;
        const ushort_t* pb = (const ushort_t*)&v2;
        ushort_t* lo = (ushort_t*)&lo12;
        ushort_t* hi = (ushort_t*)&hi12;
        #pragma unroll
        for (int i = 0; i < 8; i++) {
          ushort_t xx = pa[i], yy = pb[i];   // bf16 >= 0 -> u16 order == numeric
          lo[i] = xx < yy ? xx : yy;
          hi[i] = xx < yy ? yy : xx;
        }
      }
      {
        const ushort_t* pa = (const ushort_t*)&v3;
        const ushort_t* pb = (const ushort_t*)&v4;
        ushort_t* lo = (ushort_t*)&lo34;
        ushort_t* hi = (ushort_t*)&hi34;
        #pragma unroll
        for (int i = 0; i < 8; i++) {
          ushort_t xx = pa[i], yy = pb[i];
          lo[i] = xx < yy ? xx : yy;
          hi[i] = xx < yy ? yy : xx;
        }
      }
      a[mi][0] = *(short8*)&v0;
      a[mi][1] = *(short8*)&lo12;
      a[mi][2] = *(short8*)&hi12;
      a[mi][3] = *(short8*)&lo34;
      a[mi][4] = *(short8*)&hi34;
    }

    #pragma unroll
    for (int p = 0; p < 5; p++) {
      short8 bf[4];
      #pragma unroll
      for (int ni = 0; ni < 4; ni++)
        bf[ni] = *(const short8*)&Wt[((size_t)(p * 64 + ni * 16 + l15)) * 192 + cc * 32 + quad * 8];
      #pragma unroll
      for (int mi = 0; mi < 2; mi++)
        #pragma unroll
        for (int ni = 0; ni < 4; ni++)
          acc[mi][ni] = __builtin_amdgcn_mfma_f32_16x16x32_bf16(a[mi][p], bf[ni], acc[mi][ni], 0, 0, 0);
    }
  }

  // epilogue: write H (fp32) + fused column stats
  float s[4] = {0.f, 0.f, 0.f, 0.f}, q[4] = {0.f, 0.f, 0.f, 0.f};
  #pragma unroll
  for (int mi = 0; mi < 2; mi++) {
    #pragma unroll
    for (int reg = 0; reg < 4; reg++) {
      int r = row0 + wv * 32 + mi * 16 + quad * 4 + reg;
      if (r < E0) {
        #pragma unroll
        for (int ni = 0; ni < 4; ni++) {
          float v = acc[mi][ni][reg];
          H[(size_t)r * 64 + ni * 16 + l15] = v;
          s[ni] += v; q[ni] += v * v;
        }
      }
    }
  }
  #pragma unroll
  for (int ni = 0; ni < 4; ni++) {
    float ts = s[ni], tq = q[ni];
    ts += __shfl_xor(ts, 16); tq += __shfl_xor(tq, 16);
    ts += __shfl_xor(ts, 32); tq += __shfl_xor(tq, 32);
    if (quad == 0) {
      int col = ni * 16 + l15;
      atomicAdd(&stats[col], ts);
      atomicAdd(&stats[64 + col], tq);
    }
  }
}

// W_d1 (960 x 64 fp32) -> Wt bf16 [(p*64+n)][192]
__global__ void prep_wd1_kernel(const float* __restrict__ W, ushort_t* __restrict__ Wt)
{
  int idx = (int)blockIdx.x * 256 + threadIdx.x;
  if (idx < 5 * 64 * 192) {
    int n = idx & 63;
    int k = idx >> 6;
    int p = k / 192, c = k % 192;
    Wt[((size_t)(p * 64 + n)) * 192 + c] = f2b(W[(size_t)k * 64 + n]);
  }
}

// column sum/sumsq for split-K layers
__global__ void stats_kernel(const float* __restrict__ H, int E, int Cout,
                             float* __restrict__ stats)
{
  const int RB = 64;
  int r0 = (int)blockIdx.x * RB;
  int rend = r0 + RB; if (rend > E) rend = E;
  for (int col = threadIdx.x; col < Cout; col += blockDim.x) {
    float s = 0.f, q = 0.f;
    for (int r = r0; r < rend; r++) { float v = H[(size_t)r * Cout + col]; s += v; q += v * v; }
    atomicAdd(&stats[col], s);
    atomicAdd(&stats[Cout + col], q);
  }
}

// BN(training stats) + ReLU; optional pooling key per row; optional bf16 copy
template<int Cout, bool KEYS, bool B16>
__global__ void bn_kernel(const float* __restrict__ H, const float* __restrict__ stats,
                          const float* __restrict__ g, const float* __restrict__ b,
                          int E, float* __restrict__ Out, ushort_t* __restrict__ Outb,
                          u64* __restrict__ keys)
{
  constexpr int CPL = Cout / 64;
  const int lane = threadIdx.x & 63;
  const int wid = threadIdx.x >> 6;
  const int wpb = blockDim.x >> 6;
  const float invE = 1.0f / (float)E;
  float mu[CPL], inv[CPL], gg[CPL], bb[CPL];
  #pragma unroll
  for (int u = 0; u < CPL; u++) {
    int c = lane + u * 64;
    float m = stats[c] * invE;
    float var = stats[Cout + c] * invE - m * m;
    mu[u] = m;
    inv[u] = rsqrtf(var + BN_EPS_F);
    gg[u] = g[c]; bb[u] = b[c];
  }
  for (int r = (int)blockIdx.x * wpb + wid; r < E; r += (int)gridDim.x * wpb) {
    float ss = 0.f;
    #pragma unroll
    for (int u = 0; u < CPL; u++) {
      int c = lane + u * 64;
      float v = H[(size_t)r * Cout + c];
      float o = (v - mu[u]) * inv[u] * gg[u] + bb[u];
      o = fmaxf(o, 0.f);
      Out[(size_t)r * Cout + c] = o;
      if constexpr (B16) Outb[(size_t)r * Cout + c] = f2b(o);
      ss += o * o;
    }
    if constexpr (KEYS) {
      #pragma unroll
      for (int s = 32; s > 0; s >>= 1) ss += __shfl_xor(ss, s, 64);
      if (lane == 0) {
        float sc = sqrtf(ss);
        u32 sb = __float_as_uint(sc);
        keys[r] = ((u64)sb << 32) | (u64)(0xFFFFFFFFu - (u32)r);
      }
    }
  }
}

// fused BN+ReLU+head matmul (Cout=64 -> 4)
__global__ void head_kernel(const float* __restrict__ H, const float* __restrict__ stats,
                            const float* __restrict__ g, const float* __restrict__ b,
                            const float* __restrict__ Wh, const float* __restrict__ bh,
                            int E, float* __restrict__ out)
{
  const int lane = threadIdx.x & 63;
  const int wid = threadIdx.x >> 6;
  const int wpb = blockDim.x >> 6;
  const float invE = 1.0f / (float)E;
  float m = stats[lane] * invE;
  float var = stats[64 + lane] * invE - m * m;
  float inv = rsqrtf(var + BN_EPS_F);
  float gg = g[lane], bb = b[lane];
  float4 w = *(const float4*)&Wh[lane * 4];
  float b0 = bh[0], b1 = bh[1], b2 = bh[2], b3 = bh[3];
  for (int r = (int)blockIdx.x * wpb + wid; r < E; r += (int)gridDim.x * wpb) {
    float v = H[(size_t)r * 64 + lane];
    float o = fmaxf((v - m) * inv * gg + bb, 0.f);
    float a0 = o * w.x, a1 = o * w.y, a2 = o * w.z, a3 = o * w.w;
    #pragma unroll
    for (int s = 32; s > 0; s >>= 1) {
      a0 += __shfl_xor(a0, s, 64);
      a1 += __shfl_xor(a1, s, 64);
      a2 += __shfl_xor(a2, s, 64);
      a3 += __shfl_xor(a3, s, 64);
    }
    if (lane == 0) {
      float4 ov = make_float4(a0 + b0, a1 + b1, a2 + b2, a3 + b3);
      *(float4*)&out[(size_t)r * 4] = ov;
    }
  }
}

// -------------------- pool-1 top-k (radix select on u64 keys) --------------
__global__ void hist_kernel(const u64* __restrict__ keys, int E, u32* __restrict__ hist,
                            u32* __restrict__ chist)
{
  for (int i = (int)blockIdx.x * blockDim.x + threadIdx.x; i < E;
       i += (int)gridDim.x * blockDim.x) {
    u32 bin = (u32)(keys[i] >> 44);
    atomicAdd(&hist[bin], 1u);
    atomicAdd(&chist[bin >> 10], 1u);
  }
}

// two-level scan, all serial work over LDS copies
__global__ void scan_kernel(const u32* __restrict__ hist, const u32* __restrict__ chist,
                            int K, u32* __restrict__ sel)
{
  __shared__ u32 sc[1024];
  __shared__ u32 sb2[1024];
  __shared__ int selChunk;
  __shared__ u32 aboveChunk;
  const int tid = threadIdx.x;
  sc[tid] = chist[tid];
  __syncthreads();
  if (tid == 0) {
    u32 above = 0; int scν = 0; u32 ab = 0;
    for (int t = 1023; t >= 0; t--) {
      if (above + sc[t] >= (u32)K) { scν = t; ab = above; break; }
      above += sc[t];
    }
    selChunk = scν; aboveChunk = ab;
  }
  __syncthreads();
  sb2[tid] = hist[(size_t)selChunk * 1024 + tid];
  __syncthreads();
  if (tid == 0) {
    u32 above = aboveChunk; int sb = 0;
    for (int t = 1023; t >= 0; t--) {
      u32 c = sb2[t];
      if (above + c >= (u32)K) { sb = t; break; }
      above += c;
    }
    sel[0] = (u32)(selChunk * 1024 + sb);
    sel[1] = above;
    sel[2] = (u32)K - above;
  }
}

__global__ void collect_kernel(const u64* __restrict__ keys, int E, const u32* __restrict__ sel,
                               u64* __restrict__ cand, u32* __restrict__ count)
{
  u32 bin = sel[0];
  for (int i = (int)blockIdx.x * blockDim.x + threadIdx.x; i < E;
       i += (int)gridDim.x * blockDim.x) {
    if ((u32)(keys[i] >> 44) == bin) {
      u32 p = atomicAdd(count, 1u);
      if (p < (u32)CAND_CAP) cand[p] = keys[i];
    }
  }
}

__global__ void thresh_kernel(const u64* __restrict__ cand, const u32* __restrict__ count,
                              const u32* __restrict__ sel, u64* __restrict__ thr)
{
  __shared__ u64 sk[CAND_CAP];
  const int tid = threadIdx.x;
  const int nth = blockDim.x;
  int n = (int)(*count > (u32)CAND_CAP ? (u32)CAND_CAP : *count);
  int n2 = 2; while (n2 < n) n2 <<= 1;
  for (int i = tid; i < n2; i += nth) sk[i] = (i < n) ? cand[i] : 0ull;
  __syncthreads();
  for (int k = 2; k <= n2; k <<= 1)
    for (int j = k >> 1; j > 0; j >>= 1) {
      for (int i = tid; i < n2; i += nth) {
        int p = i ^ j;
        if (p > i) {
          u64 a = sk[i], bb = sk[p];
          bool up = ((i & k) == 0);
          bool sw = up ? (a < bb) : (a > bb);
          if (sw) { sk[i] = bb; sk[p] = a; }
        }
      }
      __syncthreads();
    }
  if (tid == 0) {
    int kr = (int)sel[2];
    thr[0] = sk[kr - 1];
  }
}

// -------------------- ordered compaction: count / scan / scatter -----------
__global__ void keep_count_kernel(const u64* __restrict__ keys, int E,
                                  const u64* __restrict__ thrp, u32* __restrict__ bcnt)
{
  const u64 thr = thrp[0];
  const int tid = threadIdx.x;
  int base = (int)blockIdx.x * 1024 + tid * 4;
  u32 c = 0;
  #pragma unroll
  for (int u = 0; u < 4; u++) {
    int i = base + u;
    if (i < E && keys[i] >= thr) c++;
  }
  __shared__ u32 sm[256];
  sm[tid] = c;
  __syncthreads();
  for (int s = 128; s > 0; s >>= 1) {
    if (tid < s) sm[tid] += sm[tid + s];
    __syncthreads();
  }
  if (tid == 0) bcnt[blockIdx.x] = sm[0];
}

__global__ void keep_scan_kernel(const u32* __restrict__ bcnt, int NB, u32* __restrict__ boffs)
{
  __shared__ u32 sm[256];
  const int tid = threadIdx.x;
  u32 v = (tid < NB) ? bcnt[tid] : 0;
  sm[tid] = v;
  __syncthreads();
  for (int off = 1; off < 256; off <<= 1) {
    u32 t = 0;
    if (tid >= off) t = sm[tid - off];
    __syncthreads();
    sm[tid] += t;
    __syncthreads();
  }
  if (tid < NB) boffs[tid] = sm[tid] - v;
}

__global__ void keep_scatter_kernel(const u64* __restrict__ keys, int E,
                                    const u64* __restrict__ thrp, const u32* __restrict__ boffs,
                                    int* __restrict__ keep, int K)
{
  const u64 thr = thrp[0];
  const int tid = threadIdx.x;
  int base = (int)blockIdx.x * 1024 + tid * 4;
  u32 f[4]; u32 c = 0;
  #pragma unroll
  for (int u = 0; u < 4; u++) {
    int i = base + u;
    f[u] = (i < E && keys[i] >= thr) ? 1u : 0u;
    c += f[u];
  }
  __shared__ u32 sm[256];
  sm[tid] = c;
  __syncthreads();
  for (int off = 1; off < 256; off <<= 1) {
    u32 t = 0;
    if (tid >= off) t = sm[tid - off];
    __syncthreads();
    sm[tid] += t;
    __syncthreads();
  }
  u32 pos = boffs[blockIdx.x] + sm[tid] - c;
  #pragma unroll
  for (int u = 0; u < 4; u++) {
    if (f[u]) {
      if (pos < (u32)K) keep[pos] = base + u;
      pos++;
    }
  }
}

// -------------------- pools 2/3: single-block full sort ---------------------
template<int NPOW>
__global__ void pool_select_kernel(const u64* __restrict__ keys, int E, int K,
                                   int* __restrict__ keep)
{
  __shared__ u64 sk[NPOW];
  __shared__ int si[NPOW];
  const int tid = threadIdx.x, nth = blockDim.x;
  for (int i = tid; i < NPOW; i += nth) sk[i] = (i < E) ? keys[i] : 0ull;
  __syncthreads();
  for (int k = 2; k <= NPOW; k <<= 1)
    for (int j = k >> 1; j > 0; j >>= 1) {
      for (int i = tid; i < NPOW; i += nth) {
        int p = i ^ j;
        if (p > i) {
          u64 a = sk[i], bb = sk[p];
          bool up = ((i & k) == 0);
          bool sw = up ? (a < bb) : (a > bb);
          if (sw) { sk[i] = bb; sk[p] = a; }
        }
      }
      __syncthreads();
    }
  for (int i = tid; i < NPOW; i += nth)
    si[i] = (i < K) ? (int)(0xFFFFFFFFu - (u32)(sk[i] & 0xFFFFFFFFull)) : 0x7FFFFFFF;
  __syncthreads();
  for (int k = 2; k <= NPOW; k <<= 1)
    for (int j = k >> 1; j > 0; j >>= 1) {
      for (int i = tid; i < NPOW; i += nth) {
        int p = i ^ j;
        if (p > i) {
          int a = si[i], bb = si[p];
          bool up = ((i & k) == 0);
          bool sw = up ? (a > bb) : (a < bb);
          if (sw) { si[i] = bb; si[p] = a; }
        }
      }
      __syncthreads();
    }
  for (int i = tid; i < K; i += nth) keep[i] = si[i];
}

template<int C>
__global__ void pool_finish_kernel(const float* __restrict__ Xsrc, const int* __restrict__ nb_src,
                                   const int* __restrict__ keep, int K, int Esrc,
                                   float* __restrict__ Xp, int* __restrict__ nbp)
{
  int total = K * C;
  for (int idx = (int)blockIdx.x * blockDim.x + threadIdx.x; idx < total;
       idx += (int)gridDim.x * blockDim.x) {
    int i = idx / C, c = idx % C;
    Xp[idx] = Xsrc[(size_t)keep[i] * C + c];
  }
  for (int idx = (int)blockIdx.x * blockDim.x + threadIdx.x; idx < K * 4;
       idx += (int)gridDim.x * blockDim.x) {
    int i = idx >> 2, j = idx & 3;
    int v = nb_src[(size_t)keep[i] * 4 + j];
    v = iclampi(v, 0, Esrc - 1);
    int p = bsearch_eq(keep, K, v);
    nbp[idx] = (p < 0) ? i : p;
  }
}

__global__ void unpool_cat_kernel(const float* __restrict__ Xc, const float* __restrict__ Xs,
                                  const int* __restrict__ keep, int K, int E,
                                  int Cc, int Cs, float* __restrict__ out)
{
  int Ct = Cc + Cs;
  int total = E * Ct;
  for (int idx = (int)blockIdx.x * blockDim.x + threadIdx.x; idx < total;
       idx += (int)gridDim.x * blockDim.x) {
    int r = idx / Ct, c = idx % Ct;
    float v;
    if (c < Cc) { int nn = nearest_keep(keep, K, r); v = Xc[(size_t)nn * Cc + c]; }
    else v = Xs[(size_t)r * Cs + (c - Cc)];
    out[idx] = v;
  }
}

__global__ void nn_map_kernel(const int* __restrict__ keep, int K, int E, int* __restrict__ nn)
{
  for (int i = (int)blockIdx.x * blockDim.x + threadIdx.x; i < E;
       i += (int)gridDim.x * blockDim.x)
    nn[i] = nearest_keep(keep, K, i);
}

// ---------------------------------------------------------------------------
extern "C" void kernel_launch(void* const* d_in, const int* in_sizes, int n_in,
                              void* d_out, int out_size, void* d_ws, size_t ws_size,
                              hipStream_t stream)
{
  (void)in_sizes; (void)n_in; (void)out_size; (void)ws_size;
  const float* x     = (const float*)d_in[0];
  const int*   nb    = (const int*)d_in[1];
  const float* W_e1  = (const float*)d_in[2];
  const float* g_e1  = (const float*)d_in[3];
  const float* b_e1  = (const float*)d_in[4];
  const float* W_e2  = (const float*)d_in[5];
  const float* g_e2  = (const float*)d_in[6];
  const float* b_e2  = (const float*)d_in[7];
  const float* W_e3  = (const float*)d_in[8];
  const float* g_e3  = (const float*)d_in[9];
  const float* b_e3  = (const float*)d_in[10];
  const float* W_e4  = (const float*)d_in[11];
  const float* g_e4  = (const float*)d_in[12];
  const float* b_e4  = (const float*)d_in[13];
  const float* W_d3  = (const float*)d_in[14];
  const float* g_d3  = (const float*)d_in[15];
  const float* b_d3  = (const float*)d_in[16];
  const float* W_d2  = (const float*)d_in[17];
  const float* g_d2  = (const float*)d_in[18];
  const float* b_d2  = (const float*)d_in[19];
  const float* W_d1  = (const float*)d_in[20];
  const float* g_d1  = (const float*)d_in[21];
  const float* b_d1  = (const float*)d_in[22];
  const float* W_head = (const float*)d_in[23];
  const float* bias_head = (const float*)d_in[24];
  float* out = (float*)d_out;

  char* p = (char*)d_ws;
  auto alloc = [&](size_t bytes) -> char* {
    char* q = p; p += (bytes + 255) & ~(size_t)255; return q;
  };

  // --- zero zone (one memset) ---
  char* zz = p;
  u32*   hist  = (u32*)alloc(sizeof(u32) * (1u << 20));
  u32*   chist = (u32*)alloc(sizeof(u32) * 1024);
  float* stats = (float*)alloc(sizeof(float) * 2 * (64 + 128 + 256 + 512 + 256 + 128 + 64));
  u32*   ctrl  = (u32*)alloc(sizeof(u32) * 16);
  u64*   thr   = (u64*)alloc(sizeof(u64) * 2);
  u32*   sel   = (u32*)alloc(sizeof(u32) * 8);
  float* H2    = (float*)alloc(sizeof(float) * T1 * 128);   // split-K -> zeroed
  float* H3    = (float*)alloc(sizeof(float) * T2 * 256);
  float* H4    = (float*)alloc(sizeof(float) * T3 * 512);
  float* Hd3   = (float*)alloc(sizeof(float) * T2 * 256);
  float* Hd2   = (float*)alloc(sizeof(float) * T1 * 128);
  size_t zz_bytes = (size_t)(p - zz);
  // --- rest ---
  u32*   bcnt  = (u32*)alloc(sizeof(u32) * 256);
  u32*   boffs = (u32*)alloc(sizeof(u32) * 256);
  float* e1    = (float*)alloc(sizeof(float) * (size_t)E0 * 64);
  u64*   keys1 = (u64*)alloc(sizeof(u64) * E0);
  u64*   cand  = (u64*)alloc(sizeof(u64) * CAND_CAP);
  int*   keep1 = (int*)alloc(sizeof(int) * T1);
  float* e1p   = (float*)alloc(sizeof(float) * T1 * 64);
  int*   nb1   = (int*)alloc(sizeof(int) * T1 * 4);
  float* e2    = (float*)alloc(sizeof(float) * T1 * 128);
  u64*   keys2 = (u64*)alloc(sizeof(u64) * T1);
  int*   keep2 = (int*)alloc(sizeof(int) * T2);
  float* e2p   = (float*)alloc(sizeof(float) * T2 * 128);
  int*   nb2   = (int*)alloc(sizeof(int) * T2 * 4);
  float* e3    = (float*)alloc(sizeof(float) * T2 * 256);
  u64*   keys3 = (u64*)alloc(sizeof(u64) * T2);
  int*   keep3 = (int*)alloc(sizeof(int) * T3);
  float* e3p   = (float*)alloc(sizeof(float) * T3 * 256);
  int*   nb3   = (int*)alloc(sizeof(int) * T3 * 4);
  float* e4    = (float*)alloc(sizeof(float) * T3 * 512);
  float* d3cat = (float*)alloc(sizeof(float) * T2 * 768);
  float* d3    = (float*)alloc(sizeof(float) * T2 * 256);
  float* d2cat = (float*)alloc(sizeof(float) * T1 * 384);
  float* d2    = (float*)alloc(sizeof(float) * T1 * 128);
  int*   nn1   = (int*)alloc(sizeof(int) * E0);
  float* Hd1   = (float*)alloc(sizeof(float) * (size_t)E0 * 64);
  ushort_t* e1b = (ushort_t*)alloc(sizeof(ushort_t) * (size_t)E0 * 64);
  ushort_t* d2b = (ushort_t*)alloc(sizeof(ushort_t) * T1 * 128);
  ushort_t* Wt  = (ushort_t*)alloc(sizeof(ushort_t) * 5 * 64 * 192);

  float* s1  = stats;
  float* s2  = s1 + 2 * 64;
  float* s3  = s2 + 2 * 128;
  float* s4  = s3 + 2 * 256;
  float* sd3 = s4 + 2 * 512;
  float* sd2 = sd3 + 2 * 256;
  float* sd1 = sd2 + 2 * 128;

  hipMemsetAsync(zz, 0, zz_bytes, stream);
  prep_wd1_kernel<<<dim3(240), 256, 0, stream>>>(W_d1, Wt);

  // ---- encoder 1 (dedicated kernel, vectorized gathers, fused stats) ----
  e1_conv_kernel<<<dim3((E0 + 127) / 128), 256, 0, stream>>>(x, nb, W_e1, e1, s1);
  bn_kernel<64, true, true><<<dim3(8192), 256, 0, stream>>>(e1, s1, g_e1, b_e1, E0, e1, e1b, keys1);

  // ---- pool 1 (top-1500 of 200000) ----
  hist_kernel<<<dim3(782), 256, 0, stream>>>(keys1, E0, hist, chist);
  scan_kernel<<<dim3(1), 1024, 0, stream>>>(hist, chist, T1, sel);
  collect_kernel<<<dim3(782), 256, 0, stream>>>(keys1, E0, sel, cand, ctrl);
  thresh_kernel<<<dim3(1), 1024, 0, stream>>>(cand, ctrl, sel, thr);
  keep_count_kernel<<<dim3(NB_KEEP), 256, 0, stream>>>(keys1, E0, thr, bcnt);
  keep_scan_kernel<<<dim3(1), 256, 0, stream>>>(bcnt, NB_KEEP, boffs);
  keep_scatter_kernel<<<dim3(NB_KEEP), 256, 0, stream>>>(keys1, E0, thr, boffs, keep1, T1);
  pool_finish_kernel<64><<<dim3(380), 256, 0, stream>>>(e1, nb, keep1, T1, E0, e1p, nb1);

  // ---- encoder 2 (split-K=2) ----
  conv_kernel<64, 128, 32, 64, 8, 2, 4, 2, false>
      <<<dim3((T1 + 31) / 32, 128 / 64, 2), 256, 0, stream>>>(e1p, nb1, T1, W_e2, H2, nullptr);
  stats_kernel<<<dim3((T1 + 63) / 64), 256, 0, stream>>>(H2, T1, 128, s2);
  bn_kernel<128, true, false><<<dim3(512), 256, 0, stream>>>(H2, s2, g_e2, b_e2, T1, e2, nullptr, keys2);
  pool_select_kernel<2048><<<dim3(1), 256, 0, stream>>>(keys2, T1, T2, keep2);
  pool_finish_kernel<128><<<dim3(380), 256, 0, stream>>>(e2, nb1, keep2, T2, T1, e2p, nb2);

  // ---- encoder 3 (split-K=4) ----
  conv_kernel<128, 256, 32, 64, 8, 2, 4, 4, false>
      <<<dim3((T2 + 31) / 32, 256 / 64, 4), 256, 0, stream>>>(e2p, nb2, T2, W_e3, H3, nullptr);
  stats_kernel<<<dim3((T2 + 63) / 64), 256, 0, stream>>>(H3, T2, 256, s3);
  bn_kernel<256, true, false><<<dim3(256), 256, 0, stream>>>(H3, s3, g_e3, b_e3, T2, e3, nullptr, keys3);
  pool_select_kernel<1024><<<dim3(1), 256, 0, stream>>>(keys3, T2, T3, keep3);
  pool_finish_kernel<256><<<dim3(380), 256, 0, stream>>>(e3, nb2, keep3, T3, T2, e3p, nb3);

  // ---- encoder 4 (split-K=4) ----
  conv_kernel<256, 512, 32, 64, 8, 2, 4, 4, false>
      <<<dim3((T3 + 31) / 32, 512 / 64, 4), 256, 0, stream>>>(e3p, nb3, T3, W_e4, H4, nullptr);
  stats_kernel<<<dim3((T3 + 63) / 64), 256, 0, stream>>>(H4, T3, 512, s4);
  bn_kernel<512, false, false><<<dim3(128), 256, 0, stream>>>(H4, s4, g_e4, b_e4, T3, e4, nullptr, nullptr);

  // ---- decoder 3 (split-K=8) ----
  unpool_cat_kernel<<<dim3((T2 * 768 + 255) / 256), 256, 0, stream>>>(
      e4, e3, keep3, T3, T2, 512, 256, d3cat);
  conv_kernel<768, 256, 32, 64, 8, 2, 4, 8, false>
      <<<dim3((T2 + 31) / 32, 256 / 64, 8), 256, 0, stream>>>(d3cat, nb2, T2, W_d3, Hd3, nullptr);
  stats_kernel<<<dim3((T2 + 63) / 64), 256, 0, stream>>>(Hd3, T2, 256, sd3);
  bn_kernel<256, false, false><<<dim3(256), 256, 0, stream>>>(Hd3, sd3, g_d3, b_d3, T2, d3, nullptr, nullptr);

  // ---- decoder 2 (split-K=8) ----
  unpool_cat_kernel<<<dim3((T1 * 384 + 255) / 256), 256, 0, stream>>>(
      d3, e2, keep2, T2, T1, 256, 128, d2cat);
  conv_kernel<384, 128, 32, 64, 8, 2, 4, 8, false>
      <<<dim3((T1 + 31) / 32, 128 / 64, 8), 256, 0, stream>>>(d2cat, nb1, T1, W_d2, Hd2, nullptr);
  stats_kernel<<<dim3((T1 + 63) / 64), 256, 0, stream>>>(Hd2, T1, 128, sd2);
  bn_kernel<128, false, true><<<dim3(512), 256, 0, stream>>>(Hd2, sd2, g_d2, b_d2, T1, d2, d2b, nullptr);

  // ---- decoder 1 (bf16 MFMA conv, row-split waves) ----
  nn_map_kernel<<<dim3(782), 256, 0, stream>>>(keep1, T1, E0, nn1);
  d1_mfma_kernel<<<dim3((E0 + 127) / 128), 256, 0, stream>>>(d2b, e1b, nn1, nb, Wt, Hd1, sd1);

  // ---- head (fused BN+ReLU+matmul) ----
  head_kernel<<<dim3(8192), 256, 0, stream>>>(Hd1, sd1, g_d1, b_d1, W_head, bias_head, E0, out);
}

// Round 6
// 1193.768 us; speedup vs baseline: 2.1496x; 2.1496x over previous
//
#include <hip/hip_runtime.h>
#include <stdint.h>

typedef unsigned long long u64;
typedef unsigned int u32;
typedef unsigned short ushort_t;

#define FI __device__ __forceinline__

static constexpr float BN_EPS_F = 1e-5f;
static constexpr int E0 = 200000;
static constexpr int T1 = 1500, T2 = 750, T3 = 375;
static constexpr int CAND_CAP = 4096;
static constexpr int NB_KEEP = (E0 + 1023) / 1024;

typedef __attribute__((ext_vector_type(8))) short short8;
typedef __attribute__((ext_vector_type(4))) float f32x4;

FI int iclampi(int v, int lo, int hi) { return v < lo ? lo : (v > hi ? hi : v); }

FI ushort_t f2b(float f) {
  u32 u = __float_as_uint(f);
  u32 r = (u + 0x7FFFu + ((u >> 16) & 1u)) >> 16;
  return (ushort_t)r;
}

FI int nearest_keep(const int* __restrict__ keep, int K, int idx) {
  int lo = 0, hi = K;
  while (lo < hi) { int mid = (lo + hi) >> 1; if (keep[mid] < idx) lo = mid + 1; else hi = mid; }
  int l = lo - 1; l = l < 0 ? 0 : (l > K - 1 ? K - 1 : l);
  int r = lo;     r = r < 0 ? 0 : (r > K - 1 ? K - 1 : r);
  int dl = idx - keep[l]; dl = dl < 0 ? -dl : dl;
  int dr = idx - keep[r]; dr = dr < 0 ? -dr : dr;
  return (dl <= dr) ? l : r;
}

FI int bsearch_eq(const int* __restrict__ keep, int K, int v) {
  int lo = 0, hi = K;
  while (lo < hi) { int mid = (lo + hi) >> 1; if (keep[mid] < v) lo = mid + 1; else hi = mid; }
  if (lo < K && keep[lo] == v) return lo;
  return -1;
}

// ---------------------------------------------------------------------------
// Generic fp32 mesh-conv for mid layers (split-K, 4-wave blocks).
// ---------------------------------------------------------------------------
template<int C, int Cout, int BR, int BC, int KT, int TR, int TC, int KSPLIT,
         bool FUSE_STATS>
__global__ __launch_bounds__((BR / TR) * (BC / TC))
void conv_kernel(const float* __restrict__ X,
                 const int* __restrict__ nb, int E,
                 const float* __restrict__ W,
                 float* __restrict__ H, float* __restrict__ stats)
{
  constexpr int NTH = (BR / TR) * (BC / TC);
  constexpr int VK = 5 * KT;
  constexpr int KC = C / KSPLIT;
  static_assert(KC % KT == 0, "KC % KT");

  const int row0 = blockIdx.x * BR;
  const int col0 = blockIdx.y * BC;
  const int c_begin = (KSPLIT > 1) ? (int)blockIdx.z * KC : 0;

  __shared__ float As[VK][BR];
  __shared__ float Bs[VK][BC];
  __shared__ int rowsS[5][BR];
  __shared__ float red[FUSE_STATS ? 2 * (BR / TR) * BC : 1];

  const int tid = threadIdx.x;

  for (int q = tid; q < BR; q += NTH) {
    int r = row0 + q;
    int rr[5];
    if (r < E) {
      rr[0] = r;
      #pragma unroll
      for (int j = 0; j < 4; j++) {
        int v = nb[(size_t)r * 4 + j];
        rr[1 + j] = iclampi(v, 0, E - 1);
      }
    } else {
      #pragma unroll
      for (int j = 0; j < 5; j++) rr[j] = -1;
    }
    #pragma unroll
    for (int j = 0; j < 5; j++) rowsS[j][q] = rr[j];
  }

  float acc[TR][TC];
  #pragma unroll
  for (int i = 0; i < TR; i++)
    #pragma unroll
    for (int j = 0; j < TC; j++) acc[i][j] = 0.f;

  const int tr = tid / (BC / TC);
  const int tc = tid % (BC / TC);
  const int rA = tr * TR;
  const int cB = tc * TC;

  for (int c0 = c_begin; c0 < c_begin + KC; c0 += KT) {
    __syncthreads();
    for (int q = tid; q < VK * (BC / 4); q += NTH) {
      int kk = q / (BC / 4);
      int c4 = q % (BC / 4);
      int p = kk / KT, t = kk % KT;
      float4 wv = *(const float4*)&W[(size_t)(p * C + c0 + t) * Cout + col0 + c4 * 4];
      *(float4*)&Bs[kk][c4 * 4] = wv;
    }
    for (int q = tid; q < BR * KT; q += NTH) {
      int t = q % KT, rq = q / KT;
      int c = c0 + t;
      float s0 = 0.f, a1 = 0.f, a2 = 0.f, a3 = 0.f, a4 = 0.f;
      if (rowsS[0][rq] >= 0) {
        float v0, v1, v2, v3;
        s0 = X[(size_t)rowsS[0][rq] * C + c];
        v0 = X[(size_t)rowsS[1][rq] * C + c];
        v1 = X[(size_t)rowsS[2][rq] * C + c];
        v2 = X[(size_t)rowsS[3][rq] * C + c];
        v3 = X[(size_t)rowsS[4][rq] * C + c];
        a1 = fminf(v0, v1); a2 = fmaxf(v0, v1);
        a3 = fminf(v2, v3); a4 = fmaxf(v2, v3);
      }
      As[0 * KT + t][rq] = s0;
      As[1 * KT + t][rq] = a1;
      As[2 * KT + t][rq] = a2;
      As[3 * KT + t][rq] = a3;
      As[4 * KT + t][rq] = a4;
    }
    __syncthreads();

    for (int kk = 0; kk < VK; kk++) {
      float a[TR], b[TC];
      #pragma unroll
      for (int i = 0; i < TR; i++) a[i] = As[kk][rA + i];
      #pragma unroll
      for (int j = 0; j < TC; j++) b[j] = Bs[kk][cB + j];
      #pragma unroll
      for (int i = 0; i < TR; i++)
        #pragma unroll
        for (int j = 0; j < TC; j++)
          acc[i][j] = fmaf(a[i], b[j], acc[i][j]);
    }
  }

  #pragma unroll
  for (int i = 0; i < TR; i++) {
    int r = row0 + rA + i;
    if (r < E) {
      if constexpr (KSPLIT > 1) {
        #pragma unroll
        for (int j = 0; j < TC; j++)
          atomicAdd(&H[(size_t)r * Cout + col0 + cB + j], acc[i][j]);
      } else {
        #pragma unroll
        for (int j = 0; j < TC; j += 4) {
          float4 v = make_float4(acc[i][j], acc[i][j + 1], acc[i][j + 2], acc[i][j + 3]);
          *(float4*)&H[(size_t)r * Cout + col0 + cB + j] = v;
        }
      }
    }
  }

  if constexpr (FUSE_STATS) {
    float s[TC], q2[TC];
    #pragma unroll
    for (int j = 0; j < TC; j++) { s[j] = 0.f; q2[j] = 0.f; }
    #pragma unroll
    for (int i = 0; i < TR; i++) {
      int r = row0 + rA + i;
      if (r < E) {
        #pragma unroll
        for (int j = 0; j < TC; j++) { float v = acc[i][j]; s[j] += v; q2[j] += v * v; }
      }
    }
    __syncthreads();
    float* redS = &red[0];
    float* redQ = &red[(BR / TR) * BC];
    #pragma unroll
    for (int j = 0; j < TC; j++) {
      redS[tr * BC + cB + j] = s[j];
      redQ[tr * BC + cB + j] = q2[j];
    }
    __syncthreads();
    for (int col = tid; col < BC; col += NTH) {
      float ts = 0.f, tq = 0.f;
      for (int g = 0; g < BR / TR; g++) { ts += redS[g * BC + col]; tq += redQ[g * BC + col]; }
      atomicAdd(&stats[col0 + col], ts);
      atomicAdd(&stats[Cout + col0 + col], tq);
    }
  }
}

// ---------------------------------------------------------------------------
// Dedicated e1 conv (C=5, Cout=64): vectorized row gathers, W in LDS, stats.
// ---------------------------------------------------------------------------
__global__ __launch_bounds__(256)
void e1_conv_kernel(const float* __restrict__ X, const int* __restrict__ nb,
                    const float* __restrict__ W,
                    float* __restrict__ H, float* __restrict__ stats)
{
  __shared__ float As[25][128];
  __shared__ float Bs[25][64];
  __shared__ float red[2 * 32 * 64];

  const int tid = threadIdx.x;
  const int row0 = (int)blockIdx.x * 128;

  if (tid < 128) {
    int r = row0 + tid; if (r > E0 - 1) r = E0 - 1;
    int rs[5];
    rs[0] = r;
    #pragma unroll
    for (int j = 0; j < 4; j++) rs[1 + j] = iclampi((int)nb[(size_t)r * 4 + j], 0, E0 - 1);
    float v[5][5];
    #pragma unroll
    for (int j = 0; j < 5; j++) {
      const float* src = &X[(size_t)rs[j] * 5];
      float4 a = *(const float4*)src;
      v[j][0] = a.x; v[j][1] = a.y; v[j][2] = a.z; v[j][3] = a.w;
      v[j][4] = src[4];
    }
    #pragma unroll
    for (int c = 0; c < 5; c++) {
      As[0 * 5 + c][tid] = v[0][c];
      As[1 * 5 + c][tid] = fminf(v[1][c], v[2][c]);
      As[2 * 5 + c][tid] = fmaxf(v[1][c], v[2][c]);
      As[3 * 5 + c][tid] = fminf(v[3][c], v[4][c]);
      As[4 * 5 + c][tid] = fmaxf(v[3][c], v[4][c]);
    }
  } else {
    for (int q = tid - 128; q < 25 * 16; q += 128) {
      int k = q / 16, c4 = q % 16;
      float4 wv = *(const float4*)&W[(size_t)k * 64 + c4 * 4];
      *(float4*)&Bs[k][c4 * 4] = wv;
    }
  }
  __syncthreads();

  const int tr = tid >> 3;
  const int tc = tid & 7;
  const int rA = tr * 4;
  const int cB = tc * 8;

  float acc[4][8];
  #pragma unroll
  for (int i = 0; i < 4; i++)
    #pragma unroll
    for (int j = 0; j < 8; j++) acc[i][j] = 0.f;

  for (int k = 0; k < 25; k++) {
    float a[4], b[8];
    #pragma unroll
    for (int i = 0; i < 4; i++) a[i] = As[k][rA + i];
    #pragma unroll
    for (int j = 0; j < 8; j++) b[j] = Bs[k][cB + j];
    #pragma unroll
    for (int i = 0; i < 4; i++)
      #pragma unroll
      for (int j = 0; j < 8; j++)
        acc[i][j] = fmaf(a[i], b[j], acc[i][j]);
  }

  float s[8], q2[8];
  #pragma unroll
  for (int j = 0; j < 8; j++) { s[j] = 0.f; q2[j] = 0.f; }
  #pragma unroll
  for (int i = 0; i < 4; i++) {
    int r = row0 + rA + i;
    if (r < E0) {
      #pragma unroll
      for (int j = 0; j < 8; j += 4) {
        float4 v = make_float4(acc[i][j], acc[i][j + 1], acc[i][j + 2], acc[i][j + 3]);
        *(float4*)&H[(size_t)r * 64 + cB + j] = v;
      }
      #pragma unroll
      for (int j = 0; j < 8; j++) { float v = acc[i][j]; s[j] += v; q2[j] += v * v; }
    }
  }
  __syncthreads();
  float* redS = &red[0];
  float* redQ = &red[32 * 64];
  #pragma unroll
  for (int j = 0; j < 8; j++) {
    redS[tr * 64 + cB + j] = s[j];
    redQ[tr * 64 + cB + j] = q2[j];
  }
  __syncthreads();
  for (int col = tid; col < 64; col += 256) {
    float ts = 0.f, tq = 0.f;
    for (int g = 0; g < 32; g++) { ts += redS[g * 64 + col]; tq += redQ[g * 64 + col]; }
    atomicAdd(&stats[col], ts);
    atomicAdd(&stats[64 + col], tq);
  }
}

// ---------------------------------------------------------------------------
// d1 conv via bf16 MFMA, row-split waves.
// ---------------------------------------------------------------------------
__global__ __launch_bounds__(256, 2)
void d1_mfma_kernel(const ushort_t* __restrict__ d2b, const ushort_t* __restrict__ e1b,
                    const int* __restrict__ nn1, const int* __restrict__ nb,
                    const ushort_t* __restrict__ Wt,
                    float* __restrict__ H, float* __restrict__ stats)
{
  __shared__ int rowsD[5][128];
  __shared__ int rowsS[5][128];

  const int tid = threadIdx.x;
  const int lane = tid & 63;
  const int wv = tid >> 6;
  const int l15 = lane & 15;
  const int quad = lane >> 4;
  const int row0 = (int)blockIdx.x * 128;

  if (tid < 128) {
    int r = row0 + tid; if (r > E0 - 1) r = E0 - 1;
    int rs[5];
    rs[0] = r;
    #pragma unroll
    for (int j = 0; j < 4; j++) rs[1 + j] = iclampi((int)nb[(size_t)r * 4 + j], 0, E0 - 1);
    #pragma unroll
    for (int j = 0; j < 5; j++) { rowsS[j][tid] = rs[j]; rowsD[j][tid] = nn1[rs[j]]; }
  }
  __syncthreads();

  f32x4 acc[2][4];
  #pragma unroll
  for (int mi = 0; mi < 2; mi++)
    #pragma unroll
    for (int ni = 0; ni < 4; ni++) acc[mi][ni] = (f32x4){0.f, 0.f, 0.f, 0.f};

  for (int cc = 0; cc < 6; cc++) {
    const bool fromD = cc < 4;
    const ushort_t* __restrict__ src = fromD ? d2b : e1b;
    const int stride = fromD ? 128 : 64;
    const int cbase = (fromD ? cc * 32 : (cc - 4) * 32) + quad * 8;

    short8 a[2][5];
    #pragma unroll
    for (int mi = 0; mi < 2; mi++) {
      int rr = wv * 32 + mi * 16 + l15;
      int r0, r1, r2, r3, r4;
      if (fromD) {
        r0 = rowsD[0][rr]; r1 = rowsD[1][rr]; r2 = rowsD[2][rr];
        r3 = rowsD[3][rr]; r4 = rowsD[4][rr];
      } else {
        r0 = rowsS[0][rr]; r1 = rowsS[1][rr]; r2 = rowsS[2][rr];
        r3 = rowsS[3][rr]; r4 = rowsS[4][rr];
      }
      uint4 v0 = *(const uint4*)&src[(size_t)r0 * stride + cbase];
      uint4 v1 = *(const uint4*)&src[(size_t)r1 * stride + cbase];
      uint4 v2 = *(const uint4*)&src[(size_t)r2 * stride + cbase];
      uint4 v3 = *(const uint4*)&src[(size_t)r3 * stride + cbase];
      uint4 v4 = *(const uint4*)&src[(size_t)r4 * stride + cbase];

      uint4 lo12, hi12, lo34, hi34;
      {
        const ushort_t* pa = (const ushort_t*)&v1;
        const ushort_t* pb = (const ushort_t*)&v2;
        ushort_t* lo = (ushort_t*)&lo12;
        ushort_t* hi = (ushort_t*)&hi12;
        #pragma unroll
        for (int i = 0; i < 8; i++) {
          ushort_t xx = pa[i], yy = pb[i];   // bf16 >= 0 -> u16 order == numeric
          lo[i] = xx < yy ? xx : yy;
          hi[i] = xx < yy ? yy : xx;
        }
      }
      {
        const ushort_t* pa = (const ushort_t*)&v3;
        const ushort_t* pb = (const ushort_t*)&v4;
        ushort_t* lo = (ushort_t*)&lo34;
        ushort_t* hi = (ushort_t*)&hi34;
        #pragma unroll
        for (int i = 0; i < 8; i++) {
          ushort_t xx = pa[i], yy = pb[i];
          lo[i] = xx < yy ? xx : yy;
          hi[i] = xx < yy ? yy : xx;
        }
      }
      a[mi][0] = *(short8*)&v0;
      a[mi][1] = *(short8*)&lo12;
      a[mi][2] = *(short8*)&hi12;
      a[mi][3] = *(short8*)&lo34;
      a[mi][4] = *(short8*)&hi34;
    }

    #pragma unroll
    for (int p = 0; p < 5; p++) {
      short8 bf[4];
      #pragma unroll
      for (int ni = 0; ni < 4; ni++)
        bf[ni] = *(const short8*)&Wt[((size_t)(p * 64 + ni * 16 + l15)) * 192 + cc * 32 + quad * 8];
      #pragma unroll
      for (int mi = 0; mi < 2; mi++)
        #pragma unroll
        for (int ni = 0; ni < 4; ni++)
          acc[mi][ni] = __builtin_amdgcn_mfma_f32_16x16x32_bf16(a[mi][p], bf[ni], acc[mi][ni], 0, 0, 0);
    }
  }

  float s[4] = {0.f, 0.f, 0.f, 0.f}, q[4] = {0.f, 0.f, 0.f, 0.f};
  #pragma unroll
  for (int mi = 0; mi < 2; mi++) {
    #pragma unroll
    for (int reg = 0; reg < 4; reg++) {
      int r = row0 + wv * 32 + mi * 16 + quad * 4 + reg;
      if (r < E0) {
        #pragma unroll
        for (int ni = 0; ni < 4; ni++) {
          float v = acc[mi][ni][reg];
          H[(size_t)r * 64 + ni * 16 + l15] = v;
          s[ni] += v; q[ni] += v * v;
        }
      }
    }
  }
  #pragma unroll
  for (int ni = 0; ni < 4; ni++) {
    float ts = s[ni], tq = q[ni];
    ts += __shfl_xor(ts, 16); tq += __shfl_xor(tq, 16);
    ts += __shfl_xor(ts, 32); tq += __shfl_xor(tq, 32);
    if (quad == 0) {
      int col = ni * 16 + l15;
      atomicAdd(&stats[col], ts);
      atomicAdd(&stats[64 + col], tq);
    }
  }
}

// W_d1 (960 x 64 fp32) -> Wt bf16 [(p*64+n)][192]
__global__ void prep_wd1_kernel(const float* __restrict__ W, ushort_t* __restrict__ Wt)
{
  int idx = (int)blockIdx.x * 256 + threadIdx.x;
  if (idx < 5 * 64 * 192) {
    int n = idx & 63;
    int k = idx >> 6;
    int p = k / 192, c = k % 192;
    Wt[((size_t)(p * 64 + n)) * 192 + c] = f2b(W[(size_t)k * 64 + n]);
  }
}

// column sum/sumsq for split-K layers
__global__ void stats_kernel(const float* __restrict__ H, int E, int Cout,
                             float* __restrict__ stats)
{
  const int RB = 64;
  int r0 = (int)blockIdx.x * RB;
  int rend = r0 + RB; if (rend > E) rend = E;
  for (int col = threadIdx.x; col < Cout; col += blockDim.x) {
    float s = 0.f, q = 0.f;
    for (int r = r0; r < rend; r++) { float v = H[(size_t)r * Cout + col]; s += v; q += v * v; }
    atomicAdd(&stats[col], s);
    atomicAdd(&stats[Cout + col], q);
  }
}

// BN(training stats) + ReLU; optional pooling key per row; optional bf16 copy
template<int Cout, bool KEYS, bool B16>
__global__ void bn_kernel(const float* __restrict__ H, const float* __restrict__ stats,
                          const float* __restrict__ g, const float* __restrict__ b,
                          int E, float* __restrict__ Out, ushort_t* __restrict__ Outb,
                          u64* __restrict__ keys)
{
  constexpr int CPL = Cout / 64;
  const int lane = threadIdx.x & 63;
  const int wid = threadIdx.x >> 6;
  const int wpb = blockDim.x >> 6;
  const float invE = 1.0f / (float)E;
  float mu[CPL], inv[CPL], gg[CPL], bb[CPL];
  #pragma unroll
  for (int u = 0; u < CPL; u++) {
    int c = lane + u * 64;
    float m = stats[c] * invE;
    float var = stats[Cout + c] * invE - m * m;
    mu[u] = m;
    inv[u] = rsqrtf(var + BN_EPS_F);
    gg[u] = g[c]; bb[u] = b[c];
  }
  for (int r = (int)blockIdx.x * wpb + wid; r < E; r += (int)gridDim.x * wpb) {
    float ss = 0.f;
    #pragma unroll
    for (int u = 0; u < CPL; u++) {
      int c = lane + u * 64;
      float v = H[(size_t)r * Cout + c];
      float o = (v - mu[u]) * inv[u] * gg[u] + bb[u];
      o = fmaxf(o, 0.f);
      Out[(size_t)r * Cout + c] = o;
      if constexpr (B16) Outb[(size_t)r * Cout + c] = f2b(o);
      ss += o * o;
    }
    if constexpr (KEYS) {
      #pragma unroll
      for (int s = 32; s > 0; s >>= 1) ss += __shfl_xor(ss, s, 64);
      if (lane == 0) {
        float sc = sqrtf(ss);
        u32 sb = __float_as_uint(sc);
        keys[r] = ((u64)sb << 32) | (u64)(0xFFFFFFFFu - (u32)r);
      }
    }
  }
}

// fused BN+ReLU+head matmul (Cout=64 -> 4)
__global__ void head_kernel(const float* __restrict__ H, const float* __restrict__ stats,
                            const float* __restrict__ g, const float* __restrict__ b,
                            const float* __restrict__ Wh, const float* __restrict__ bh,
                            int E, float* __restrict__ out)
{
  const int lane = threadIdx.x & 63;
  const int wid = threadIdx.x >> 6;
  const int wpb = blockDim.x >> 6;
  const float invE = 1.0f / (float)E;
  float m = stats[lane] * invE;
  float var = stats[64 + lane] * invE - m * m;
  float inv = rsqrtf(var + BN_EPS_F);
  float gg = g[lane], bb = b[lane];
  float4 w = *(const float4*)&Wh[lane * 4];
  float b0 = bh[0], b1 = bh[1], b2 = bh[2], b3 = bh[3];
  for (int r = (int)blockIdx.x * wpb + wid; r < E; r += (int)gridDim.x * wpb) {
    float v = H[(size_t)r * 64 + lane];
    float o = fmaxf((v - m) * inv * gg + bb, 0.f);
    float a0 = o * w.x, a1 = o * w.y, a2 = o * w.z, a3 = o * w.w;
    #pragma unroll
    for (int s = 32; s > 0; s >>= 1) {
      a0 += __shfl_xor(a0, s, 64);
      a1 += __shfl_xor(a1, s, 64);
      a2 += __shfl_xor(a2, s, 64);
      a3 += __shfl_xor(a3, s, 64);
    }
    if (lane == 0) {
      float4 ov = make_float4(a0 + b0, a1 + b1, a2 + b2, a3 + b3);
      *(float4*)&out[(size_t)r * 4] = ov;
    }
  }
}

// -------------------- pool-1 top-k (radix select on u64 keys) --------------
// fine bins only — coarse bins had catastrophic atomic contention (r5 lesson)
__global__ void hist_kernel(const u64* __restrict__ keys, int E, u32* __restrict__ hist)
{
  for (int i = (int)blockIdx.x * blockDim.x + threadIdx.x; i < E;
       i += (int)gridDim.x * blockDim.x) {
    u32 bin = (u32)(keys[i] >> 44);
    atomicAdd(&hist[bin], 1u);
  }
}

// parallel per-thread chunk sums (uint4 loads) + all-LDS serial scans
__global__ void scan_kernel(const u32* __restrict__ hist, int K, u32* __restrict__ sel)
{
  __shared__ u32 csum[1024];
  __shared__ u32 sb2[1024];
  __shared__ int selChunk;
  __shared__ u32 aboveChunk;
  const int tid = threadIdx.x;
  {
    const uint4* hp = (const uint4*)(hist + (size_t)tid * 1024);
    u32 s = 0;
    for (int i = 0; i < 256; i++) {
      uint4 v = hp[i];
      s += v.x + v.y + v.z + v.w;
    }
    csum[tid] = s;
  }
  __syncthreads();
  if (tid == 0) {
    u32 above = 0; int sc = 0; u32 ab = 0;
    for (int t = 1023; t >= 0; t--) {
      if (above + csum[t] >= (u32)K) { sc = t; ab = above; break; }
      above += csum[t];
    }
    selChunk = sc; aboveChunk = ab;
  }
  __syncthreads();
  sb2[tid] = hist[(size_t)selChunk * 1024 + tid];
  __syncthreads();
  if (tid == 0) {
    u32 above = aboveChunk; int sb = 0;
    for (int t = 1023; t >= 0; t--) {
      u32 c = sb2[t];
      if (above + c >= (u32)K) { sb = t; break; }
      above += c;
    }
    sel[0] = (u32)(selChunk * 1024 + sb);
    sel[1] = above;
    sel[2] = (u32)K - above;
  }
}

__global__ void collect_kernel(const u64* __restrict__ keys, int E, const u32* __restrict__ sel,
                               u64* __restrict__ cand, u32* __restrict__ count)
{
  u32 bin = sel[0];
  for (int i = (int)blockIdx.x * blockDim.x + threadIdx.x; i < E;
       i += (int)gridDim.x * blockDim.x) {
    if ((u32)(keys[i] >> 44) == bin) {
      u32 p = atomicAdd(count, 1u);
      if (p < (u32)CAND_CAP) cand[p] = keys[i];
    }
  }
}

__global__ void thresh_kernel(const u64* __restrict__ cand, const u32* __restrict__ count,
                              const u32* __restrict__ sel, u64* __restrict__ thr)
{
  __shared__ u64 sk[CAND_CAP];
  const int tid = threadIdx.x;
  const int nth = blockDim.x;
  int n = (int)(*count > (u32)CAND_CAP ? (u32)CAND_CAP : *count);
  int n2 = 2; while (n2 < n) n2 <<= 1;
  for (int i = tid; i < n2; i += nth) sk[i] = (i < n) ? cand[i] : 0ull;
  __syncthreads();
  for (int k = 2; k <= n2; k <<= 1)
    for (int j = k >> 1; j > 0; j >>= 1) {
      for (int i = tid; i < n2; i += nth) {
        int p = i ^ j;
        if (p > i) {
          u64 a = sk[i], bb = sk[p];
          bool up = ((i & k) == 0);
          bool sw = up ? (a < bb) : (a > bb);
          if (sw) { sk[i] = bb; sk[p] = a; }
        }
      }
      __syncthreads();
    }
  if (tid == 0) {
    int kr = (int)sel[2];
    thr[0] = sk[kr - 1];
  }
}

// -------------------- ordered compaction: count / scan / scatter -----------
__global__ void keep_count_kernel(const u64* __restrict__ keys, int E,
                                  const u64* __restrict__ thrp, u32* __restrict__ bcnt)
{
  const u64 thr = thrp[0];
  const int tid = threadIdx.x;
  int base = (int)blockIdx.x * 1024 + tid * 4;
  u32 c = 0;
  #pragma unroll
  for (int u = 0; u < 4; u++) {
    int i = base + u;
    if (i < E && keys[i] >= thr) c++;
  }
  __shared__ u32 sm[256];
  sm[tid] = c;
  __syncthreads();
  for (int s = 128; s > 0; s >>= 1) {
    if (tid < s) sm[tid] += sm[tid + s];
    __syncthreads();
  }
  if (tid == 0) bcnt[blockIdx.x] = sm[0];
}

__global__ void keep_scan_kernel(const u32* __restrict__ bcnt, int NB, u32* __restrict__ boffs)
{
  __shared__ u32 sm[256];
  const int tid = threadIdx.x;
  u32 v = (tid < NB) ? bcnt[tid] : 0;
  sm[tid] = v;
  __syncthreads();
  for (int off = 1; off < 256; off <<= 1) {
    u32 t = 0;
    if (tid >= off) t = sm[tid - off];
    __syncthreads();
    sm[tid] += t;
    __syncthreads();
  }
  if (tid < NB) boffs[tid] = sm[tid] - v;
}

__global__ void keep_scatter_kernel(const u64* __restrict__ keys, int E,
                                    const u64* __restrict__ thrp, const u32* __restrict__ boffs,
                                    int* __restrict__ keep, int K)
{
  const u64 thr = thrp[0];
  const int tid = threadIdx.x;
  int base = (int)blockIdx.x * 1024 + tid * 4;
  u32 f[4]; u32 c = 0;
  #pragma unroll
  for (int u = 0; u < 4; u++) {
    int i = base + u;
    f[u] = (i < E && keys[i] >= thr) ? 1u : 0u;
    c += f[u];
  }
  __shared__ u32 sm[256];
  sm[tid] = c;
  __syncthreads();
  for (int off = 1; off < 256; off <<= 1) {
    u32 t = 0;
    if (tid >= off) t = sm[tid - off];
    __syncthreads();
    sm[tid] += t;
    __syncthreads();
  }
  u32 pos = boffs[blockIdx.x] + sm[tid] - c;
  #pragma unroll
  for (int u = 0; u < 4; u++) {
    if (f[u]) {
      if (pos < (u32)K) keep[pos] = base + u;
      pos++;
    }
  }
}

// -------------------- pools 2/3: single-block full sort ---------------------
template<int NPOW>
__global__ void pool_select_kernel(const u64* __restrict__ keys, int E, int K,
                                   int* __restrict__ keep)
{
  __shared__ u64 sk[NPOW];
  __shared__ int si[NPOW];
  const int tid = threadIdx.x, nth = blockDim.x;
  for (int i = tid; i < NPOW; i += nth) sk[i] = (i < E) ? keys[i] : 0ull;
  __syncthreads();
  for (int k = 2; k <= NPOW; k <<= 1)
    for (int j = k >> 1; j > 0; j >>= 1) {
      for (int i = tid; i < NPOW; i += nth) {
        int p = i ^ j;
        if (p > i) {
          u64 a = sk[i], bb = sk[p];
          bool up = ((i & k) == 0);
          bool sw = up ? (a < bb) : (a > bb);
          if (sw) { sk[i] = bb; sk[p] = a; }
        }
      }
      __syncthreads();
    }
  for (int i = tid; i < NPOW; i += nth)
    si[i] = (i < K) ? (int)(0xFFFFFFFFu - (u32)(sk[i] & 0xFFFFFFFFull)) : 0x7FFFFFFF;
  __syncthreads();
  for (int k = 2; k <= NPOW; k <<= 1)
    for (int j = k >> 1; j > 0; j >>= 1) {
      for (int i = tid; i < NPOW; i += nth) {
        int p = i ^ j;
        if (p > i) {
          int a = si[i], bb = si[p];
          bool up = ((i & k) == 0);
          bool sw = up ? (a > bb) : (a < bb);
          if (sw) { si[i] = bb; si[p] = a; }
        }
      }
      __syncthreads();
    }
  for (int i = tid; i < K; i += nth) keep[i] = si[i];
}

template<int C>
__global__ void pool_finish_kernel(const float* __restrict__ Xsrc, const int* __restrict__ nb_src,
                                   const int* __restrict__ keep, int K, int Esrc,
                                   float* __restrict__ Xp, int* __restrict__ nbp)
{
  int total = K * C;
  for (int idx = (int)blockIdx.x * blockDim.x + threadIdx.x; idx < total;
       idx += (int)gridDim.x * blockDim.x) {
    int i = idx / C, c = idx % C;
    Xp[idx] = Xsrc[(size_t)keep[i] * C + c];
  }
  for (int idx = (int)blockIdx.x * blockDim.x + threadIdx.x; idx < K * 4;
       idx += (int)gridDim.x * blockDim.x) {
    int i = idx >> 2, j = idx & 3;
    int v = nb_src[(size_t)keep[i] * 4 + j];
    v = iclampi(v, 0, Esrc - 1);
    int p = bsearch_eq(keep, K, v);
    nbp[idx] = (p < 0) ? i : p;
  }
}

__global__ void unpool_cat_kernel(const float* __restrict__ Xc, const float* __restrict__ Xs,
                                  const int* __restrict__ keep, int K, int E,
                                  int Cc, int Cs, float* __restrict__ out)
{
  int Ct = Cc + Cs;
  int total = E * Ct;
  for (int idx = (int)blockIdx.x * blockDim.x + threadIdx.x; idx < total;
       idx += (int)gridDim.x * blockDim.x) {
    int r = idx / Ct, c = idx % Ct;
    float v;
    if (c < Cc) { int nn = nearest_keep(keep, K, r); v = Xc[(size_t)nn * Cc + c]; }
    else v = Xs[(size_t)r * Cs + (c - Cc)];
    out[idx] = v;
  }
}

__global__ void nn_map_kernel(const int* __restrict__ keep, int K, int E, int* __restrict__ nn)
{
  for (int i = (int)blockIdx.x * blockDim.x + threadIdx.x; i < E;
       i += (int)gridDim.x * blockDim.x)
    nn[i] = nearest_keep(keep, K, i);
}

// ---------------------------------------------------------------------------
extern "C" void kernel_launch(void* const* d_in, const int* in_sizes, int n_in,
                              void* d_out, int out_size, void* d_ws, size_t ws_size,
                              hipStream_t stream)
{
  (void)in_sizes; (void)n_in; (void)out_size; (void)ws_size;
  const float* x     = (const float*)d_in[0];
  const int*   nb    = (const int*)d_in[1];
  const float* W_e1  = (const float*)d_in[2];
  const float* g_e1  = (const float*)d_in[3];
  const float* b_e1  = (const float*)d_in[4];
  const float* W_e2  = (const float*)d_in[5];
  const float* g_e2  = (const float*)d_in[6];
  const float* b_e2  = (const float*)d_in[7];
  const float* W_e3  = (const float*)d_in[8];
  const float* g_e3  = (const float*)d_in[9];
  const float* b_e3  = (const float*)d_in[10];
  const float* W_e4  = (const float*)d_in[11];
  const float* g_e4  = (const float*)d_in[12];
  const float* b_e4  = (const float*)d_in[13];
  const float* W_d3  = (const float*)d_in[14];
  const float* g_d3  = (const float*)d_in[15];
  const float* b_d3  = (const float*)d_in[16];
  const float* W_d2  = (const float*)d_in[17];
  const float* g_d2  = (const float*)d_in[18];
  const float* b_d2  = (const float*)d_in[19];
  const float* W_d1  = (const float*)d_in[20];
  const float* g_d1  = (const float*)d_in[21];
  const float* b_d1  = (const float*)d_in[22];
  const float* W_head = (const float*)d_in[23];
  const float* bias_head = (const float*)d_in[24];
  float* out = (float*)d_out;

  char* p = (char*)d_ws;
  auto alloc = [&](size_t bytes) -> char* {
    char* q = p; p += (bytes + 255) & ~(size_t)255; return q;
  };

  // --- zero zone (one memset) ---
  char* zz = p;
  u32*   hist  = (u32*)alloc(sizeof(u32) * (1u << 20));
  float* stats = (float*)alloc(sizeof(float) * 2 * (64 + 128 + 256 + 512 + 256 + 128 + 64));
  u32*   ctrl  = (u32*)alloc(sizeof(u32) * 16);
  u64*   thr   = (u64*)alloc(sizeof(u64) * 2);
  u32*   sel   = (u32*)alloc(sizeof(u32) * 8);
  float* H2    = (float*)alloc(sizeof(float) * T1 * 128);   // split-K -> zeroed
  float* H3    = (float*)alloc(sizeof(float) * T2 * 256);
  float* H4    = (float*)alloc(sizeof(float) * T3 * 512);
  float* Hd3   = (float*)alloc(sizeof(float) * T2 * 256);
  float* Hd2   = (float*)alloc(sizeof(float) * T1 * 128);
  size_t zz_bytes = (size_t)(p - zz);
  // --- rest ---
  u32*   bcnt  = (u32*)alloc(sizeof(u32) * 256);
  u32*   boffs = (u32*)alloc(sizeof(u32) * 256);
  float* e1    = (float*)alloc(sizeof(float) * (size_t)E0 * 64);
  u64*   keys1 = (u64*)alloc(sizeof(u64) * E0);
  u64*   cand  = (u64*)alloc(sizeof(u64) * CAND_CAP);
  int*   keep1 = (int*)alloc(sizeof(int) * T1);
  float* e1p   = (float*)alloc(sizeof(float) * T1 * 64);
  int*   nb1   = (int*)alloc(sizeof(int) * T1 * 4);
  float* e2    = (float*)alloc(sizeof(float) * T1 * 128);
  u64*   keys2 = (u64*)alloc(sizeof(u64) * T1);
  int*   keep2 = (int*)alloc(sizeof(int) * T2);
  float* e2p   = (float*)alloc(sizeof(float) * T2 * 128);
  int*   nb2   = (int*)alloc(sizeof(int) * T2 * 4);
  float* e3    = (float*)alloc(sizeof(float) * T2 * 256);
  u64*   keys3 = (u64*)alloc(sizeof(u64) * T2);
  int*   keep3 = (int*)alloc(sizeof(int) * T3);
  float* e3p   = (float*)alloc(sizeof(float) * T3 * 256);
  int*   nb3   = (int*)alloc(sizeof(int) * T3 * 4);
  float* e4    = (float*)alloc(sizeof(float) * T3 * 512);
  float* d3cat = (float*)alloc(sizeof(float) * T2 * 768);
  float* d3    = (float*)alloc(sizeof(float) * T2 * 256);
  float* d2cat = (float*)alloc(sizeof(float) * T1 * 384);
  float* d2    = (float*)alloc(sizeof(float) * T1 * 128);
  int*   nn1   = (int*)alloc(sizeof(int) * E0);
  float* Hd1   = (float*)alloc(sizeof(float) * (size_t)E0 * 64);
  ushort_t* e1b = (ushort_t*)alloc(sizeof(ushort_t) * (size_t)E0 * 64);
  ushort_t* d2b = (ushort_t*)alloc(sizeof(ushort_t) * T1 * 128);
  ushort_t* Wt  = (ushort_t*)alloc(sizeof(ushort_t) * 5 * 64 * 192);

  float* s1  = stats;
  float* s2  = s1 + 2 * 64;
  float* s3  = s2 + 2 * 128;
  float* s4  = s3 + 2 * 256;
  float* sd3 = s4 + 2 * 512;
  float* sd2 = sd3 + 2 * 256;
  float* sd1 = sd2 + 2 * 128;

  hipMemsetAsync(zz, 0, zz_bytes, stream);
  prep_wd1_kernel<<<dim3(240), 256, 0, stream>>>(W_d1, Wt);

  // ---- encoder 1 (dedicated kernel, vectorized gathers, fused stats) ----
  e1_conv_kernel<<<dim3((E0 + 127) / 128), 256, 0, stream>>>(x, nb, W_e1, e1, s1);
  bn_kernel<64, true, true><<<dim3(8192), 256, 0, stream>>>(e1, s1, g_e1, b_e1, E0, e1, e1b, keys1);

  // ---- pool 1 (top-1500 of 200000) ----
  hist_kernel<<<dim3(782), 256, 0, stream>>>(keys1, E0, hist);
  scan_kernel<<<dim3(1), 1024, 0, stream>>>(hist, T1, sel);
  collect_kernel<<<dim3(782), 256, 0, stream>>>(keys1, E0, sel, cand, ctrl);
  thresh_kernel<<<dim3(1), 1024, 0, stream>>>(cand, ctrl, sel, thr);
  keep_count_kernel<<<dim3(NB_KEEP), 256, 0, stream>>>(keys1, E0, thr, bcnt);
  keep_scan_kernel<<<dim3(1), 256, 0, stream>>>(bcnt, NB_KEEP, boffs);
  keep_scatter_kernel<<<dim3(NB_KEEP), 256, 0, stream>>>(keys1, E0, thr, boffs, keep1, T1);
  pool_finish_kernel<64><<<dim3(380), 256, 0, stream>>>(e1, nb, keep1, T1, E0, e1p, nb1);

  // ---- encoder 2 (split-K=2) ----
  conv_kernel<64, 128, 32, 64, 8, 2, 4, 2, false>
      <<<dim3((T1 + 31) / 32, 128 / 64, 2), 256, 0, stream>>>(e1p, nb1, T1, W_e2, H2, nullptr);
  stats_kernel<<<dim3((T1 + 63) / 64), 256, 0, stream>>>(H2, T1, 128, s2);
  bn_kernel<128, true, false><<<dim3(512), 256, 0, stream>>>(H2, s2, g_e2, b_e2, T1, e2, nullptr, keys2);
  pool_select_kernel<2048><<<dim3(1), 256, 0, stream>>>(keys2, T1, T2, keep2);
  pool_finish_kernel<128><<<dim3(380), 256, 0, stream>>>(e2, nb1, keep2, T2, T1, e2p, nb2);

  // ---- encoder 3 (split-K=4) ----
  conv_kernel<128, 256, 32, 64, 8, 2, 4, 4, false>
      <<<dim3((T2 + 31) / 32, 256 / 64, 4), 256, 0, stream>>>(e2p, nb2, T2, W_e3, H3, nullptr);
  stats_kernel<<<dim3((T2 + 63) / 64), 256, 0, stream>>>(H3, T2, 256, s3);
  bn_kernel<256, true, false><<<dim3(256), 256, 0, stream>>>(H3, s3, g_e3, b_e3, T2, e3, nullptr, keys3);
  pool_select_kernel<1024><<<dim3(1), 256, 0, stream>>>(keys3, T2, T3, keep3);
  pool_finish_kernel<256><<<dim3(380), 256, 0, stream>>>(e3, nb2, keep3, T3, T2, e3p, nb3);

  // ---- encoder 4 (split-K=4) ----
  conv_kernel<256, 512, 32, 64, 8, 2, 4, 4, false>
      <<<dim3((T3 + 31) / 32, 512 / 64, 4), 256, 0, stream>>>(e3p, nb3, T3, W_e4, H4, nullptr);
  stats_kernel<<<dim3((T3 + 63) / 64), 256, 0, stream>>>(H4, T3, 512, s4);
  bn_kernel<512, false, false><<<dim3(128), 256, 0, stream>>>(H4, s4, g_e4, b_e4, T3, e4, nullptr, nullptr);

  // ---- decoder 3 (split-K=8) ----
  unpool_cat_kernel<<<dim3((T2 * 768 + 255) / 256), 256, 0, stream>>>(
      e4, e3, keep3, T3, T2, 512, 256, d3cat);
  conv_kernel<768, 256, 32, 64, 8, 2, 4, 8, false>
      <<<dim3((T2 + 31) / 32, 256 / 64, 8), 256, 0, stream>>>(d3cat, nb2, T2, W_d3, Hd3, nullptr);
  stats_kernel<<<dim3((T2 + 63) / 64), 256, 0, stream>>>(Hd3, T2, 256, sd3);
  bn_kernel<256, false, false><<<dim3(256), 256, 0, stream>>>(Hd3, sd3, g_d3, b_d3, T2, d3, nullptr, nullptr);

  // ---- decoder 2 (split-K=8) ----
  unpool_cat_kernel<<<dim3((T1 * 384 + 255) / 256), 256, 0, stream>>>(
      d3, e2, keep2, T2, T1, 256, 128, d2cat);
  conv_kernel<384, 128, 32, 64, 8, 2, 4, 8, false>
      <<<dim3((T1 + 31) / 32, 128 / 64, 8), 256, 0, stream>>>(d2cat, nb1, T1, W_d2, Hd2, nullptr);
  stats_kernel<<<dim3((T1 + 63) / 64), 256, 0, stream>>>(Hd2, T1, 128, sd2);
  bn_kernel<128, false, true><<<dim3(512), 256, 0, stream>>>(Hd2, sd2, g_d2, b_d2, T1, d2, d2b, nullptr);

  // ---- decoder 1 (bf16 MFMA conv, row-split waves) ----
  nn_map_kernel<<<dim3(782), 256, 0, stream>>>(keep1, T1, E0, nn1);
  d1_mfma_kernel<<<dim3((E0 + 127) / 128), 256, 0, stream>>>(d2b, e1b, nn1, nb, Wt, Hd1, sd1);

  // ---- head (fused BN+ReLU+matmul) ----
  head_kernel<<<dim3(8192), 256, 0, stream>>>(Hd1, sd1, g_d1, b_d1, W_head, bias_head, E0, out);
}

// Round 7
// 1138.856 us; speedup vs baseline: 2.2532x; 1.0482x over previous
//
#include <hip/hip_runtime.h>
#include <stdint.h>

typedef unsigned long long u64;
typedef unsigned int u32;
typedef unsigned short ushort_t;

#define FI __device__ __forceinline__

static constexpr float BN_EPS_F = 1e-5f;
static constexpr int E0 = 200000;
static constexpr int T1 = 1500, T2 = 750, T3 = 375;
static constexpr int CAND_CAP = 4096;
static constexpr int NB_KEEP = (E0 + 1023) / 1024;

typedef __attribute__((ext_vector_type(8))) short short8;
typedef __attribute__((ext_vector_type(4))) float f32x4;

FI int iclampi(int v, int lo, int hi) { return v < lo ? lo : (v > hi ? hi : v); }

FI ushort_t f2b(float f) {
  u32 u = __float_as_uint(f);
  u32 r = (u + 0x7FFFu + ((u >> 16) & 1u)) >> 16;
  return (ushort_t)r;
}

// bf16 >= 0 (post-ReLU) -> u16 order == numeric order
FI void u16minmax(const uint4& va, const uint4& vb, uint4& lo, uint4& hi) {
  const ushort_t* a = (const ushort_t*)&va;
  const ushort_t* b = (const ushort_t*)&vb;
  ushort_t* l = (ushort_t*)&lo;
  ushort_t* h = (ushort_t*)&hi;
  #pragma unroll
  for (int i = 0; i < 8; i++) {
    ushort_t x = a[i], y = b[i];
    l[i] = x < y ? x : y;
    h[i] = x < y ? y : x;
  }
}

FI int nearest_keep(const int* __restrict__ keep, int K, int idx) {
  int lo = 0, hi = K;
  while (lo < hi) { int mid = (lo + hi) >> 1; if (keep[mid] < idx) lo = mid + 1; else hi = mid; }
  int l = lo - 1; l = l < 0 ? 0 : (l > K - 1 ? K - 1 : l);
  int r = lo;     r = r < 0 ? 0 : (r > K - 1 ? K - 1 : r);
  int dl = idx - keep[l]; dl = dl < 0 ? -dl : dl;
  int dr = idx - keep[r]; dr = dr < 0 ? -dr : dr;
  return (dl <= dr) ? l : r;
}

FI int bsearch_eq(const int* __restrict__ keep, int K, int v) {
  int lo = 0, hi = K;
  while (lo < hi) { int mid = (lo + hi) >> 1; if (keep[mid] < v) lo = mid + 1; else hi = mid; }
  if (lo < K && keep[lo] == v) return lo;
  return -1;
}

// ---------------------------------------------------------------------------
// Generic fp32 mesh-conv (split-K) — still used for e2/e3 (pool-key layers).
// ---------------------------------------------------------------------------
template<int C, int Cout, int BR, int BC, int KT, int TR, int TC, int KSPLIT,
         bool FUSE_STATS>
__global__ __launch_bounds__((BR / TR) * (BC / TC))
void conv_kernel(const float* __restrict__ X,
                 const int* __restrict__ nb, int E,
                 const float* __restrict__ W,
                 float* __restrict__ H, float* __restrict__ stats)
{
  constexpr int NTH = (BR / TR) * (BC / TC);
  constexpr int VK = 5 * KT;
  constexpr int KC = C / KSPLIT;
  static_assert(KC % KT == 0, "KC % KT");

  const int row0 = blockIdx.x * BR;
  const int col0 = blockIdx.y * BC;
  const int c_begin = (KSPLIT > 1) ? (int)blockIdx.z * KC : 0;

  __shared__ float As[VK][BR];
  __shared__ float Bs[VK][BC];
  __shared__ int rowsS[5][BR];
  __shared__ float red[FUSE_STATS ? 2 * (BR / TR) * BC : 1];

  const int tid = threadIdx.x;

  for (int q = tid; q < BR; q += NTH) {
    int r = row0 + q;
    int rr[5];
    if (r < E) {
      rr[0] = r;
      #pragma unroll
      for (int j = 0; j < 4; j++) {
        int v = nb[(size_t)r * 4 + j];
        rr[1 + j] = iclampi(v, 0, E - 1);
      }
    } else {
      #pragma unroll
      for (int j = 0; j < 5; j++) rr[j] = -1;
    }
    #pragma unroll
    for (int j = 0; j < 5; j++) rowsS[j][q] = rr[j];
  }

  float acc[TR][TC];
  #pragma unroll
  for (int i = 0; i < TR; i++)
    #pragma unroll
    for (int j = 0; j < TC; j++) acc[i][j] = 0.f;

  const int tr = tid / (BC / TC);
  const int tc = tid % (BC / TC);
  const int rA = tr * TR;
  const int cB = tc * TC;

  for (int c0 = c_begin; c0 < c_begin + KC; c0 += KT) {
    __syncthreads();
    for (int q = tid; q < VK * (BC / 4); q += NTH) {
      int kk = q / (BC / 4);
      int c4 = q % (BC / 4);
      int p = kk / KT, t = kk % KT;
      float4 wv = *(const float4*)&W[(size_t)(p * C + c0 + t) * Cout + col0 + c4 * 4];
      *(float4*)&Bs[kk][c4 * 4] = wv;
    }
    for (int q = tid; q < BR * KT; q += NTH) {
      int t = q % KT, rq = q / KT;
      int c = c0 + t;
      float s0 = 0.f, a1 = 0.f, a2 = 0.f, a3 = 0.f, a4 = 0.f;
      if (rowsS[0][rq] >= 0) {
        float v0, v1, v2, v3;
        s0 = X[(size_t)rowsS[0][rq] * C + c];
        v0 = X[(size_t)rowsS[1][rq] * C + c];
        v1 = X[(size_t)rowsS[2][rq] * C + c];
        v2 = X[(size_t)rowsS[3][rq] * C + c];
        v3 = X[(size_t)rowsS[4][rq] * C + c];
        a1 = fminf(v0, v1); a2 = fmaxf(v0, v1);
        a3 = fminf(v2, v3); a4 = fmaxf(v2, v3);
      }
      As[0 * KT + t][rq] = s0;
      As[1 * KT + t][rq] = a1;
      As[2 * KT + t][rq] = a2;
      As[3 * KT + t][rq] = a3;
      As[4 * KT + t][rq] = a4;
    }
    __syncthreads();

    for (int kk = 0; kk < VK; kk++) {
      float a[TR], b[TC];
      #pragma unroll
      for (int i = 0; i < TR; i++) a[i] = As[kk][rA + i];
      #pragma unroll
      for (int j = 0; j < TC; j++) b[j] = Bs[kk][cB + j];
      #pragma unroll
      for (int i = 0; i < TR; i++)
        #pragma unroll
        for (int j = 0; j < TC; j++)
          acc[i][j] = fmaf(a[i], b[j], acc[i][j]);
    }
  }

  #pragma unroll
  for (int i = 0; i < TR; i++) {
    int r = row0 + rA + i;
    if (r < E) {
      if constexpr (KSPLIT > 1) {
        #pragma unroll
        for (int j = 0; j < TC; j++)
          atomicAdd(&H[(size_t)r * Cout + col0 + cB + j], acc[i][j]);
      } else {
        #pragma unroll
        for (int j = 0; j < TC; j += 4) {
          float4 v = make_float4(acc[i][j], acc[i][j + 1], acc[i][j + 2], acc[i][j + 3]);
          *(float4*)&H[(size_t)r * Cout + col0 + cB + j] = v;
        }
      }
    }
  }

  if constexpr (FUSE_STATS) {
    float s[TC], q2[TC];
    #pragma unroll
    for (int j = 0; j < TC; j++) { s[j] = 0.f; q2[j] = 0.f; }
    #pragma unroll
    for (int i = 0; i < TR; i++) {
      int r = row0 + rA + i;
      if (r < E) {
        #pragma unroll
        for (int j = 0; j < TC; j++) { float v = acc[i][j]; s[j] += v; q2[j] += v * v; }
      }
    }
    __syncthreads();
    float* redS = &red[0];
    float* redQ = &red[(BR / TR) * BC];
    #pragma unroll
    for (int j = 0; j < TC; j++) {
      redS[tr * BC + cB + j] = s[j];
      redQ[tr * BC + cB + j] = q2[j];
    }
    __syncthreads();
    for (int col = tid; col < BC; col += NTH) {
      float ts = 0.f, tq = 0.f;
      for (int g = 0; g < BR / TR; g++) { ts += redS[g * BC + col]; tq += redQ[g * BC + col]; }
      atomicAdd(&stats[col0 + col], ts);
      atomicAdd(&stats[Cout + col0 + col], tq);
    }
  }
}

// ---------------------------------------------------------------------------
// Dedicated e1 conv (C=5, Cout=64): vectorized row gathers, W in LDS, stats.
// ---------------------------------------------------------------------------
__global__ __launch_bounds__(256)
void e1_conv_kernel(const float* __restrict__ X, const int* __restrict__ nb,
                    const float* __restrict__ W,
                    float* __restrict__ H, float* __restrict__ stats)
{
  __shared__ float As[25][128];
  __shared__ float Bs[25][64];
  __shared__ float red[2 * 32 * 64];

  const int tid = threadIdx.x;
  const int row0 = (int)blockIdx.x * 128;

  if (tid < 128) {
    int r = row0 + tid; if (r > E0 - 1) r = E0 - 1;
    int rs[5];
    rs[0] = r;
    #pragma unroll
    for (int j = 0; j < 4; j++) rs[1 + j] = iclampi((int)nb[(size_t)r * 4 + j], 0, E0 - 1);
    float v[5][5];
    #pragma unroll
    for (int j = 0; j < 5; j++) {
      const float* src = &X[(size_t)rs[j] * 5];
      float4 a = *(const float4*)src;
      v[j][0] = a.x; v[j][1] = a.y; v[j][2] = a.z; v[j][3] = a.w;
      v[j][4] = src[4];
    }
    #pragma unroll
    for (int c = 0; c < 5; c++) {
      As[0 * 5 + c][tid] = v[0][c];
      As[1 * 5 + c][tid] = fminf(v[1][c], v[2][c]);
      As[2 * 5 + c][tid] = fmaxf(v[1][c], v[2][c]);
      As[3 * 5 + c][tid] = fminf(v[3][c], v[4][c]);
      As[4 * 5 + c][tid] = fmaxf(v[3][c], v[4][c]);
    }
  } else {
    for (int q = tid - 128; q < 25 * 16; q += 128) {
      int k = q / 16, c4 = q % 16;
      float4 wv = *(const float4*)&W[(size_t)k * 64 + c4 * 4];
      *(float4*)&Bs[k][c4 * 4] = wv;
    }
  }
  __syncthreads();

  const int tr = tid >> 3;
  const int tc = tid & 7;
  const int rA = tr * 4;
  const int cB = tc * 8;

  float acc[4][8];
  #pragma unroll
  for (int i = 0; i < 4; i++)
    #pragma unroll
    for (int j = 0; j < 8; j++) acc[i][j] = 0.f;

  for (int k = 0; k < 25; k++) {
    float a[4], b[8];
    #pragma unroll
    for (int i = 0; i < 4; i++) a[i] = As[k][rA + i];
    #pragma unroll
    for (int j = 0; j < 8; j++) b[j] = Bs[k][cB + j];
    #pragma unroll
    for (int i = 0; i < 4; i++)
      #pragma unroll
      for (int j = 0; j < 8; j++)
        acc[i][j] = fmaf(a[i], b[j], acc[i][j]);
  }

  float s[8], q2[8];
  #pragma unroll
  for (int j = 0; j < 8; j++) { s[j] = 0.f; q2[j] = 0.f; }
  #pragma unroll
  for (int i = 0; i < 4; i++) {
    int r = row0 + rA + i;
    if (r < E0) {
      #pragma unroll
      for (int j = 0; j < 8; j += 4) {
        float4 v = make_float4(acc[i][j], acc[i][j + 1], acc[i][j + 2], acc[i][j + 3]);
        *(float4*)&H[(size_t)r * 64 + cB + j] = v;
      }
      #pragma unroll
      for (int j = 0; j < 8; j++) { float v = acc[i][j]; s[j] += v; q2[j] += v * v; }
    }
  }
  __syncthreads();
  float* redS = &red[0];
  float* redQ = &red[32 * 64];
  #pragma unroll
  for (int j = 0; j < 8; j++) {
    redS[tr * 64 + cB + j] = s[j];
    redQ[tr * 64 + cB + j] = q2[j];
  }
  __syncthreads();
  for (int col = tid; col < 64; col += 256) {
    float ts = 0.f, tq = 0.f;
    for (int g = 0; g < 32; g++) { ts += redS[g * 64 + col]; tq += redQ[g * 64 + col]; }
    atomicAdd(&stats[col], ts);
    atomicAdd(&stats[64 + col], tq);
  }
}

// ---------------------------------------------------------------------------
// Generic bf16 MFMA mesh-conv for e4/d3/d2 (downstream of all pooling):
// 128 thr = 2 waves; wave = 16 rows x 64 cols; block = 32 rows x (col-block 64).
// Register-double-buffered A-gather pipeline across C/32 K-chunks.
// ---------------------------------------------------------------------------
template<int C, int Cout>
__global__ __launch_bounds__(128)
void mfma_conv_kernel(const ushort_t* __restrict__ src,
                      const int* __restrict__ nb, int E,
                      const ushort_t* __restrict__ Wt,
                      float* __restrict__ H, float* __restrict__ stats)
{
  constexpr int NCC = C / 32;
  __shared__ int rows[5][32];

  const int tid = threadIdx.x;
  const int lane = tid & 63;
  const int wv = tid >> 6;
  const int l15 = lane & 15;
  const int quad = lane >> 4;
  const int row0 = (int)blockIdx.x * 32;
  const int col0 = (int)blockIdx.y * 64;

  if (tid < 32) {
    int r = row0 + tid; if (r > E - 1) r = E - 1;
    rows[0][tid] = r;
    #pragma unroll
    for (int j = 0; j < 4; j++) rows[1 + j][tid] = iclampi(nb[(size_t)r * 4 + j], 0, E - 1);
  }
  __syncthreads();

  const int rr = wv * 16 + l15;
  int r5[5];
  #pragma unroll
  for (int j = 0; j < 5; j++) r5[j] = rows[j][rr];

  f32x4 acc[4];
  #pragma unroll
  for (int ni = 0; ni < 4; ni++) acc[ni] = (f32x4){0.f, 0.f, 0.f, 0.f};

  uint4 raw[2][5];
  auto loadcc = [&](int par, int cc2) {
    int cb = cc2 * 32 + quad * 8;
    #pragma unroll
    for (int j = 0; j < 5; j++)
      raw[par][j] = *(const uint4*)&src[(size_t)r5[j] * C + cb];
  };

  loadcc(0, 0);
  #pragma unroll
  for (int cc = 0; cc < NCC; cc++) {
    const int par = cc & 1;
    if (cc + 1 < NCC) loadcc(par ^ 1, cc + 1);
    short8 a[5];
    a[0] = *(short8*)&raw[par][0];
    {
      uint4 lo, hi;
      u16minmax(raw[par][1], raw[par][2], lo, hi);
      a[1] = *(short8*)&lo; a[2] = *(short8*)&hi;
    }
    {
      uint4 lo, hi;
      u16minmax(raw[par][3], raw[par][4], lo, hi);
      a[3] = *(short8*)&lo; a[4] = *(short8*)&hi;
    }
    #pragma unroll
    for (int p = 0; p < 5; p++) {
      #pragma unroll
      for (int ni = 0; ni < 4; ni++) {
        short8 bf = *(const short8*)&Wt[((size_t)(p * Cout + col0 + ni * 16 + l15)) * C + cc * 32 + quad * 8];
        acc[ni] = __builtin_amdgcn_mfma_f32_16x16x32_bf16(a[p], bf, acc[ni], 0, 0, 0);
      }
    }
  }

  float s[4] = {0.f, 0.f, 0.f, 0.f}, q[4] = {0.f, 0.f, 0.f, 0.f};
  #pragma unroll
  for (int reg = 0; reg < 4; reg++) {
    int r = row0 + wv * 16 + quad * 4 + reg;
    if (r < E) {
      #pragma unroll
      for (int ni = 0; ni < 4; ni++) {
        float v = acc[ni][reg];
        H[(size_t)r * Cout + col0 + ni * 16 + l15] = v;
        s[ni] += v; q[ni] += v * v;
      }
    }
  }
  #pragma unroll
  for (int ni = 0; ni < 4; ni++) {
    float ts = s[ni], tq = q[ni];
    ts += __shfl_xor(ts, 16); tq += __shfl_xor(tq, 16);
    ts += __shfl_xor(ts, 32); tq += __shfl_xor(tq, 32);
    if (quad == 0) {
      int col = col0 + ni * 16 + l15;
      atomicAdd(&stats[col], ts);
      atomicAdd(&stats[Cout + col], tq);
    }
  }
}

// ---------------------------------------------------------------------------
// d1 conv via bf16 MFMA, row-split waves + register-double-buffered pipeline.
// ---------------------------------------------------------------------------
__global__ __launch_bounds__(256, 2)
void d1_mfma_kernel(const ushort_t* __restrict__ d2b, const ushort_t* __restrict__ e1b,
                    const int* __restrict__ nn1, const int* __restrict__ nb,
                    const ushort_t* __restrict__ Wt,
                    float* __restrict__ H, float* __restrict__ stats)
{
  __shared__ int rowsD[5][128];
  __shared__ int rowsS[5][128];

  const int tid = threadIdx.x;
  const int lane = tid & 63;
  const int wv = tid >> 6;
  const int l15 = lane & 15;
  const int quad = lane >> 4;
  const int row0 = (int)blockIdx.x * 128;

  if (tid < 128) {
    int r = row0 + tid; if (r > E0 - 1) r = E0 - 1;
    int rs[5];
    rs[0] = r;
    #pragma unroll
    for (int j = 0; j < 4; j++) rs[1 + j] = iclampi((int)nb[(size_t)r * 4 + j], 0, E0 - 1);
    #pragma unroll
    for (int j = 0; j < 5; j++) { rowsS[j][tid] = rs[j]; rowsD[j][tid] = nn1[rs[j]]; }
  }
  __syncthreads();

  int rD[2][5], rS[2][5];
  #pragma unroll
  for (int mi = 0; mi < 2; mi++) {
    int rr = wv * 32 + mi * 16 + l15;
    #pragma unroll
    for (int j = 0; j < 5; j++) { rD[mi][j] = rowsD[j][rr]; rS[mi][j] = rowsS[j][rr]; }
  }

  f32x4 acc[2][4];
  #pragma unroll
  for (int mi = 0; mi < 2; mi++)
    #pragma unroll
    for (int ni = 0; ni < 4; ni++) acc[mi][ni] = (f32x4){0.f, 0.f, 0.f, 0.f};

  uint4 raw[2][2][5];
  auto loadcc = [&](int par, int cc2) {
    const bool fD = cc2 < 4;
    const ushort_t* s2 = fD ? d2b : e1b;
    const int st = fD ? 128 : 64;
    const int cb = (fD ? cc2 * 32 : (cc2 - 4) * 32) + quad * 8;
    #pragma unroll
    for (int mi = 0; mi < 2; mi++)
      #pragma unroll
      for (int j = 0; j < 5; j++) {
        int r = fD ? rD[mi][j] : rS[mi][j];
        raw[par][mi][j] = *(const uint4*)&s2[(size_t)r * st + cb];
      }
  };

  loadcc(0, 0);
  #pragma unroll
  for (int cc = 0; cc < 6; cc++) {
    const int par = cc & 1;
    if (cc + 1 < 6) loadcc(par ^ 1, cc + 1);
    short8 a[2][5];
    #pragma unroll
    for (int mi = 0; mi < 2; mi++) {
      a[mi][0] = *(short8*)&raw[par][mi][0];
      {
        uint4 lo, hi;
        u16minmax(raw[par][mi][1], raw[par][mi][2], lo, hi);
        a[mi][1] = *(short8*)&lo; a[mi][2] = *(short8*)&hi;
      }
      {
        uint4 lo, hi;
        u16minmax(raw[par][mi][3], raw[par][mi][4], lo, hi);
        a[mi][3] = *(short8*)&lo; a[mi][4] = *(short8*)&hi;
      }
    }
    #pragma unroll
    for (int p = 0; p < 5; p++) {
      short8 bf[4];
      #pragma unroll
      for (int ni = 0; ni < 4; ni++)
        bf[ni] = *(const short8*)&Wt[((size_t)(p * 64 + ni * 16 + l15)) * 192 + cc * 32 + quad * 8];
      #pragma unroll
      for (int mi = 0; mi < 2; mi++)
        #pragma unroll
        for (int ni = 0; ni < 4; ni++)
          acc[mi][ni] = __builtin_amdgcn_mfma_f32_16x16x32_bf16(a[mi][p], bf[ni], acc[mi][ni], 0, 0, 0);
    }
  }

  float s[4] = {0.f, 0.f, 0.f, 0.f}, q[4] = {0.f, 0.f, 0.f, 0.f};
  #pragma unroll
  for (int mi = 0; mi < 2; mi++) {
    #pragma unroll
    for (int reg = 0; reg < 4; reg++) {
      int r = row0 + wv * 32 + mi * 16 + quad * 4 + reg;
      if (r < E0) {
        #pragma unroll
        for (int ni = 0; ni < 4; ni++) {
          float v = acc[mi][ni][reg];
          H[(size_t)r * 64 + ni * 16 + l15] = v;
          s[ni] += v; q[ni] += v * v;
        }
      }
    }
  }
  #pragma unroll
  for (int ni = 0; ni < 4; ni++) {
    float ts = s[ni], tq = q[ni];
    ts += __shfl_xor(ts, 16); tq += __shfl_xor(tq, 16);
    ts += __shfl_xor(ts, 32); tq += __shfl_xor(tq, 32);
    if (quad == 0) {
      int col = ni * 16 + l15;
      atomicAdd(&stats[col], ts);
      atomicAdd(&stats[64 + col], tq);
    }
  }
}

// W (5C x Cout fp32) -> Wt bf16 [(p*Cout+n)][C]
template<int C, int Cout>
__global__ void prep_w_kernel(const float* __restrict__ W, ushort_t* __restrict__ Wt)
{
  int idx = (int)blockIdx.x * 256 + threadIdx.x;
  if (idx < 5 * C * Cout) {
    int n = idx % Cout;
    int k = idx / Cout;
    int p = k / C, c = k % C;
    Wt[((size_t)(p * Cout + n)) * C + c] = f2b(W[(size_t)k * Cout + n]);
  }
}

// column sum/sumsq for split-K layers
__global__ void stats_kernel(const float* __restrict__ H, int E, int Cout,
                             float* __restrict__ stats)
{
  const int RB = 64;
  int r0 = (int)blockIdx.x * RB;
  int rend = r0 + RB; if (rend > E) rend = E;
  for (int col = threadIdx.x; col < Cout; col += blockDim.x) {
    float s = 0.f, q = 0.f;
    for (int r = r0; r < rend; r++) { float v = H[(size_t)r * Cout + col]; s += v; q += v * v; }
    atomicAdd(&stats[col], s);
    atomicAdd(&stats[Cout + col], q);
  }
}

// BN(training stats) + ReLU; optional pooling key per row; optional bf16 copy
template<int Cout, bool KEYS, bool B16>
__global__ void bn_kernel(const float* __restrict__ H, const float* __restrict__ stats,
                          const float* __restrict__ g, const float* __restrict__ b,
                          int E, float* __restrict__ Out, ushort_t* __restrict__ Outb,
                          u64* __restrict__ keys)
{
  constexpr int CPL = Cout / 64;
  const int lane = threadIdx.x & 63;
  const int wid = threadIdx.x >> 6;
  const int wpb = blockDim.x >> 6;
  const float invE = 1.0f / (float)E;
  float mu[CPL], inv[CPL], gg[CPL], bb[CPL];
  #pragma unroll
  for (int u = 0; u < CPL; u++) {
    int c = lane + u * 64;
    float m = stats[c] * invE;
    float var = stats[Cout + c] * invE - m * m;
    mu[u] = m;
    inv[u] = rsqrtf(var + BN_EPS_F);
    gg[u] = g[c]; bb[u] = b[c];
  }
  for (int r = (int)blockIdx.x * wpb + wid; r < E; r += (int)gridDim.x * wpb) {
    float ss = 0.f;
    #pragma unroll
    for (int u = 0; u < CPL; u++) {
      int c = lane + u * 64;
      float v = H[(size_t)r * Cout + c];
      float o = (v - mu[u]) * inv[u] * gg[u] + bb[u];
      o = fmaxf(o, 0.f);
      Out[(size_t)r * Cout + c] = o;
      if constexpr (B16) Outb[(size_t)r * Cout + c] = f2b(o);
      ss += o * o;
    }
    if constexpr (KEYS) {
      #pragma unroll
      for (int s = 32; s > 0; s >>= 1) ss += __shfl_xor(ss, s, 64);
      if (lane == 0) {
        float sc = sqrtf(ss);
        u32 sb = __float_as_uint(sc);
        keys[r] = ((u64)sb << 32) | (u64)(0xFFFFFFFFu - (u32)r);
      }
    }
  }
}

// fused BN+ReLU+head matmul (Cout=64 -> 4)
__global__ void head_kernel(const float* __restrict__ H, const float* __restrict__ stats,
                            const float* __restrict__ g, const float* __restrict__ b,
                            const float* __restrict__ Wh, const float* __restrict__ bh,
                            int E, float* __restrict__ out)
{
  const int lane = threadIdx.x & 63;
  const int wid = threadIdx.x >> 6;
  const int wpb = blockDim.x >> 6;
  const float invE = 1.0f / (float)E;
  float m = stats[lane] * invE;
  float var = stats[64 + lane] * invE - m * m;
  float inv = rsqrtf(var + BN_EPS_F);
  float gg = g[lane], bb = b[lane];
  float4 w = *(const float4*)&Wh[lane * 4];
  float b0 = bh[0], b1 = bh[1], b2 = bh[2], b3 = bh[3];
  for (int r = (int)blockIdx.x * wpb + wid; r < E; r += (int)gridDim.x * wpb) {
    float v = H[(size_t)r * 64 + lane];
    float o = fmaxf((v - m) * inv * gg + bb, 0.f);
    float a0 = o * w.x, a1 = o * w.y, a2 = o * w.z, a3 = o * w.w;
    #pragma unroll
    for (int s = 32; s > 0; s >>= 1) {
      a0 += __shfl_xor(a0, s, 64);
      a1 += __shfl_xor(a1, s, 64);
      a2 += __shfl_xor(a2, s, 64);
      a3 += __shfl_xor(a3, s, 64);
    }
    if (lane == 0) {
      float4 ov = make_float4(a0 + b0, a1 + b1, a2 + b2, a3 + b3);
      *(float4*)&out[(size_t)r * 4] = ov;
    }
  }
}

// -------------------- pool-1 top-k (radix select on u64 keys) --------------
__global__ void hist_kernel(const u64* __restrict__ keys, int E, u32* __restrict__ hist)
{
  for (int i = (int)blockIdx.x * blockDim.x + threadIdx.x; i < E;
       i += (int)gridDim.x * blockDim.x) {
    u32 bin = (u32)(keys[i] >> 44);
    atomicAdd(&hist[bin], 1u);
  }
}

// parallel per-thread chunk sums (uint4 loads) + all-LDS serial scans
__global__ void scan_kernel(const u32* __restrict__ hist, int K, u32* __restrict__ sel)
{
  __shared__ u32 csum[1024];
  __shared__ u32 sb2[1024];
  __shared__ int selChunk;
  __shared__ u32 aboveChunk;
  const int tid = threadIdx.x;
  {
    const uint4* hp = (const uint4*)(hist + (size_t)tid * 1024);
    u32 s = 0;
    for (int i = 0; i < 256; i++) {
      uint4 v = hp[i];
      s += v.x + v.y + v.z + v.w;
    }
    csum[tid] = s;
  }
  __syncthreads();
  if (tid == 0) {
    u32 above = 0; int sc = 0; u32 ab = 0;
    for (int t = 1023; t >= 0; t--) {
      if (above + csum[t] >= (u32)K) { sc = t; ab = above; break; }
      above += csum[t];
    }
    selChunk = sc; aboveChunk = ab;
  }
  __syncthreads();
  sb2[tid] = hist[(size_t)selChunk * 1024 + tid];
  __syncthreads();
  if (tid == 0) {
    u32 above = aboveChunk; int sb = 0;
    for (int t = 1023; t >= 0; t--) {
      u32 c = sb2[t];
      if (above + c >= (u32)K) { sb = t; break; }
      above += c;
    }
    sel[0] = (u32)(selChunk * 1024 + sb);
    sel[1] = above;
    sel[2] = (u32)K - above;
  }
}

__global__ void collect_kernel(const u64* __restrict__ keys, int E, const u32* __restrict__ sel,
                               u64* __restrict__ cand, u32* __restrict__ count)
{
  u32 bin = sel[0];
  for (int i = (int)blockIdx.x * blockDim.x + threadIdx.x; i < E;
       i += (int)gridDim.x * blockDim.x) {
    if ((u32)(keys[i] >> 44) == bin) {
      u32 p = atomicAdd(count, 1u);
      if (p < (u32)CAND_CAP) cand[p] = keys[i];
    }
  }
}

__global__ void thresh_kernel(const u64* __restrict__ cand, const u32* __restrict__ count,
                              const u32* __restrict__ sel, u64* __restrict__ thr)
{
  __shared__ u64 sk[CAND_CAP];
  const int tid = threadIdx.x;
  const int nth = blockDim.x;
  int n = (int)(*count > (u32)CAND_CAP ? (u32)CAND_CAP : *count);
  int n2 = 2; while (n2 < n) n2 <<= 1;
  for (int i = tid; i < n2; i += nth) sk[i] = (i < n) ? cand[i] : 0ull;
  __syncthreads();
  for (int k = 2; k <= n2; k <<= 1)
    for (int j = k >> 1; j > 0; j >>= 1) {
      for (int i = tid; i < n2; i += nth) {
        int p = i ^ j;
        if (p > i) {
          u64 a = sk[i], bb = sk[p];
          bool up = ((i & k) == 0);
          bool sw = up ? (a < bb) : (a > bb);
          if (sw) { sk[i] = bb; sk[p] = a; }
        }
      }
      __syncthreads();
    }
  if (tid == 0) {
    int kr = (int)sel[2];
    thr[0] = sk[kr - 1];
  }
}

// -------------------- ordered compaction: count / scan / scatter -----------
__global__ void keep_count_kernel(const u64* __restrict__ keys, int E,
                                  const u64* __restrict__ thrp, u32* __restrict__ bcnt)
{
  const u64 thr = thrp[0];
  const int tid = threadIdx.x;
  int base = (int)blockIdx.x * 1024 + tid * 4;
  u32 c = 0;
  #pragma unroll
  for (int u = 0; u < 4; u++) {
    int i = base + u;
    if (i < E && keys[i] >= thr) c++;
  }
  __shared__ u32 sm[256];
  sm[tid] = c;
  __syncthreads();
  for (int s = 128; s > 0; s >>= 1) {
    if (tid < s) sm[tid] += sm[tid + s];
    __syncthreads();
  }
  if (tid == 0) bcnt[blockIdx.x] = sm[0];
}

__global__ void keep_scan_kernel(const u32* __restrict__ bcnt, int NB, u32* __restrict__ boffs)
{
  __shared__ u32 sm[256];
  const int tid = threadIdx.x;
  u32 v = (tid < NB) ? bcnt[tid] : 0;
  sm[tid] = v;
  __syncthreads();
  for (int off = 1; off < 256; off <<= 1) {
    u32 t = 0;
    if (tid >= off) t = sm[tid - off];
    __syncthreads();
    sm[tid] += t;
    __syncthreads();
  }
  if (tid < NB) boffs[tid] = sm[tid] - v;
}

__global__ void keep_scatter_kernel(const u64* __restrict__ keys, int E,
                                    const u64* __restrict__ thrp, const u32* __restrict__ boffs,
                                    int* __restrict__ keep, int K)
{
  const u64 thr = thrp[0];
  const int tid = threadIdx.x;
  int base = (int)blockIdx.x * 1024 + tid * 4;
  u32 f[4]; u32 c = 0;
  #pragma unroll
  for (int u = 0; u < 4; u++) {
    int i = base + u;
    f[u] = (i < E && keys[i] >= thr) ? 1u : 0u;
    c += f[u];
  }
  __shared__ u32 sm[256];
  sm[tid] = c;
  __syncthreads();
  for (int off = 1; off < 256; off <<= 1) {
    u32 t = 0;
    if (tid >= off) t = sm[tid - off];
    __syncthreads();
    sm[tid] += t;
    __syncthreads();
  }
  u32 pos = boffs[blockIdx.x] + sm[tid] - c;
  #pragma unroll
  for (int u = 0; u < 4; u++) {
    if (f[u]) {
      if (pos < (u32)K) keep[pos] = base + u;
      pos++;
    }
  }
}

// -------------------- pools 2/3: single-block full sort ---------------------
template<int NPOW>
__global__ void pool_select_kernel(const u64* __restrict__ keys, int E, int K,
                                   int* __restrict__ keep)
{
  __shared__ u64 sk[NPOW];
  __shared__ int si[NPOW];
  const int tid = threadIdx.x, nth = blockDim.x;
  for (int i = tid; i < NPOW; i += nth) sk[i] = (i < E) ? keys[i] : 0ull;
  __syncthreads();
  for (int k = 2; k <= NPOW; k <<= 1)
    for (int j = k >> 1; j > 0; j >>= 1) {
      for (int i = tid; i < NPOW; i += nth) {
        int p = i ^ j;
        if (p > i) {
          u64 a = sk[i], bb = sk[p];
          bool up = ((i & k) == 0);
          bool sw = up ? (a < bb) : (a > bb);
          if (sw) { sk[i] = bb; sk[p] = a; }
        }
      }
      __syncthreads();
    }
  for (int i = tid; i < NPOW; i += nth)
    si[i] = (i < K) ? (int)(0xFFFFFFFFu - (u32)(sk[i] & 0xFFFFFFFFull)) : 0x7FFFFFFF;
  __syncthreads();
  for (int k = 2; k <= NPOW; k <<= 1)
    for (int j = k >> 1; j > 0; j >>= 1) {
      for (int i = tid; i < NPOW; i += nth) {
        int p = i ^ j;
        if (p > i) {
          int a = si[i], bb = si[p];
          bool up = ((i & k) == 0);
          bool sw = up ? (a > bb) : (a < bb);
          if (sw) { si[i] = bb; si[p] = a; }
        }
      }
      __syncthreads();
    }
  for (int i = tid; i < K; i += nth) keep[i] = si[i];
}

template<int C, bool B16>
__global__ void pool_finish_kernel(const float* __restrict__ Xsrc, const int* __restrict__ nb_src,
                                   const int* __restrict__ keep, int K, int Esrc,
                                   float* __restrict__ Xp, ushort_t* __restrict__ Xpb,
                                   int* __restrict__ nbp)
{
  int total = K * C;
  for (int idx = (int)blockIdx.x * blockDim.x + threadIdx.x; idx < total;
       idx += (int)gridDim.x * blockDim.x) {
    int i = idx / C, c = idx % C;
    float v = Xsrc[(size_t)keep[i] * C + c];
    if constexpr (B16) Xpb[idx] = f2b(v);
    else Xp[idx] = v;
  }
  for (int idx = (int)blockIdx.x * blockDim.x + threadIdx.x; idx < K * 4;
       idx += (int)gridDim.x * blockDim.x) {
    int i = idx >> 2, j = idx & 3;
    int v = nb_src[(size_t)keep[i] * 4 + j];
    v = iclampi(v, 0, Esrc - 1);
    int p = bsearch_eq(keep, K, v);
    nbp[idx] = (p < 0) ? i : p;
  }
}

// unpool (nearest kept) + concat skip -> bf16 output
__global__ void unpool_cat_b16_kernel(const float* __restrict__ Xc, const float* __restrict__ Xs,
                                      const int* __restrict__ keep, int K, int E,
                                      int Cc, int Cs, ushort_t* __restrict__ out)
{
  int Ct = Cc + Cs;
  int total = E * Ct;
  for (int idx = (int)blockIdx.x * blockDim.x + threadIdx.x; idx < total;
       idx += (int)gridDim.x * blockDim.x) {
    int r = idx / Ct, c = idx % Ct;
    float v;
    if (c < Cc) { int nn = nearest_keep(keep, K, r); v = Xc[(size_t)nn * Cc + c]; }
    else v = Xs[(size_t)r * Cs + (c - Cc)];
    out[idx] = f2b(v);
  }
}

__global__ void nn_map_kernel(const int* __restrict__ keep, int K, int E, int* __restrict__ nn)
{
  for (int i = (int)blockIdx.x * blockDim.x + threadIdx.x; i < E;
       i += (int)gridDim.x * blockDim.x)
    nn[i] = nearest_keep(keep, K, i);
}

// ---------------------------------------------------------------------------
extern "C" void kernel_launch(void* const* d_in, const int* in_sizes, int n_in,
                              void* d_out, int out_size, void* d_ws, size_t ws_size,
                              hipStream_t stream)
{
  (void)in_sizes; (void)n_in; (void)out_size; (void)ws_size;
  const float* x     = (const float*)d_in[0];
  const int*   nb    = (const int*)d_in[1];
  const float* W_e1  = (const float*)d_in[2];
  const float* g_e1  = (const float*)d_in[3];
  const float* b_e1  = (const float*)d_in[4];
  const float* W_e2  = (const float*)d_in[5];
  const float* g_e2  = (const float*)d_in[6];
  const float* b_e2  = (const float*)d_in[7];
  const float* W_e3  = (const float*)d_in[8];
  const float* g_e3  = (const float*)d_in[9];
  const float* b_e3  = (const float*)d_in[10];
  const float* W_e4  = (const float*)d_in[11];
  const float* g_e4  = (const float*)d_in[12];
  const float* b_e4  = (const float*)d_in[13];
  const float* W_d3  = (const float*)d_in[14];
  const float* g_d3  = (const float*)d_in[15];
  const float* b_d3  = (const float*)d_in[16];
  const float* W_d2  = (const float*)d_in[17];
  const float* g_d2  = (const float*)d_in[18];
  const float* b_d2  = (const float*)d_in[19];
  const float* W_d1  = (const float*)d_in[20];
  const float* g_d1  = (const float*)d_in[21];
  const float* b_d1  = (const float*)d_in[22];
  const float* W_head = (const float*)d_in[23];
  const float* bias_head = (const float*)d_in[24];
  float* out = (float*)d_out;

  char* p = (char*)d_ws;
  auto alloc = [&](size_t bytes) -> char* {
    char* q = p; p += (bytes + 255) & ~(size_t)255; return q;
  };

  // --- zero zone (one memset) ---
  char* zz = p;
  u32*   hist  = (u32*)alloc(sizeof(u32) * (1u << 20));
  float* stats = (float*)alloc(sizeof(float) * 2 * (64 + 128 + 256 + 512 + 256 + 128 + 64));
  u32*   ctrl  = (u32*)alloc(sizeof(u32) * 16);
  u64*   thr   = (u64*)alloc(sizeof(u64) * 2);
  u32*   sel   = (u32*)alloc(sizeof(u32) * 8);
  float* H2    = (float*)alloc(sizeof(float) * T1 * 128);   // split-K -> zeroed
  float* H3    = (float*)alloc(sizeof(float) * T2 * 256);   // split-K -> zeroed
  size_t zz_bytes = (size_t)(p - zz);
  // --- rest ---
  float* H4    = (float*)alloc(sizeof(float) * T3 * 512);
  float* Hd3   = (float*)alloc(sizeof(float) * T2 * 256);
  float* Hd2   = (float*)alloc(sizeof(float) * T1 * 128);
  u32*   bcnt  = (u32*)alloc(sizeof(u32) * 256);
  u32*   boffs = (u32*)alloc(sizeof(u32) * 256);
  float* e1    = (float*)alloc(sizeof(float) * (size_t)E0 * 64);
  u64*   keys1 = (u64*)alloc(sizeof(u64) * E0);
  u64*   cand  = (u64*)alloc(sizeof(u64) * CAND_CAP);
  int*   keep1 = (int*)alloc(sizeof(int) * T1);
  float* e1p   = (float*)alloc(sizeof(float) * T1 * 64);
  int*   nb1   = (int*)alloc(sizeof(int) * T1 * 4);
  float* e2    = (float*)alloc(sizeof(float) * T1 * 128);
  u64*   keys2 = (u64*)alloc(sizeof(u64) * T1);
  int*   keep2 = (int*)alloc(sizeof(int) * T2);
  float* e2p   = (float*)alloc(sizeof(float) * T2 * 128);
  int*   nb2   = (int*)alloc(sizeof(int) * T2 * 4);
  float* e3    = (float*)alloc(sizeof(float) * T2 * 256);
  u64*   keys3 = (u64*)alloc(sizeof(u64) * T2);
  int*   keep3 = (int*)alloc(sizeof(int) * T3);
  ushort_t* e3pb = (ushort_t*)alloc(sizeof(ushort_t) * T3 * 256);
  int*   nb3   = (int*)alloc(sizeof(int) * T3 * 4);
  float* e4    = (float*)alloc(sizeof(float) * T3 * 512);
  ushort_t* d3catb = (ushort_t*)alloc(sizeof(ushort_t) * T2 * 768);
  float* d3    = (float*)alloc(sizeof(float) * T2 * 256);
  ushort_t* d2catb = (ushort_t*)alloc(sizeof(ushort_t) * T1 * 384);
  float* d2    = (float*)alloc(sizeof(float) * T1 * 128);
  int*   nn1   = (int*)alloc(sizeof(int) * E0);
  float* Hd1   = (float*)alloc(sizeof(float) * (size_t)E0 * 64);
  ushort_t* e1b = (ushort_t*)alloc(sizeof(ushort_t) * (size_t)E0 * 64);
  ushort_t* d2b = (ushort_t*)alloc(sizeof(ushort_t) * T1 * 128);
  ushort_t* Wt1 = (ushort_t*)alloc(sizeof(ushort_t) * 5 * 64 * 192);
  ushort_t* Wt4 = (ushort_t*)alloc(sizeof(ushort_t) * 5 * 512 * 256);
  ushort_t* Wtd3 = (ushort_t*)alloc(sizeof(ushort_t) * 5 * 256 * 768);
  ushort_t* Wtd2 = (ushort_t*)alloc(sizeof(ushort_t) * 5 * 128 * 384);

  float* s1  = stats;
  float* s2  = s1 + 2 * 64;
  float* s3  = s2 + 2 * 128;
  float* s4  = s3 + 2 * 256;
  float* sd3 = s4 + 2 * 512;
  float* sd2 = sd3 + 2 * 256;
  float* sd1 = sd2 + 2 * 128;

  hipMemsetAsync(zz, 0, zz_bytes, stream);
  prep_w_kernel<192, 64><<<dim3((5 * 192 * 64 + 255) / 256), 256, 0, stream>>>(W_d1, Wt1);
  prep_w_kernel<256, 512><<<dim3((5 * 256 * 512 + 255) / 256), 256, 0, stream>>>(W_e4, Wt4);
  prep_w_kernel<768, 256><<<dim3((5 * 768 * 256 + 255) / 256), 256, 0, stream>>>(W_d3, Wtd3);
  prep_w_kernel<384, 128><<<dim3((5 * 384 * 128 + 255) / 256), 256, 0, stream>>>(W_d2, Wtd2);

  // ---- encoder 1 (fp32, pool-key-critical) ----
  e1_conv_kernel<<<dim3((E0 + 127) / 128), 256, 0, stream>>>(x, nb, W_e1, e1, s1);
  bn_kernel<64, true, true><<<dim3(8192), 256, 0, stream>>>(e1, s1, g_e1, b_e1, E0, e1, e1b, keys1);

  // ---- pool 1 (top-1500 of 200000) ----
  hist_kernel<<<dim3(782), 256, 0, stream>>>(keys1, E0, hist);
  scan_kernel<<<dim3(1), 1024, 0, stream>>>(hist, T1, sel);
  collect_kernel<<<dim3(782), 256, 0, stream>>>(keys1, E0, sel, cand, ctrl);
  thresh_kernel<<<dim3(1), 1024, 0, stream>>>(cand, ctrl, sel, thr);
  keep_count_kernel<<<dim3(NB_KEEP), 256, 0, stream>>>(keys1, E0, thr, bcnt);
  keep_scan_kernel<<<dim3(1), 256, 0, stream>>>(bcnt, NB_KEEP, boffs);
  keep_scatter_kernel<<<dim3(NB_KEEP), 256, 0, stream>>>(keys1, E0, thr, boffs, keep1, T1);
  pool_finish_kernel<64, false><<<dim3(380), 256, 0, stream>>>(e1, nb, keep1, T1, E0, e1p, nullptr, nb1);

  // ---- encoder 2 (fp32 split-K=2, pool-key-critical) ----
  conv_kernel<64, 128, 32, 64, 8, 2, 4, 2, false>
      <<<dim3((T1 + 31) / 32, 128 / 64, 2), 256, 0, stream>>>(e1p, nb1, T1, W_e2, H2, nullptr);
  stats_kernel<<<dim3((T1 + 63) / 64), 256, 0, stream>>>(H2, T1, 128, s2);
  bn_kernel<128, true, false><<<dim3(512), 256, 0, stream>>>(H2, s2, g_e2, b_e2, T1, e2, nullptr, keys2);
  pool_select_kernel<2048><<<dim3(1), 256, 0, stream>>>(keys2, T1, T2, keep2);
  pool_finish_kernel<128, false><<<dim3(380), 256, 0, stream>>>(e2, nb1, keep2, T2, T1, e2p, nullptr, nb2);

  // ---- encoder 3 (fp32 split-K=4, pool-key-critical) ----
  conv_kernel<128, 256, 32, 64, 8, 2, 4, 4, false>
      <<<dim3((T2 + 31) / 32, 256 / 64, 4), 256, 0, stream>>>(e2p, nb2, T2, W_e3, H3, nullptr);
  stats_kernel<<<dim3((T2 + 63) / 64), 256, 0, stream>>>(H3, T2, 256, s3);
  bn_kernel<256, true, false><<<dim3(256), 256, 0, stream>>>(H3, s3, g_e3, b_e3, T2, e3, nullptr, keys3);
  pool_select_kernel<1024><<<dim3(1), 256, 0, stream>>>(keys3, T2, T3, keep3);
  pool_finish_kernel<256, true><<<dim3(380), 256, 0, stream>>>(e3, nb2, keep3, T3, T2, nullptr, e3pb, nb3);

  // ---- encoder 4 (bf16 MFMA, downstream of all pooling) ----
  mfma_conv_kernel<256, 512><<<dim3((T3 + 31) / 32, 512 / 64), 128, 0, stream>>>(
      e3pb, nb3, T3, Wt4, H4, s4);
  bn_kernel<512, false, false><<<dim3(128), 256, 0, stream>>>(H4, s4, g_e4, b_e4, T3, e4, nullptr, nullptr);

  // ---- decoder 3 (bf16 MFMA) ----
  unpool_cat_b16_kernel<<<dim3((T2 * 768 + 255) / 256), 256, 0, stream>>>(
      e4, e3, keep3, T3, T2, 512, 256, d3catb);
  mfma_conv_kernel<768, 256><<<dim3((T2 + 31) / 32, 256 / 64), 128, 0, stream>>>(
      d3catb, nb2, T2, Wtd3, Hd3, sd3);
  bn_kernel<256, false, false><<<dim3(256), 256, 0, stream>>>(Hd3, sd3, g_d3, b_d3, T2, d3, nullptr, nullptr);

  // ---- decoder 2 (bf16 MFMA) ----
  unpool_cat_b16_kernel<<<dim3((T1 * 384 + 255) / 256), 256, 0, stream>>>(
      d3, e2, keep2, T2, T1, 256, 128, d2catb);
  mfma_conv_kernel<384, 128><<<dim3((T1 + 31) / 32, 128 / 64), 128, 0, stream>>>(
      d2catb, nb1, T1, Wtd2, Hd2, sd2);
  bn_kernel<128, false, true><<<dim3(512), 256, 0, stream>>>(Hd2, sd2, g_d2, b_d2, T1, d2, d2b, nullptr);

  // ---- decoder 1 (bf16 MFMA, pipelined gathers) ----
  nn_map_kernel<<<dim3(782), 256, 0, stream>>>(keep1, T1, E0, nn1);
  d1_mfma_kernel<<<dim3((E0 + 127) / 128), 256, 0, stream>>>(d2b, e1b, nn1, nb, Wt1, Hd1, sd1);

  // ---- head (fused BN+ReLU+matmul) ----
  head_kernel<<<dim3(8192), 256, 0, stream>>>(Hd1, sd1, g_d1, b_d1, W_head, bias_head, E0, out);
}

// Round 9
// 1111.208 us; speedup vs baseline: 2.3093x; 1.0249x over previous
//
#include <hip/hip_runtime.h>
#include <stdint.h>

typedef unsigned long long u64;
typedef unsigned int u32;
typedef unsigned short ushort_t;

#define FI __device__ __forceinline__

static constexpr float BN_EPS_F = 1e-5f;
static constexpr int E0 = 200000;
static constexpr int T1 = 1500, T2 = 750, T3 = 375;
static constexpr int CAND_CAP = 4096;
static constexpr int NB_KEEP = (E0 + 1023) / 1024;

typedef __attribute__((ext_vector_type(8))) short short8;
typedef __attribute__((ext_vector_type(4))) float f32x4;

FI int iclampi(int v, int lo, int hi) { return v < lo ? lo : (v > hi ? hi : v); }

FI ushort_t f2b(float f) {
  u32 u = __float_as_uint(f);
  u32 r = (u + 0x7FFFu + ((u >> 16) & 1u)) >> 16;
  return (ushort_t)r;
}

// bf16 >= 0 (post-ReLU) -> u16 order == numeric order
FI void u16minmax(const uint4& va, const uint4& vb, uint4& lo, uint4& hi) {
  const ushort_t* a = (const ushort_t*)&va;
  const ushort_t* b = (const ushort_t*)&vb;
  ushort_t* l = (ushort_t*)&lo;
  ushort_t* h = (ushort_t*)&hi;
  #pragma unroll
  for (int i = 0; i < 8; i++) {
    ushort_t x = a[i], y = b[i];
    l[i] = x < y ? x : y;
    h[i] = x < y ? y : x;
  }
}

FI int nearest_keep(const int* __restrict__ keep, int K, int idx) {
  int lo = 0, hi = K;
  while (lo < hi) { int mid = (lo + hi) >> 1; if (keep[mid] < idx) lo = mid + 1; else hi = mid; }
  int l = lo - 1; l = l < 0 ? 0 : (l > K - 1 ? K - 1 : l);
  int r = lo;     r = r < 0 ? 0 : (r > K - 1 ? K - 1 : r);
  int dl = idx - keep[l]; dl = dl < 0 ? -dl : dl;
  int dr = idx - keep[r]; dr = dr < 0 ? -dr : dr;
  return (dl <= dr) ? l : r;
}

FI int bsearch_eq(const int* __restrict__ keep, int K, int v) {
  int lo = 0, hi = K;
  while (lo < hi) { int mid = (lo + hi) >> 1; if (keep[mid] < v) lo = mid + 1; else hi = mid; }
  if (lo < K && keep[lo] == v) return lo;
  return -1;
}

// ---------------------------------------------------------------------------
// Generic fp32 mesh-conv (split-K) — e2/e3 (pool-key layers).
// ---------------------------------------------------------------------------
template<int C, int Cout, int BR, int BC, int KT, int TR, int TC, int KSPLIT,
         bool FUSE_STATS>
__global__ __launch_bounds__((BR / TR) * (BC / TC))
void conv_kernel(const float* __restrict__ X,
                 const int* __restrict__ nb, int E,
                 const float* __restrict__ W,
                 float* __restrict__ H, float* __restrict__ stats)
{
  constexpr int NTH = (BR / TR) * (BC / TC);
  constexpr int VK = 5 * KT;
  constexpr int KC = C / KSPLIT;
  static_assert(KC % KT == 0, "KC % KT");

  const int row0 = blockIdx.x * BR;
  const int col0 = blockIdx.y * BC;
  const int c_begin = (KSPLIT > 1) ? (int)blockIdx.z * KC : 0;

  __shared__ float As[VK][BR];
  __shared__ float Bs[VK][BC];
  __shared__ int rowsS[5][BR];
  __shared__ float red[FUSE_STATS ? 2 * (BR / TR) * BC : 1];

  const int tid = threadIdx.x;

  for (int q = tid; q < BR; q += NTH) {
    int r = row0 + q;
    int rr[5];
    if (r < E) {
      rr[0] = r;
      #pragma unroll
      for (int j = 0; j < 4; j++) {
        int v = nb[(size_t)r * 4 + j];
        rr[1 + j] = iclampi(v, 0, E - 1);
      }
    } else {
      #pragma unroll
      for (int j = 0; j < 5; j++) rr[j] = -1;
    }
    #pragma unroll
    for (int j = 0; j < 5; j++) rowsS[j][q] = rr[j];
  }

  float acc[TR][TC];
  #pragma unroll
  for (int i = 0; i < TR; i++)
    #pragma unroll
    for (int j = 0; j < TC; j++) acc[i][j] = 0.f;

  const int tr = tid / (BC / TC);
  const int tc = tid % (BC / TC);
  const int rA = tr * TR;
  const int cB = tc * TC;

  for (int c0 = c_begin; c0 < c_begin + KC; c0 += KT) {
    __syncthreads();
    for (int q = tid; q < VK * (BC / 4); q += NTH) {
      int kk = q / (BC / 4);
      int c4 = q % (BC / 4);
      int p = kk / KT, t = kk % KT;
      float4 wv = *(const float4*)&W[(size_t)(p * C + c0 + t) * Cout + col0 + c4 * 4];
      *(float4*)&Bs[kk][c4 * 4] = wv;
    }
    for (int q = tid; q < BR * KT; q += NTH) {
      int t = q % KT, rq = q / KT;
      int c = c0 + t;
      float s0 = 0.f, a1 = 0.f, a2 = 0.f, a3 = 0.f, a4 = 0.f;
      if (rowsS[0][rq] >= 0) {
        float v0, v1, v2, v3;
        s0 = X[(size_t)rowsS[0][rq] * C + c];
        v0 = X[(size_t)rowsS[1][rq] * C + c];
        v1 = X[(size_t)rowsS[2][rq] * C + c];
        v2 = X[(size_t)rowsS[3][rq] * C + c];
        v3 = X[(size_t)rowsS[4][rq] * C + c];
        a1 = fminf(v0, v1); a2 = fmaxf(v0, v1);
        a3 = fminf(v2, v3); a4 = fmaxf(v2, v3);
      }
      As[0 * KT + t][rq] = s0;
      As[1 * KT + t][rq] = a1;
      As[2 * KT + t][rq] = a2;
      As[3 * KT + t][rq] = a3;
      As[4 * KT + t][rq] = a4;
    }
    __syncthreads();

    for (int kk = 0; kk < VK; kk++) {
      float a[TR], b[TC];
      #pragma unroll
      for (int i = 0; i < TR; i++) a[i] = As[kk][rA + i];
      #pragma unroll
      for (int j = 0; j < TC; j++) b[j] = Bs[kk][cB + j];
      #pragma unroll
      for (int i = 0; i < TR; i++)
        #pragma unroll
        for (int j = 0; j < TC; j++)
          acc[i][j] = fmaf(a[i], b[j], acc[i][j]);
    }
  }

  #pragma unroll
  for (int i = 0; i < TR; i++) {
    int r = row0 + rA + i;
    if (r < E) {
      if constexpr (KSPLIT > 1) {
        #pragma unroll
        for (int j = 0; j < TC; j++)
          atomicAdd(&H[(size_t)r * Cout + col0 + cB + j], acc[i][j]);
      } else {
        #pragma unroll
        for (int j = 0; j < TC; j += 4) {
          float4 v = make_float4(acc[i][j], acc[i][j + 1], acc[i][j + 2], acc[i][j + 3]);
          *(float4*)&H[(size_t)r * Cout + col0 + cB + j] = v;
        }
      }
    }
  }

  if constexpr (FUSE_STATS) {
    float s[TC], q2[TC];
    #pragma unroll
    for (int j = 0; j < TC; j++) { s[j] = 0.f; q2[j] = 0.f; }
    #pragma unroll
    for (int i = 0; i < TR; i++) {
      int r = row0 + rA + i;
      if (r < E) {
        #pragma unroll
        for (int j = 0; j < TC; j++) { float v = acc[i][j]; s[j] += v; q2[j] += v * v; }
      }
    }
    __syncthreads();
    float* redS = &red[0];
    float* redQ = &red[(BR / TR) * BC];
    #pragma unroll
    for (int j = 0; j < TC; j++) {
      redS[tr * BC + cB + j] = s[j];
      redQ[tr * BC + cB + j] = q2[j];
    }
    __syncthreads();
    for (int col = tid; col < BC; col += NTH) {
      float ts = 0.f, tq = 0.f;
      for (int g = 0; g < BR / TR; g++) { ts += redS[g * BC + col]; tq += redQ[g * BC + col]; }
      atomicAdd(&stats[col0 + col], ts);
      atomicAdd(&stats[Cout + col0 + col], tq);
    }
  }
}

// ---------------------------------------------------------------------------
// Dedicated e1 conv (C=5, Cout=64): vectorized row gathers, W in LDS, stats.
// ---------------------------------------------------------------------------
__global__ __launch_bounds__(256)
void e1_conv_kernel(const float* __restrict__ X, const int* __restrict__ nb,
                    const float* __restrict__ W,
                    float* __restrict__ H, float* __restrict__ stats)
{
  __shared__ float As[25][128];
  __shared__ float Bs[25][64];
  __shared__ float red[2 * 32 * 64];

  const int tid = threadIdx.x;
  const int row0 = (int)blockIdx.x * 128;

  if (tid < 128) {
    int r = row0 + tid; if (r > E0 - 1) r = E0 - 1;
    int rs[5];
    rs[0] = r;
    #pragma unroll
    for (int j = 0; j < 4; j++) rs[1 + j] = iclampi((int)nb[(size_t)r * 4 + j], 0, E0 - 1);
    float v[5][5];
    #pragma unroll
    for (int j = 0; j < 5; j++) {
      const float* src = &X[(size_t)rs[j] * 5];
      float4 a = *(const float4*)src;
      v[j][0] = a.x; v[j][1] = a.y; v[j][2] = a.z; v[j][3] = a.w;
      v[j][4] = src[4];
    }
    #pragma unroll
    for (int c = 0; c < 5; c++) {
      As[0 * 5 + c][tid] = v[0][c];
      As[1 * 5 + c][tid] = fminf(v[1][c], v[2][c]);
      As[2 * 5 + c][tid] = fmaxf(v[1][c], v[2][c]);
      As[3 * 5 + c][tid] = fminf(v[3][c], v[4][c]);
      As[4 * 5 + c][tid] = fmaxf(v[3][c], v[4][c]);
    }
  } else {
    for (int q = tid - 128; q < 25 * 16; q += 128) {
      int k = q / 16, c4 = q % 16;
      float4 wv = *(const float4*)&W[(size_t)k * 64 + c4 * 4];
      *(float4*)&Bs[k][c4 * 4] = wv;
    }
  }
  __syncthreads();

  const int tr = tid >> 3;
  const int tc = tid & 7;
  const int rA = tr * 4;
  const int cB = tc * 8;

  float acc[4][8];
  #pragma unroll
  for (int i = 0; i < 4; i++)
    #pragma unroll
    for (int j = 0; j < 8; j++) acc[i][j] = 0.f;

  for (int k = 0; k < 25; k++) {
    float a[4], b[8];
    #pragma unroll
    for (int i = 0; i < 4; i++) a[i] = As[k][rA + i];
    #pragma unroll
    for (int j = 0; j < 8; j++) b[j] = Bs[k][cB + j];
    #pragma unroll
    for (int i = 0; i < 4; i++)
      #pragma unroll
      for (int j = 0; j < 8; j++)
        acc[i][j] = fmaf(a[i], b[j], acc[i][j]);
  }

  float s[8], q2[8];
  #pragma unroll
  for (int j = 0; j < 8; j++) { s[j] = 0.f; q2[j] = 0.f; }
  #pragma unroll
  for (int i = 0; i < 4; i++) {
    int r = row0 + rA + i;
    if (r < E0) {
      #pragma unroll
      for (int j = 0; j < 8; j += 4) {
        float4 v = make_float4(acc[i][j], acc[i][j + 1], acc[i][j + 2], acc[i][j + 3]);
        *(float4*)&H[(size_t)r * 64 + cB + j] = v;
      }
      #pragma unroll
      for (int j = 0; j < 8; j++) { float v = acc[i][j]; s[j] += v; q2[j] += v * v; }
    }
  }
  __syncthreads();
  float* redS = &red[0];
  float* redQ = &red[32 * 64];
  #pragma unroll
  for (int j = 0; j < 8; j++) {
    redS[tr * 64 + cB + j] = s[j];
    redQ[tr * 64 + cB + j] = q2[j];
  }
  __syncthreads();
  for (int col = tid; col < 64; col += 256) {
    float ts = 0.f, tq = 0.f;
    for (int g = 0; g < 32; g++) { ts += redS[g * 64 + col]; tq += redQ[g * 64 + col]; }
    atomicAdd(&stats[col], ts);
    atomicAdd(&stats[64 + col], tq);
  }
}

// ---------------------------------------------------------------------------
// Generic bf16 MFMA mesh-conv for e4/d3/d2 (downstream of all pooling).
// ---------------------------------------------------------------------------
template<int C, int Cout>
__global__ __launch_bounds__(128)
void mfma_conv_kernel(const ushort_t* __restrict__ src,
                      const int* __restrict__ nb, int E,
                      const ushort_t* __restrict__ Wt,
                      float* __restrict__ H, float* __restrict__ stats)
{
  constexpr int NCC = C / 32;
  __shared__ int rows[5][32];

  const int tid = threadIdx.x;
  const int lane = tid & 63;
  const int wv = tid >> 6;
  const int l15 = lane & 15;
  const int quad = lane >> 4;
  const int row0 = (int)blockIdx.x * 32;
  const int col0 = (int)blockIdx.y * 64;

  if (tid < 32) {
    int r = row0 + tid; if (r > E - 1) r = E - 1;
    rows[0][tid] = r;
    #pragma unroll
    for (int j = 0; j < 4; j++) rows[1 + j][tid] = iclampi(nb[(size_t)r * 4 + j], 0, E - 1);
  }
  __syncthreads();

  const int rr = wv * 16 + l15;
  int r5[5];
  #pragma unroll
  for (int j = 0; j < 5; j++) r5[j] = rows[j][rr];

  f32x4 acc[4];
  #pragma unroll
  for (int ni = 0; ni < 4; ni++) acc[ni] = (f32x4){0.f, 0.f, 0.f, 0.f};

  uint4 raw[2][5];
  auto loadcc = [&](int par, int cc2) {
    int cb = cc2 * 32 + quad * 8;
    #pragma unroll
    for (int j = 0; j < 5; j++)
      raw[par][j] = *(const uint4*)&src[(size_t)r5[j] * C + cb];
  };

  loadcc(0, 0);
  #pragma unroll
  for (int cc = 0; cc < NCC; cc++) {
    const int par = cc & 1;
    if (cc + 1 < NCC) loadcc(par ^ 1, cc + 1);
    short8 a[5];
    a[0] = *(short8*)&raw[par][0];
    {
      uint4 lo, hi;
      u16minmax(raw[par][1], raw[par][2], lo, hi);
      a[1] = *(short8*)&lo; a[2] = *(short8*)&hi;
    }
    {
      uint4 lo, hi;
      u16minmax(raw[par][3], raw[par][4], lo, hi);
      a[3] = *(short8*)&lo; a[4] = *(short8*)&hi;
    }
    #pragma unroll
    for (int p = 0; p < 5; p++) {
      #pragma unroll
      for (int ni = 0; ni < 4; ni++) {
        short8 bf = *(const short8*)&Wt[((size_t)(p * Cout + col0 + ni * 16 + l15)) * C + cc * 32 + quad * 8];
        acc[ni] = __builtin_amdgcn_mfma_f32_16x16x32_bf16(a[p], bf, acc[ni], 0, 0, 0);
      }
    }
  }

  float s[4] = {0.f, 0.f, 0.f, 0.f}, q[4] = {0.f, 0.f, 0.f, 0.f};
  #pragma unroll
  for (int reg = 0; reg < 4; reg++) {
    int r = row0 + wv * 16 + quad * 4 + reg;
    if (r < E) {
      #pragma unroll
      for (int ni = 0; ni < 4; ni++) {
        float v = acc[ni][reg];
        H[(size_t)r * Cout + col0 + ni * 16 + l15] = v;
        s[ni] += v; q[ni] += v * v;
      }
    }
  }
  #pragma unroll
  for (int ni = 0; ni < 4; ni++) {
    float ts = s[ni], tq = q[ni];
    ts += __shfl_xor(ts, 16); tq += __shfl_xor(tq, 16);
    ts += __shfl_xor(ts, 32); tq += __shfl_xor(tq, 32);
    if (quad == 0) {
      int col = col0 + ni * 16 + l15;
      atomicAdd(&stats[col], ts);
      atomicAdd(&stats[Cout + col], tq);
    }
  }
}

// ---------------------------------------------------------------------------
// d1 conv via bf16 MFMA — r4 col-split variant (fastest measured: 208 us).
// 256 thr = 4 waves; 128 rows x 64 cols; wave w owns cols [16w,16w+16).
// Per-lane 16B gathers land directly in MFMA A-fragment layout; redundant
// issue across waves maximizes requests in flight (latency-bound regime).
// ---------------------------------------------------------------------------
__global__ __launch_bounds__(256, 4)
void d1_mfma_kernel(const ushort_t* __restrict__ d2b, const ushort_t* __restrict__ e1b,
                    const int* __restrict__ nn1, const int* __restrict__ nb,
                    const ushort_t* __restrict__ Wt,
                    float* __restrict__ H, float* __restrict__ stats)
{
  __shared__ int rowsD[5][128];
  __shared__ int rowsS[5][128];

  const int tid = threadIdx.x;
  const int lane = tid & 63;
  const int wv = tid >> 6;          // col-strip
  const int l15 = lane & 15;
  const int quad = lane >> 4;
  const int row0 = (int)blockIdx.x * 128;

  if (tid < 128) {
    int r = row0 + tid; if (r > E0 - 1) r = E0 - 1;
    int rs[5];
    rs[0] = r;
    #pragma unroll
    for (int j = 0; j < 4; j++) rs[1 + j] = iclampi((int)nb[(size_t)r * 4 + j], 0, E0 - 1);
    #pragma unroll
    for (int j = 0; j < 5; j++) { rowsS[j][tid] = rs[j]; rowsD[j][tid] = nn1[rs[j]]; }
  }
  __syncthreads();

  f32x4 acc[8];
  #pragma unroll
  for (int mi = 0; mi < 8; mi++) acc[mi] = (f32x4){0.f, 0.f, 0.f, 0.f};

  for (int cc = 0; cc < 6; cc++) {
    const bool fromD = cc < 4;
    const ushort_t* __restrict__ src = fromD ? d2b : e1b;
    const int stride = fromD ? 128 : 64;
    const int cbase = (fromD ? cc * 32 : (cc - 4) * 32) + quad * 8;

    // B fragments for this K-chunk (Wt small & L1/L2-hot)
    short8 bf[5];
    #pragma unroll
    for (int p = 0; p < 5; p++)
      bf[p] = *(const short8*)&Wt[((size_t)(p * 64 + wv * 16 + l15)) * 192 + cc * 32 + quad * 8];

    #pragma unroll 2
    for (int mi = 0; mi < 8; mi++) {
      int rr = mi * 16 + l15;
      int r0, r1, r2, r3, r4;
      if (fromD) {
        r0 = rowsD[0][rr]; r1 = rowsD[1][rr]; r2 = rowsD[2][rr];
        r3 = rowsD[3][rr]; r4 = rowsD[4][rr];
      } else {
        r0 = rowsS[0][rr]; r1 = rowsS[1][rr]; r2 = rowsS[2][rr];
        r3 = rowsS[3][rr]; r4 = rowsS[4][rr];
      }
      uint4 v0 = *(const uint4*)&src[(size_t)r0 * stride + cbase];
      uint4 v1 = *(const uint4*)&src[(size_t)r1 * stride + cbase];
      uint4 v2 = *(const uint4*)&src[(size_t)r2 * stride + cbase];
      uint4 v3 = *(const uint4*)&src[(size_t)r3 * stride + cbase];
      uint4 v4 = *(const uint4*)&src[(size_t)r4 * stride + cbase];

      uint4 lo12, hi12, lo34, hi34;
      u16minmax(v1, v2, lo12, hi12);
      u16minmax(v3, v4, lo34, hi34);

      acc[mi] = __builtin_amdgcn_mfma_f32_16x16x32_bf16(*(short8*)&v0,   bf[0], acc[mi], 0, 0, 0);
      acc[mi] = __builtin_amdgcn_mfma_f32_16x16x32_bf16(*(short8*)&lo12, bf[1], acc[mi], 0, 0, 0);
      acc[mi] = __builtin_amdgcn_mfma_f32_16x16x32_bf16(*(short8*)&hi12, bf[2], acc[mi], 0, 0, 0);
      acc[mi] = __builtin_amdgcn_mfma_f32_16x16x32_bf16(*(short8*)&lo34, bf[3], acc[mi], 0, 0, 0);
      acc[mi] = __builtin_amdgcn_mfma_f32_16x16x32_bf16(*(short8*)&hi34, bf[4], acc[mi], 0, 0, 0);
    }
  }

  // epilogue: write H (fp32) + fused column stats
  const int col = wv * 16 + l15;
  float s = 0.f, q = 0.f;
  #pragma unroll
  for (int mi = 0; mi < 8; mi++) {
    #pragma unroll
    for (int reg = 0; reg < 4; reg++) {
      int r = row0 + mi * 16 + quad * 4 + reg;
      if (r < E0) {
        float v = acc[mi][reg];
        H[(size_t)r * 64 + col] = v;
        s += v; q += v * v;
      }
    }
  }
  s += __shfl_xor(s, 16); q += __shfl_xor(q, 16);
  s += __shfl_xor(s, 32); q += __shfl_xor(q, 32);
  if (quad == 0) {
    atomicAdd(&stats[col], s);
    atomicAdd(&stats[64 + col], q);
  }
}

// W (5C x Cout fp32) -> Wt bf16 [(p*Cout+n)][C]
template<int C, int Cout>
__global__ void prep_w_kernel(const float* __restrict__ W, ushort_t* __restrict__ Wt)
{
  int idx = (int)blockIdx.x * 256 + threadIdx.x;
  if (idx < 5 * C * Cout) {
    int n = idx % Cout;
    int k = idx / Cout;
    int p = k / C, c = k % C;
    Wt[((size_t)(p * Cout + n)) * C + c] = f2b(W[(size_t)k * Cout + n]);
  }
}

// column sum/sumsq for split-K layers
__global__ void stats_kernel(const float* __restrict__ H, int E, int Cout,
                             float* __restrict__ stats)
{
  const int RB = 64;
  int r0 = (int)blockIdx.x * RB;
  int rend = r0 + RB; if (rend > E) rend = E;
  for (int col = threadIdx.x; col < Cout; col += blockDim.x) {
    float s = 0.f, q = 0.f;
    for (int r = r0; r < rend; r++) { float v = H[(size_t)r * Cout + col]; s += v; q += v * v; }
    atomicAdd(&stats[col], s);
    atomicAdd(&stats[Cout + col], q);
  }
}

// BN(training stats) + ReLU; optional pooling key per row; optional bf16 copy
template<int Cout, bool KEYS, bool B16>
__global__ void bn_kernel(const float* __restrict__ H, const float* __restrict__ stats,
                          const float* __restrict__ g, const float* __restrict__ b,
                          int E, float* __restrict__ Out, ushort_t* __restrict__ Outb,
                          u64* __restrict__ keys)
{
  constexpr int CPL = Cout / 64;
  const int lane = threadIdx.x & 63;
  const int wid = threadIdx.x >> 6;
  const int wpb = blockDim.x >> 6;
  const float invE = 1.0f / (float)E;
  float mu[CPL], inv[CPL], gg[CPL], bb[CPL];
  #pragma unroll
  for (int u = 0; u < CPL; u++) {
    int c = lane + u * 64;
    float m = stats[c] * invE;
    float var = stats[Cout + c] * invE - m * m;
    mu[u] = m;
    inv[u] = rsqrtf(var + BN_EPS_F);
    gg[u] = g[c]; bb[u] = b[c];
  }
  for (int r = (int)blockIdx.x * wpb + wid; r < E; r += (int)gridDim.x * wpb) {
    float ss = 0.f;
    #pragma unroll
    for (int u = 0; u < CPL; u++) {
      int c = lane + u * 64;
      float v = H[(size_t)r * Cout + c];
      float o = (v - mu[u]) * inv[u] * gg[u] + bb[u];
      o = fmaxf(o, 0.f);
      Out[(size_t)r * Cout + c] = o;
      if constexpr (B16) Outb[(size_t)r * Cout + c] = f2b(o);
      ss += o * o;
    }
    if constexpr (KEYS) {
      #pragma unroll
      for (int s = 32; s > 0; s >>= 1) ss += __shfl_xor(ss, s, 64);
      if (lane == 0) {
        float sc = sqrtf(ss);
        u32 sb = __float_as_uint(sc);
        keys[r] = ((u64)sb << 32) | (u64)(0xFFFFFFFFu - (u32)r);
      }
    }
  }
}

// fused BN+ReLU+head matmul (Cout=64 -> 4)
__global__ void head_kernel(const float* __restrict__ H, const float* __restrict__ stats,
                            const float* __restrict__ g, const float* __restrict__ b,
                            const float* __restrict__ Wh, const float* __restrict__ bh,
                            int E, float* __restrict__ out)
{
  const int lane = threadIdx.x & 63;
  const int wid = threadIdx.x >> 6;
  const int wpb = blockDim.x >> 6;
  const float invE = 1.0f / (float)E;
  float m = stats[lane] * invE;
  float var = stats[64 + lane] * invE - m * m;
  float inv = rsqrtf(var + BN_EPS_F);
  float gg = g[lane], bb = b[lane];
  float4 w = *(const float4*)&Wh[lane * 4];
  float b0 = bh[0], b1 = bh[1], b2 = bh[2], b3 = bh[3];
  for (int r = (int)blockIdx.x * wpb + wid; r < E; r += (int)gridDim.x * wpb) {
    float v = H[(size_t)r * 64 + lane];
    float o = fmaxf((v - m) * inv * gg + bb, 0.f);
    float a0 = o * w.x, a1 = o * w.y, a2 = o * w.z, a3 = o * w.w;
    #pragma unroll
    for (int s = 32; s > 0; s >>= 1) {
      a0 += __shfl_xor(a0, s, 64);
      a1 += __shfl_xor(a1, s, 64);
      a2 += __shfl_xor(a2, s, 64);
      a3 += __shfl_xor(a3, s, 64);
    }
    if (lane == 0) {
      float4 ov = make_float4(a0 + b0, a1 + b1, a2 + b2, a3 + b3);
      *(float4*)&out[(size_t)r * 4] = ov;
    }
  }
}

// -------------------- pool-1 top-k (radix select on u64 keys) --------------
__global__ void hist_kernel(const u64* __restrict__ keys, int E, u32* __restrict__ hist)
{
  for (int i = (int)blockIdx.x * blockDim.x + threadIdx.x; i < E;
       i += (int)gridDim.x * blockDim.x) {
    u32 bin = (u32)(keys[i] >> 44);
    atomicAdd(&hist[bin], 1u);
  }
}

__global__ void scan_kernel(const u32* __restrict__ hist, int K, u32* __restrict__ sel)
{
  __shared__ u32 csum[1024];
  __shared__ u32 sb2[1024];
  __shared__ int selChunk;
  __shared__ u32 aboveChunk;
  const int tid = threadIdx.x;
  {
    const uint4* hp = (const uint4*)(hist + (size_t)tid * 1024);
    u32 s = 0;
    for (int i = 0; i < 256; i++) {
      uint4 v = hp[i];
      s += v.x + v.y + v.z + v.w;
    }
    csum[tid] = s;
  }
  __syncthreads();
  if (tid == 0) {
    u32 above = 0; int sc = 0; u32 ab = 0;
    for (int t = 1023; t >= 0; t--) {
      if (above + csum[t] >= (u32)K) { sc = t; ab = above; break; }
      above += csum[t];
    }
    selChunk = sc; aboveChunk = ab;
  }
  __syncthreads();
  sb2[tid] = hist[(size_t)selChunk * 1024 + tid];
  __syncthreads();
  if (tid == 0) {
    u32 above = aboveChunk; int sb = 0;
    for (int t = 1023; t >= 0; t--) {
      u32 c = sb2[t];
      if (above + c >= (u32)K) { sb = t; break; }
      above += c;
    }
    sel[0] = (u32)(selChunk * 1024 + sb);
    sel[1] = above;
    sel[2] = (u32)K - above;
  }
}

__global__ void collect_kernel(const u64* __restrict__ keys, int E, const u32* __restrict__ sel,
                               u64* __restrict__ cand, u32* __restrict__ count)
{
  u32 bin = sel[0];
  for (int i = (int)blockIdx.x * blockDim.x + threadIdx.x; i < E;
       i += (int)gridDim.x * blockDim.x) {
    if ((u32)(keys[i] >> 44) == bin) {
      u32 p = atomicAdd(count, 1u);
      if (p < (u32)CAND_CAP) cand[p] = keys[i];
    }
  }
}

__global__ void thresh_kernel(const u64* __restrict__ cand, const u32* __restrict__ count,
                              const u32* __restrict__ sel, u64* __restrict__ thr)
{
  __shared__ u64 sk[CAND_CAP];
  const int tid = threadIdx.x;
  const int nth = blockDim.x;
  int n = (int)(*count > (u32)CAND_CAP ? (u32)CAND_CAP : *count);
  int n2 = 2; while (n2 < n) n2 <<= 1;
  for (int i = tid; i < n2; i += nth) sk[i] = (i < n) ? cand[i] : 0ull;
  __syncthreads();
  for (int k = 2; k <= n2; k <<= 1)
    for (int j = k >> 1; j > 0; j >>= 1) {
      for (int i = tid; i < n2; i += nth) {
        int p = i ^ j;
        if (p > i) {
          u64 a = sk[i], bb = sk[p];
          bool up = ((i & k) == 0);
          bool sw = up ? (a < bb) : (a > bb);
          if (sw) { sk[i] = bb; sk[p] = a; }
        }
      }
      __syncthreads();
    }
  if (tid == 0) {
    int kr = (int)sel[2];
    thr[0] = sk[kr - 1];
  }
}

// -------------------- ordered compaction: count / scan / scatter -----------
__global__ void keep_count_kernel(const u64* __restrict__ keys, int E,
                                  const u64* __restrict__ thrp, u32* __restrict__ bcnt)
{
  const u64 thr = thrp[0];
  const int tid = threadIdx.x;
  int base = (int)blockIdx.x * 1024 + tid * 4;
  u32 c = 0;
  #pragma unroll
  for (int u = 0; u < 4; u++) {
    int i = base + u;
    if (i < E && keys[i] >= thr) c++;
  }
  __shared__ u32 sm[256];
  sm[tid] = c;
  __syncthreads();
  for (int s = 128; s > 0; s >>= 1) {
    if (tid < s) sm[tid] += sm[tid + s];
    __syncthreads();
  }
  if (tid == 0) bcnt[blockIdx.x] = sm[0];
}

__global__ void keep_scan_kernel(const u32* __restrict__ bcnt, int NB, u32* __restrict__ boffs)
{
  __shared__ u32 sm[256];
  const int tid = threadIdx.x;
  u32 v = (tid < NB) ? bcnt[tid] : 0;
  sm[tid] = v;
  __syncthreads();
  for (int off = 1; off < 256; off <<= 1) {
    u32 t = 0;
    if (tid >= off) t = sm[tid - off];
    __syncthreads();
    sm[tid] += t;
    __syncthreads();
  }
  if (tid < NB) boffs[tid] = sm[tid] - v;
}

__global__ void keep_scatter_kernel(const u64* __restrict__ keys, int E,
                                    const u64* __restrict__ thrp, const u32* __restrict__ boffs,
                                    int* __restrict__ keep, int K)
{
  const u64 thr = thrp[0];
  const int tid = threadIdx.x;
  int base = (int)blockIdx.x * 1024 + tid * 4;
  u32 f[4]; u32 c = 0;
  #pragma unroll
  for (int u = 0; u < 4; u++) {
    int i = base + u;
    f[u] = (i < E && keys[i] >= thr) ? 1u : 0u;
    c += f[u];
  }
  __shared__ u32 sm[256];
  sm[tid] = c;
  __syncthreads();
  for (int off = 1; off < 256; off <<= 1) {
    u32 t = 0;
    if (tid >= off) t = sm[tid - off];
    __syncthreads();
    sm[tid] += t;
    __syncthreads();
  }
  u32 pos = boffs[blockIdx.x] + sm[tid] - c;
  #pragma unroll
  for (int u = 0; u < 4; u++) {
    if (f[u]) {
      if (pos < (u32)K) keep[pos] = base + u;
      pos++;
    }
  }
}

// -------------------- pools 2/3: single-block full sort ---------------------
template<int NPOW>
__global__ void pool_select_kernel(const u64* __restrict__ keys, int E, int K,
                                   int* __restrict__ keep)
{
  __shared__ u64 sk[NPOW];
  __shared__ int si[NPOW];
  const int tid = threadIdx.x, nth = blockDim.x;
  for (int i = tid; i < NPOW; i += nth) sk[i] = (i < E) ? keys[i] : 0ull;
  __syncthreads();
  for (int k = 2; k <= NPOW; k <<= 1)
    for (int j = k >> 1; j > 0; j >>= 1) {
      for (int i = tid; i < NPOW; i += nth) {
        int p = i ^ j;
        if (p > i) {
          u64 a = sk[i], bb = sk[p];
          bool up = ((i & k) == 0);
          bool sw = up ? (a < bb) : (a > bb);
          if (sw) { sk[i] = bb; sk[p] = a; }
        }
      }
      __syncthreads();
    }
  for (int i = tid; i < NPOW; i += nth)
    si[i] = (i < K) ? (int)(0xFFFFFFFFu - (u32)(sk[i] & 0xFFFFFFFFull)) : 0x7FFFFFFF;
  __syncthreads();
  for (int k = 2; k <= NPOW; k <<= 1)
    for (int j = k >> 1; j > 0; j >>= 1) {
      for (int i = tid; i < NPOW; i += nth) {
        int p = i ^ j;
        if (p > i) {
          int a = si[i], bb = si[p];
          bool up = ((i & k) == 0);
          bool sw = up ? (a > bb) : (a < bb);
          if (sw) { si[i] = bb; si[p] = a; }
        }
      }
      __syncthreads();
    }
  for (int i = tid; i < K; i += nth) keep[i] = si[i];
}

template<int C, bool B16>
__global__ void pool_finish_kernel(const float* __restrict__ Xsrc, const int* __restrict__ nb_src,
                                   const int* __restrict__ keep, int K, int Esrc,
                                   float* __restrict__ Xp, ushort_t* __restrict__ Xpb,
                                   int* __restrict__ nbp)
{
  int total = K * C;
  for (int idx = (int)blockIdx.x * blockDim.x + threadIdx.x; idx < total;
       idx += (int)gridDim.x * blockDim.x) {
    int i = idx / C, c = idx % C;
    float v = Xsrc[(size_t)keep[i] * C + c];
    if constexpr (B16) Xpb[idx] = f2b(v);
    else Xp[idx] = v;
  }
  for (int idx = (int)blockIdx.x * blockDim.x + threadIdx.x; idx < K * 4;
       idx += (int)gridDim.x * blockDim.x) {
    int i = idx >> 2, j = idx & 3;
    int v = nb_src[(size_t)keep[i] * 4 + j];
    v = iclampi(v, 0, Esrc - 1);
    int p = bsearch_eq(keep, K, v);
    nbp[idx] = (p < 0) ? i : p;
  }
}

// unpool (nearest kept) + concat skip -> bf16 output
__global__ void unpool_cat_b16_kernel(const float* __restrict__ Xc, const float* __restrict__ Xs,
                                      const int* __restrict__ keep, int K, int E,
                                      int Cc, int Cs, ushort_t* __restrict__ out)
{
  int Ct = Cc + Cs;
  int total = E * Ct;
  for (int idx = (int)blockIdx.x * blockDim.x + threadIdx.x; idx < total;
       idx += (int)gridDim.x * blockDim.x) {
    int r = idx / Ct, c = idx % Ct;
    float v;
    if (c < Cc) { int nn = nearest_keep(keep, K, r); v = Xc[(size_t)nn * Cc + c]; }
    else v = Xs[(size_t)r * Cs + (c - Cc)];
    out[idx] = f2b(v);
  }
}

__global__ void nn_map_kernel(const int* __restrict__ keep, int K, int E, int* __restrict__ nn)
{
  for (int i = (int)blockIdx.x * blockDim.x + threadIdx.x; i < E;
       i += (int)gridDim.x * blockDim.x)
    nn[i] = nearest_keep(keep, K, i);
}

// ---------------------------------------------------------------------------
extern "C" void kernel_launch(void* const* d_in, const int* in_sizes, int n_in,
                              void* d_out, int out_size, void* d_ws, size_t ws_size,
                              hipStream_t stream)
{
  (void)in_sizes; (void)n_in; (void)out_size; (void)ws_size;
  const float* x     = (const float*)d_in[0];
  const int*   nb    = (const int*)d_in[1];
  const float* W_e1  = (const float*)d_in[2];
  const float* g_e1  = (const float*)d_in[3];
  const float* b_e1  = (const float*)d_in[4];
  const float* W_e2  = (const float*)d_in[5];
  const float* g_e2  = (const float*)d_in[6];
  const float* b_e2  = (const float*)d_in[7];
  const float* W_e3  = (const float*)d_in[8];
  const float* g_e3  = (const float*)d_in[9];
  const float* b_e3  = (const float*)d_in[10];
  const float* W_e4  = (const float*)d_in[11];
  const float* g_e4  = (const float*)d_in[12];
  const float* b_e4  = (const float*)d_in[13];
  const float* W_d3  = (const float*)d_in[14];
  const float* g_d3  = (const float*)d_in[15];
  const float* b_d3  = (const float*)d_in[16];
  const float* W_d2  = (const float*)d_in[17];
  const float* g_d2  = (const float*)d_in[18];
  const float* b_d2  = (const float*)d_in[19];
  const float* W_d1  = (const float*)d_in[20];
  const float* g_d1  = (const float*)d_in[21];
  const float* b_d1  = (const float*)d_in[22];
  const float* W_head = (const float*)d_in[23];
  const float* bias_head = (const float*)d_in[24];
  float* out = (float*)d_out;

  char* p = (char*)d_ws;
  auto alloc = [&](size_t bytes) -> char* {
    char* q = p; p += (bytes + 255) & ~(size_t)255; return q;
  };

  // --- zero zone (one memset) ---
  char* zz = p;
  u32*   hist  = (u32*)alloc(sizeof(u32) * (1u << 20));
  float* stats = (float*)alloc(sizeof(float) * 2 * (64 + 128 + 256 + 512 + 256 + 128 + 64));
  u32*   ctrl  = (u32*)alloc(sizeof(u32) * 16);
  u64*   thr   = (u64*)alloc(sizeof(u64) * 2);
  u32*   sel   = (u32*)alloc(sizeof(u32) * 8);
  float* H2    = (float*)alloc(sizeof(float) * T1 * 128);   // split-K -> zeroed
  float* H3    = (float*)alloc(sizeof(float) * T2 * 256);   // split-K -> zeroed
  size_t zz_bytes = (size_t)(p - zz);
  // --- rest ---
  float* H4    = (float*)alloc(sizeof(float) * T3 * 512);
  float* Hd3   = (float*)alloc(sizeof(float) * T2 * 256);
  float* Hd2   = (float*)alloc(sizeof(float) * T1 * 128);
  u32*   bcnt  = (u32*)alloc(sizeof(u32) * 256);
  u32*   boffs = (u32*)alloc(sizeof(u32) * 256);
  float* e1    = (float*)alloc(sizeof(float) * (size_t)E0 * 64);
  u64*   keys1 = (u64*)alloc(sizeof(u64) * E0);
  u64*   cand  = (u64*)alloc(sizeof(u64) * CAND_CAP);
  int*   keep1 = (int*)alloc(sizeof(int) * T1);
  float* e1p   = (float*)alloc(sizeof(float) * T1 * 64);
  int*   nb1   = (int*)alloc(sizeof(int) * T1 * 4);
  float* e2    = (float*)alloc(sizeof(float) * T1 * 128);
  u64*   keys2 = (u64*)alloc(sizeof(u64) * T1);
  int*   keep2 = (int*)alloc(sizeof(int) * T2);
  float* e2p   = (float*)alloc(sizeof(float) * T2 * 128);
  int*   nb2   = (int*)alloc(sizeof(int) * T2 * 4);
  float* e3    = (float*)alloc(sizeof(float) * T2 * 256);
  u64*   keys3 = (u64*)alloc(sizeof(u64) * T2);
  int*   keep3 = (int*)alloc(sizeof(int) * T3);
  ushort_t* e3pb = (ushort_t*)alloc(sizeof(ushort_t) * T3 * 256);
  int*   nb3   = (int*)alloc(sizeof(int) * T3 * 4);
  float* e4    = (float*)alloc(sizeof(float) * T3 * 512);
  ushort_t* d3catb = (ushort_t*)alloc(sizeof(ushort_t) * T2 * 768);
  float* d3    = (float*)alloc(sizeof(float) * T2 * 256);
  ushort_t* d2catb = (ushort_t*)alloc(sizeof(ushort_t) * T1 * 384);
  float* d2    = (float*)alloc(sizeof(float) * T1 * 128);
  int*   nn1   = (int*)alloc(sizeof(int) * E0);
  float* Hd1   = (float*)alloc(sizeof(float) * (size_t)E0 * 64);
  ushort_t* e1b = (ushort_t*)alloc(sizeof(ushort_t) * (size_t)E0 * 64);
  ushort_t* d2b = (ushort_t*)alloc(sizeof(ushort_t) * T1 * 128);
  ushort_t* Wt1 = (ushort_t*)alloc(sizeof(ushort_t) * 5 * 64 * 192);
  ushort_t* Wt4 = (ushort_t*)alloc(sizeof(ushort_t) * 5 * 512 * 256);
  ushort_t* Wtd3 = (ushort_t*)alloc(sizeof(ushort_t) * 5 * 256 * 768);
  ushort_t* Wtd2 = (ushort_t*)alloc(sizeof(ushort_t) * 5 * 128 * 384);

  float* s1  = stats;
  float* s2  = s1 + 2 * 64;
  float* s3  = s2 + 2 * 128;
  float* s4  = s3 + 2 * 256;
  float* sd3 = s4 + 2 * 512;
  float* sd2 = sd3 + 2 * 256;
  float* sd1 = sd2 + 2 * 128;

  hipMemsetAsync(zz, 0, zz_bytes, stream);
  prep_w_kernel<192, 64><<<dim3((5 * 192 * 64 + 255) / 256), 256, 0, stream>>>(W_d1, Wt1);
  prep_w_kernel<256, 512><<<dim3((5 * 256 * 512 + 255) / 256), 256, 0, stream>>>(W_e4, Wt4);
  prep_w_kernel<768, 256><<<dim3((5 * 768 * 256 + 255) / 256), 256, 0, stream>>>(W_d3, Wtd3);
  prep_w_kernel<384, 128><<<dim3((5 * 384 * 128 + 255) / 256), 256, 0, stream>>>(W_d2, Wtd2);

  // ---- encoder 1 (fp32, pool-key-critical) ----
  e1_conv_kernel<<<dim3((E0 + 127) / 128), 256, 0, stream>>>(x, nb, W_e1, e1, s1);
  bn_kernel<64, true, true><<<dim3(8192), 256, 0, stream>>>(e1, s1, g_e1, b_e1, E0, e1, e1b, keys1);

  // ---- pool 1 (top-1500 of 200000) ----
  hist_kernel<<<dim3(782), 256, 0, stream>>>(keys1, E0, hist);
  scan_kernel<<<dim3(1), 1024, 0, stream>>>(hist, T1, sel);
  collect_kernel<<<dim3(782), 256, 0, stream>>>(keys1, E0, sel, cand, ctrl);
  thresh_kernel<<<dim3(1), 1024, 0, stream>>>(cand, ctrl, sel, thr);
  keep_count_kernel<<<dim3(NB_KEEP), 256, 0, stream>>>(keys1, E0, thr, bcnt);
  keep_scan_kernel<<<dim3(1), 256, 0, stream>>>(bcnt, NB_KEEP, boffs);
  keep_scatter_kernel<<<dim3(NB_KEEP), 256, 0, stream>>>(keys1, E0, thr, boffs, keep1, T1);
  pool_finish_kernel<64, false><<<dim3(380), 256, 0, stream>>>(e1, nb, keep1, T1, E0, e1p, nullptr, nb1);

  // ---- encoder 2 (fp32 split-K=2, pool-key-critical) ----
  conv_kernel<64, 128, 32, 64, 8, 2, 4, 2, false>
      <<<dim3((T1 + 31) / 32, 128 / 64, 2), 256, 0, stream>>>(e1p, nb1, T1, W_e2, H2, nullptr);
  stats_kernel<<<dim3((T1 + 63) / 64), 256, 0, stream>>>(H2, T1, 128, s2);
  bn_kernel<128, true, false><<<dim3(512), 256, 0, stream>>>(H2, s2, g_e2, b_e2, T1, e2, nullptr, keys2);
  pool_select_kernel<2048><<<dim3(1), 256, 0, stream>>>(keys2, T1, T2, keep2);
  pool_finish_kernel<128, false><<<dim3(380), 256, 0, stream>>>(e2, nb1, keep2, T2, T1, e2p, nullptr, nb2);

  // ---- encoder 3 (fp32 split-K=4, pool-key-critical) ----
  conv_kernel<128, 256, 32, 64, 8, 2, 4, 4, false>
      <<<dim3((T2 + 31) / 32, 256 / 64, 4), 256, 0, stream>>>(e2p, nb2, T2, W_e3, H3, nullptr);
  stats_kernel<<<dim3((T2 + 63) / 64), 256, 0, stream>>>(H3, T2, 256, s3);
  bn_kernel<256, true, false><<<dim3(256), 256, 0, stream>>>(H3, s3, g_e3, b_e3, T2, e3, nullptr, keys3);
  pool_select_kernel<1024><<<dim3(1), 256, 0, stream>>>(keys3, T2, T3, keep3);
  pool_finish_kernel<256, true><<<dim3(380), 256, 0, stream>>>(e3, nb2, keep3, T3, T2, nullptr, e3pb, nb3);

  // ---- encoder 4 (bf16 MFMA, downstream of all pooling) ----
  mfma_conv_kernel<256, 512><<<dim3((T3 + 31) / 32, 512 / 64), 128, 0, stream>>>(
      e3pb, nb3, T3, Wt4, H4, s4);
  bn_kernel<512, false, false><<<dim3(128), 256, 0, stream>>>(
      H4, s4, g_e4, b_e4, T3, e4, nullptr, nullptr);

  // ---- decoder 3 (bf16 MFMA) ----
  unpool_cat_b16_kernel<<<dim3((T2 * 768 + 255) / 256), 256, 0, stream>>>(
      e4, e3, keep3, T3, T2, 512, 256, d3catb);
  mfma_conv_kernel<768, 256><<<dim3((T2 + 31) / 32, 256 / 64), 128, 0, stream>>>(
      d3catb, nb2, T2, Wtd3, Hd3, sd3);
  bn_kernel<256, false, false><<<dim3(256), 256, 0, stream>>>(
      Hd3, sd3, g_d3, b_d3, T2, d3, nullptr, nullptr);

  // ---- decoder 2 (bf16 MFMA) ----
  unpool_cat_b16_kernel<<<dim3((T1 * 384 + 255) / 256), 256, 0, stream>>>(
      d3, e2, keep2, T2, T1, 256, 128, d2catb);
  mfma_conv_kernel<384, 128><<<dim3((T1 + 31) / 32, 128 / 64), 128, 0, stream>>>(
      d2catb, nb1, T1, Wtd2, Hd2, sd2);
  bn_kernel<128, false, true><<<dim3(512), 256, 0, stream>>>(
      Hd2, sd2, g_d2, b_d2, T1, d2, d2b, nullptr);

  // ---- decoder 1 (bf16 MFMA, col-split — fastest measured variant) ----
  nn_map_kernel<<<dim3(782), 256, 0, stream>>>(keep1, T1, E0, nn1);
  d1_mfma_kernel<<<dim3((E0 + 127) / 128), 256, 0, stream>>>(d2b, e1b, nn1, nb, Wt1, Hd1, sd1);

  // ---- head (fused BN+ReLU+matmul) ----
  head_kernel<<<dim3(8192), 256, 0, stream>>>(Hd1, sd1, g_d1, b_d1, W_head, bias_head, E0, out);
}

// Round 10
// 987.709 us; speedup vs baseline: 2.5980x; 1.1250x over previous
//
#include <hip/hip_runtime.h>
#include <stdint.h>

typedef unsigned long long u64;
typedef unsigned int u32;
typedef unsigned short ushort_t;

#define FI __device__ __forceinline__

static constexpr float BN_EPS_F = 1e-5f;
static constexpr int E0 = 200000;
static constexpr int T1 = 1500, T2 = 750, T3 = 375;
static constexpr int CAND_CAP = 4096;
static constexpr int NB_KEEP = (E0 + 1023) / 1024;

typedef __attribute__((ext_vector_type(8))) short short8;
typedef __attribute__((ext_vector_type(4))) float f32x4;

FI int iclampi(int v, int lo, int hi) { return v < lo ? lo : (v > hi ? hi : v); }

FI ushort_t f2b(float f) {
  u32 u = __float_as_uint(f);
  u32 r = (u + 0x7FFFu + ((u >> 16) & 1u)) >> 16;
  return (ushort_t)r;
}

// bf16 >= 0 (post-ReLU) -> u16 order == numeric order
FI void u16minmax(const uint4& va, const uint4& vb, uint4& lo, uint4& hi) {
  const ushort_t* a = (const ushort_t*)&va;
  const ushort_t* b = (const ushort_t*)&vb;
  ushort_t* l = (ushort_t*)&lo;
  ushort_t* h = (ushort_t*)&hi;
  #pragma unroll
  for (int i = 0; i < 8; i++) {
    ushort_t x = a[i], y = b[i];
    l[i] = x < y ? x : y;
    h[i] = x < y ? y : x;
  }
}

FI int nearest_keep(const int* __restrict__ keep, int K, int idx) {
  int lo = 0, hi = K;
  while (lo < hi) { int mid = (lo + hi) >> 1; if (keep[mid] < idx) lo = mid + 1; else hi = mid; }
  int l = lo - 1; l = l < 0 ? 0 : (l > K - 1 ? K - 1 : l);
  int r = lo;     r = r < 0 ? 0 : (r > K - 1 ? K - 1 : r);
  int dl = idx - keep[l]; dl = dl < 0 ? -dl : dl;
  int dr = idx - keep[r]; dr = dr < 0 ? -dr : dr;
  return (dl <= dr) ? l : r;
}

FI int bsearch_eq(const int* __restrict__ keep, int K, int v) {
  int lo = 0, hi = K;
  while (lo < hi) { int mid = (lo + hi) >> 1; if (keep[mid] < v) lo = mid + 1; else hi = mid; }
  if (lo < K && keep[lo] == v) return lo;
  return -1;
}

// ---------------------------------------------------------------------------
// Generic fp32 mesh-conv (split-K) — e2/e3 (pool-key layers).
// ---------------------------------------------------------------------------
template<int C, int Cout, int BR, int BC, int KT, int TR, int TC, int KSPLIT,
         bool FUSE_STATS>
__global__ __launch_bounds__((BR / TR) * (BC / TC))
void conv_kernel(const float* __restrict__ X,
                 const int* __restrict__ nb, int E,
                 const float* __restrict__ W,
                 float* __restrict__ H, float* __restrict__ stats)
{
  constexpr int NTH = (BR / TR) * (BC / TC);
  constexpr int VK = 5 * KT;
  constexpr int KC = C / KSPLIT;
  static_assert(KC % KT == 0, "KC % KT");

  const int row0 = blockIdx.x * BR;
  const int col0 = blockIdx.y * BC;
  const int c_begin = (KSPLIT > 1) ? (int)blockIdx.z * KC : 0;

  __shared__ float As[VK][BR];
  __shared__ float Bs[VK][BC];
  __shared__ int rowsS[5][BR];
  __shared__ float red[FUSE_STATS ? 2 * (BR / TR) * BC : 1];

  const int tid = threadIdx.x;

  for (int q = tid; q < BR; q += NTH) {
    int r = row0 + q;
    int rr[5];
    if (r < E) {
      rr[0] = r;
      #pragma unroll
      for (int j = 0; j < 4; j++) {
        int v = nb[(size_t)r * 4 + j];
        rr[1 + j] = iclampi(v, 0, E - 1);
      }
    } else {
      #pragma unroll
      for (int j = 0; j < 5; j++) rr[j] = -1;
    }
    #pragma unroll
    for (int j = 0; j < 5; j++) rowsS[j][q] = rr[j];
  }

  float acc[TR][TC];
  #pragma unroll
  for (int i = 0; i < TR; i++)
    #pragma unroll
    for (int j = 0; j < TC; j++) acc[i][j] = 0.f;

  const int tr = tid / (BC / TC);
  const int tc = tid % (BC / TC);
  const int rA = tr * TR;
  const int cB = tc * TC;

  for (int c0 = c_begin; c0 < c_begin + KC; c0 += KT) {
    __syncthreads();
    for (int q = tid; q < VK * (BC / 4); q += NTH) {
      int kk = q / (BC / 4);
      int c4 = q % (BC / 4);
      int p = kk / KT, t = kk % KT;
      float4 wv = *(const float4*)&W[(size_t)(p * C + c0 + t) * Cout + col0 + c4 * 4];
      *(float4*)&Bs[kk][c4 * 4] = wv;
    }
    for (int q = tid; q < BR * KT; q += NTH) {
      int t = q % KT, rq = q / KT;
      int c = c0 + t;
      float s0 = 0.f, a1 = 0.f, a2 = 0.f, a3 = 0.f, a4 = 0.f;
      if (rowsS[0][rq] >= 0) {
        float v0, v1, v2, v3;
        s0 = X[(size_t)rowsS[0][rq] * C + c];
        v0 = X[(size_t)rowsS[1][rq] * C + c];
        v1 = X[(size_t)rowsS[2][rq] * C + c];
        v2 = X[(size_t)rowsS[3][rq] * C + c];
        v3 = X[(size_t)rowsS[4][rq] * C + c];
        a1 = fminf(v0, v1); a2 = fmaxf(v0, v1);
        a3 = fminf(v2, v3); a4 = fmaxf(v2, v3);
      }
      As[0 * KT + t][rq] = s0;
      As[1 * KT + t][rq] = a1;
      As[2 * KT + t][rq] = a2;
      As[3 * KT + t][rq] = a3;
      As[4 * KT + t][rq] = a4;
    }
    __syncthreads();

    for (int kk = 0; kk < VK; kk++) {
      float a[TR], b[TC];
      #pragma unroll
      for (int i = 0; i < TR; i++) a[i] = As[kk][rA + i];
      #pragma unroll
      for (int j = 0; j < TC; j++) b[j] = Bs[kk][cB + j];
      #pragma unroll
      for (int i = 0; i < TR; i++)
        #pragma unroll
        for (int j = 0; j < TC; j++)
          acc[i][j] = fmaf(a[i], b[j], acc[i][j]);
    }
  }

  #pragma unroll
  for (int i = 0; i < TR; i++) {
    int r = row0 + rA + i;
    if (r < E) {
      if constexpr (KSPLIT > 1) {
        #pragma unroll
        for (int j = 0; j < TC; j++)
          atomicAdd(&H[(size_t)r * Cout + col0 + cB + j], acc[i][j]);
      } else {
        #pragma unroll
        for (int j = 0; j < TC; j += 4) {
          float4 v = make_float4(acc[i][j], acc[i][j + 1], acc[i][j + 2], acc[i][j + 3]);
          *(float4*)&H[(size_t)r * Cout + col0 + cB + j] = v;
        }
      }
    }
  }

  if constexpr (FUSE_STATS) {
    float s[TC], q2[TC];
    #pragma unroll
    for (int j = 0; j < TC; j++) { s[j] = 0.f; q2[j] = 0.f; }
    #pragma unroll
    for (int i = 0; i < TR; i++) {
      int r = row0 + rA + i;
      if (r < E) {
        #pragma unroll
        for (int j = 0; j < TC; j++) { float v = acc[i][j]; s[j] += v; q2[j] += v * v; }
      }
    }
    __syncthreads();
    float* redS = &red[0];
    float* redQ = &red[(BR / TR) * BC];
    #pragma unroll
    for (int j = 0; j < TC; j++) {
      redS[tr * BC + cB + j] = s[j];
      redQ[tr * BC + cB + j] = q2[j];
    }
    __syncthreads();
    for (int col = tid; col < BC; col += NTH) {
      float ts = 0.f, tq = 0.f;
      for (int g = 0; g < BR / TR; g++) { ts += redS[g * BC + col]; tq += redQ[g * BC + col]; }
      atomicAdd(&stats[col0 + col], ts);
      atomicAdd(&stats[Cout + col0 + col], tq);
    }
  }
}

// ---------------------------------------------------------------------------
// Dedicated e1 conv (C=5, Cout=64): vectorized row gathers, W in LDS, stats.
// ---------------------------------------------------------------------------
__global__ __launch_bounds__(256)
void e1_conv_kernel(const float* __restrict__ X, const int* __restrict__ nb,
                    const float* __restrict__ W,
                    float* __restrict__ H, float* __restrict__ stats)
{
  __shared__ float As[25][128];
  __shared__ float Bs[25][64];
  __shared__ float red[2 * 32 * 64];

  const int tid = threadIdx.x;
  const int row0 = (int)blockIdx.x * 128;

  if (tid < 128) {
    int r = row0 + tid; if (r > E0 - 1) r = E0 - 1;
    int rs[5];
    rs[0] = r;
    #pragma unroll
    for (int j = 0; j < 4; j++) rs[1 + j] = iclampi((int)nb[(size_t)r * 4 + j], 0, E0 - 1);
    float v[5][5];
    #pragma unroll
    for (int j = 0; j < 5; j++) {
      const float* src = &X[(size_t)rs[j] * 5];
      float4 a = *(const float4*)src;
      v[j][0] = a.x; v[j][1] = a.y; v[j][2] = a.z; v[j][3] = a.w;
      v[j][4] = src[4];
    }
    #pragma unroll
    for (int c = 0; c < 5; c++) {
      As[0 * 5 + c][tid] = v[0][c];
      As[1 * 5 + c][tid] = fminf(v[1][c], v[2][c]);
      As[2 * 5 + c][tid] = fmaxf(v[1][c], v[2][c]);
      As[3 * 5 + c][tid] = fminf(v[3][c], v[4][c]);
      As[4 * 5 + c][tid] = fmaxf(v[3][c], v[4][c]);
    }
  } else {
    for (int q = tid - 128; q < 25 * 16; q += 128) {
      int k = q / 16, c4 = q % 16;
      float4 wv = *(const float4*)&W[(size_t)k * 64 + c4 * 4];
      *(float4*)&Bs[k][c4 * 4] = wv;
    }
  }
  __syncthreads();

  const int tr = tid >> 3;
  const int tc = tid & 7;
  const int rA = tr * 4;
  const int cB = tc * 8;

  float acc[4][8];
  #pragma unroll
  for (int i = 0; i < 4; i++)
    #pragma unroll
    for (int j = 0; j < 8; j++) acc[i][j] = 0.f;

  for (int k = 0; k < 25; k++) {
    float a[4], b[8];
    #pragma unroll
    for (int i = 0; i < 4; i++) a[i] = As[k][rA + i];
    #pragma unroll
    for (int j = 0; j < 8; j++) b[j] = Bs[k][cB + j];
    #pragma unroll
    for (int i = 0; i < 4; i++)
      #pragma unroll
      for (int j = 0; j < 8; j++)
        acc[i][j] = fmaf(a[i], b[j], acc[i][j]);
  }

  float s[8], q2[8];
  #pragma unroll
  for (int j = 0; j < 8; j++) { s[j] = 0.f; q2[j] = 0.f; }
  #pragma unroll
  for (int i = 0; i < 4; i++) {
    int r = row0 + rA + i;
    if (r < E0) {
      #pragma unroll
      for (int j = 0; j < 8; j += 4) {
        float4 v = make_float4(acc[i][j], acc[i][j + 1], acc[i][j + 2], acc[i][j + 3]);
        *(float4*)&H[(size_t)r * 64 + cB + j] = v;
      }
      #pragma unroll
      for (int j = 0; j < 8; j++) { float v = acc[i][j]; s[j] += v; q2[j] += v * v; }
    }
  }
  __syncthreads();
  float* redS = &red[0];
  float* redQ = &red[32 * 64];
  #pragma unroll
  for (int j = 0; j < 8; j++) {
    redS[tr * 64 + cB + j] = s[j];
    redQ[tr * 64 + cB + j] = q2[j];
  }
  __syncthreads();
  for (int col = tid; col < 64; col += 256) {
    float ts = 0.f, tq = 0.f;
    for (int g = 0; g < 32; g++) { ts += redS[g * 64 + col]; tq += redQ[g * 64 + col]; }
    atomicAdd(&stats[col], ts);
    atomicAdd(&stats[64 + col], tq);
  }
}

// ---------------------------------------------------------------------------
// Generic bf16 MFMA mesh-conv (e4/d3/d2) — split-K for occupancy.
// KSPLIT>1: partial-K accumulation via fp32 atomics into pre-zeroed H.
// ---------------------------------------------------------------------------
template<int C, int Cout, int KSPLIT>
__global__ __launch_bounds__(128)
void mfma_conv_kernel(const ushort_t* __restrict__ src,
                      const int* __restrict__ nb, int E,
                      const ushort_t* __restrict__ Wt,
                      float* __restrict__ H)
{
  constexpr int NCC_T = C / 32;
  constexpr int NCC = NCC_T / KSPLIT;
  static_assert(NCC_T % KSPLIT == 0, "NCC_T % KSPLIT");
  __shared__ int rows[5][32];

  const int tid = threadIdx.x;
  const int lane = tid & 63;
  const int wv = tid >> 6;
  const int l15 = lane & 15;
  const int quad = lane >> 4;
  const int row0 = (int)blockIdx.x * 32;
  const int col0 = (int)blockIdx.y * 64;
  const int cc0 = (KSPLIT > 1) ? (int)blockIdx.z * NCC : 0;

  if (tid < 32) {
    int r = row0 + tid; if (r > E - 1) r = E - 1;
    rows[0][tid] = r;
    #pragma unroll
    for (int j = 0; j < 4; j++) rows[1 + j][tid] = iclampi(nb[(size_t)r * 4 + j], 0, E - 1);
  }
  __syncthreads();

  const int rr = wv * 16 + l15;
  int r5[5];
  #pragma unroll
  for (int j = 0; j < 5; j++) r5[j] = rows[j][rr];

  f32x4 acc[4];
  #pragma unroll
  for (int ni = 0; ni < 4; ni++) acc[ni] = (f32x4){0.f, 0.f, 0.f, 0.f};

  uint4 raw[2][5];
  auto loadcc = [&](int par, int cc2) {
    int cb = (cc0 + cc2) * 32 + quad * 8;
    #pragma unroll
    for (int j = 0; j < 5; j++)
      raw[par][j] = *(const uint4*)&src[(size_t)r5[j] * C + cb];
  };

  loadcc(0, 0);
  #pragma unroll
  for (int cc = 0; cc < NCC; cc++) {
    const int par = cc & 1;
    if (cc + 1 < NCC) loadcc(par ^ 1, cc + 1);
    short8 a[5];
    a[0] = *(short8*)&raw[par][0];
    {
      uint4 lo, hi;
      u16minmax(raw[par][1], raw[par][2], lo, hi);
      a[1] = *(short8*)&lo; a[2] = *(short8*)&hi;
    }
    {
      uint4 lo, hi;
      u16minmax(raw[par][3], raw[par][4], lo, hi);
      a[3] = *(short8*)&lo; a[4] = *(short8*)&hi;
    }
    #pragma unroll
    for (int p = 0; p < 5; p++) {
      #pragma unroll
      for (int ni = 0; ni < 4; ni++) {
        short8 bf = *(const short8*)&Wt[((size_t)(p * Cout + col0 + ni * 16 + l15)) * C + (cc0 + cc) * 32 + quad * 8];
        acc[ni] = __builtin_amdgcn_mfma_f32_16x16x32_bf16(a[p], bf, acc[ni], 0, 0, 0);
      }
    }
  }

  #pragma unroll
  for (int reg = 0; reg < 4; reg++) {
    int r = row0 + wv * 16 + quad * 4 + reg;
    if (r < E) {
      #pragma unroll
      for (int ni = 0; ni < 4; ni++) {
        if constexpr (KSPLIT > 1)
          atomicAdd(&H[(size_t)r * Cout + col0 + ni * 16 + l15], acc[ni][reg]);
        else
          H[(size_t)r * Cout + col0 + ni * 16 + l15] = acc[ni][reg];
      }
    }
  }
}

// ---------------------------------------------------------------------------
// d1 conv via bf16 MFMA — col-split (fastest measured: ~211 us, gather-bound).
// ---------------------------------------------------------------------------
__global__ __launch_bounds__(256, 4)
void d1_mfma_kernel(const ushort_t* __restrict__ d2b, const ushort_t* __restrict__ e1b,
                    const int* __restrict__ nn1, const int* __restrict__ nb,
                    const ushort_t* __restrict__ Wt,
                    float* __restrict__ H, float* __restrict__ stats)
{
  __shared__ int rowsD[5][128];
  __shared__ int rowsS[5][128];

  const int tid = threadIdx.x;
  const int lane = tid & 63;
  const int wv = tid >> 6;          // col-strip
  const int l15 = lane & 15;
  const int quad = lane >> 4;
  const int row0 = (int)blockIdx.x * 128;

  if (tid < 128) {
    int r = row0 + tid; if (r > E0 - 1) r = E0 - 1;
    int rs[5];
    rs[0] = r;
    #pragma unroll
    for (int j = 0; j < 4; j++) rs[1 + j] = iclampi((int)nb[(size_t)r * 4 + j], 0, E0 - 1);
    #pragma unroll
    for (int j = 0; j < 5; j++) { rowsS[j][tid] = rs[j]; rowsD[j][tid] = nn1[rs[j]]; }
  }
  __syncthreads();

  f32x4 acc[8];
  #pragma unroll
  for (int mi = 0; mi < 8; mi++) acc[mi] = (f32x4){0.f, 0.f, 0.f, 0.f};

  for (int cc = 0; cc < 6; cc++) {
    const bool fromD = cc < 4;
    const ushort_t* __restrict__ src = fromD ? d2b : e1b;
    const int stride = fromD ? 128 : 64;
    const int cbase = (fromD ? cc * 32 : (cc - 4) * 32) + quad * 8;

    short8 bf[5];
    #pragma unroll
    for (int p = 0; p < 5; p++)
      bf[p] = *(const short8*)&Wt[((size_t)(p * 64 + wv * 16 + l15)) * 192 + cc * 32 + quad * 8];

    #pragma unroll 2
    for (int mi = 0; mi < 8; mi++) {
      int rr = mi * 16 + l15;
      int r0, r1, r2, r3, r4;
      if (fromD) {
        r0 = rowsD[0][rr]; r1 = rowsD[1][rr]; r2 = rowsD[2][rr];
        r3 = rowsD[3][rr]; r4 = rowsD[4][rr];
      } else {
        r0 = rowsS[0][rr]; r1 = rowsS[1][rr]; r2 = rowsS[2][rr];
        r3 = rowsS[3][rr]; r4 = rowsS[4][rr];
      }
      uint4 v0 = *(const uint4*)&src[(size_t)r0 * stride + cbase];
      uint4 v1 = *(const uint4*)&src[(size_t)r1 * stride + cbase];
      uint4 v2 = *(const uint4*)&src[(size_t)r2 * stride + cbase];
      uint4 v3 = *(const uint4*)&src[(size_t)r3 * stride + cbase];
      uint4 v4 = *(const uint4*)&src[(size_t)r4 * stride + cbase];

      uint4 lo12, hi12, lo34, hi34;
      u16minmax(v1, v2, lo12, hi12);
      u16minmax(v3, v4, lo34, hi34);

      acc[mi] = __builtin_amdgcn_mfma_f32_16x16x32_bf16(*(short8*)&v0,   bf[0], acc[mi], 0, 0, 0);
      acc[mi] = __builtin_amdgcn_mfma_f32_16x16x32_bf16(*(short8*)&lo12, bf[1], acc[mi], 0, 0, 0);
      acc[mi] = __builtin_amdgcn_mfma_f32_16x16x32_bf16(*(short8*)&hi12, bf[2], acc[mi], 0, 0, 0);
      acc[mi] = __builtin_amdgcn_mfma_f32_16x16x32_bf16(*(short8*)&lo34, bf[3], acc[mi], 0, 0, 0);
      acc[mi] = __builtin_amdgcn_mfma_f32_16x16x32_bf16(*(short8*)&hi34, bf[4], acc[mi], 0, 0, 0);
    }
  }

  const int col = wv * 16 + l15;
  float s = 0.f, q = 0.f;
  #pragma unroll
  for (int mi = 0; mi < 8; mi++) {
    #pragma unroll
    for (int reg = 0; reg < 4; reg++) {
      int r = row0 + mi * 16 + quad * 4 + reg;
      if (r < E0) {
        float v = acc[mi][reg];
        H[(size_t)r * 64 + col] = v;
        s += v; q += v * v;
      }
    }
  }
  s += __shfl_xor(s, 16); q += __shfl_xor(q, 16);
  s += __shfl_xor(s, 32); q += __shfl_xor(q, 32);
  if (quad == 0) {
    atomicAdd(&stats[col], s);
    atomicAdd(&stats[64 + col], q);
  }
}

// All weight transposes in one kernel: W (5C x Cout fp32) -> Wt bf16 [(p*Cout+n)][C]
FI void prep_one(const float* __restrict__ W, ushort_t* __restrict__ Wt,
                 int C, int Cout, int i)
{
  int n = i % Cout;
  int k = i / Cout;
  int p = k / C, c = k % C;
  Wt[((size_t)(p * Cout + n)) * C + c] = f2b(W[(size_t)k * Cout + n]);
}

__global__ void prep_all_kernel(const float* __restrict__ W1, const float* __restrict__ W4,
                                const float* __restrict__ Wd3, const float* __restrict__ Wd2,
                                ushort_t* __restrict__ Wt1, ushort_t* __restrict__ Wt4,
                                ushort_t* __restrict__ Wtd3, ushort_t* __restrict__ Wtd2)
{
  int idx = (int)blockIdx.x * 256 + threadIdx.x;
  const int S1 = 5 * 192 * 64, S4 = 5 * 256 * 512, Sd3 = 5 * 768 * 256, Sd2 = 5 * 384 * 128;
  if (idx < S1) { prep_one(W1, Wt1, 192, 64, idx); return; }
  idx -= S1;
  if (idx < S4) { prep_one(W4, Wt4, 256, 512, idx); return; }
  idx -= S4;
  if (idx < Sd3) { prep_one(Wd3, Wtd3, 768, 256, idx); return; }
  idx -= Sd3;
  if (idx < Sd2) { prep_one(Wd2, Wtd2, 384, 128, idx); return; }
}

// column sum/sumsq for split-K layers
__global__ void stats_kernel(const float* __restrict__ H, int E, int Cout,
                             float* __restrict__ stats)
{
  const int RB = 64;
  int r0 = (int)blockIdx.x * RB;
  int rend = r0 + RB; if (rend > E) rend = E;
  for (int col = threadIdx.x; col < Cout; col += blockDim.x) {
    float s = 0.f, q = 0.f;
    for (int r = r0; r < rend; r++) { float v = H[(size_t)r * Cout + col]; s += v; q += v * v; }
    atomicAdd(&stats[col], s);
    atomicAdd(&stats[Cout + col], q);
  }
}

// BN(training stats) + ReLU; optional pooling key per row; optional bf16 copy
template<int Cout, bool KEYS, bool B16>
__global__ void bn_kernel(const float* __restrict__ H, const float* __restrict__ stats,
                          const float* __restrict__ g, const float* __restrict__ b,
                          int E, float* __restrict__ Out, ushort_t* __restrict__ Outb,
                          u64* __restrict__ keys)
{
  constexpr int CPL = Cout / 64;
  const int lane = threadIdx.x & 63;
  const int wid = threadIdx.x >> 6;
  const int wpb = blockDim.x >> 6;
  const float invE = 1.0f / (float)E;
  float mu[CPL], inv[CPL], gg[CPL], bb[CPL];
  #pragma unroll
  for (int u = 0; u < CPL; u++) {
    int c = lane + u * 64;
    float m = stats[c] * invE;
    float var = stats[Cout + c] * invE - m * m;
    mu[u] = m;
    inv[u] = rsqrtf(var + BN_EPS_F);
    gg[u] = g[c]; bb[u] = b[c];
  }
  for (int r = (int)blockIdx.x * wpb + wid; r < E; r += (int)gridDim.x * wpb) {
    float ss = 0.f;
    #pragma unroll
    for (int u = 0; u < CPL; u++) {
      int c = lane + u * 64;
      float v = H[(size_t)r * Cout + c];
      float o = (v - mu[u]) * inv[u] * gg[u] + bb[u];
      o = fmaxf(o, 0.f);
      Out[(size_t)r * Cout + c] = o;
      if constexpr (B16) Outb[(size_t)r * Cout + c] = f2b(o);
      ss += o * o;
    }
    if constexpr (KEYS) {
      #pragma unroll
      for (int s = 32; s > 0; s >>= 1) ss += __shfl_xor(ss, s, 64);
      if (lane == 0) {
        float sc = sqrtf(ss);
        u32 sb = __float_as_uint(sc);
        keys[r] = ((u64)sb << 32) | (u64)(0xFFFFFFFFu - (u32)r);
      }
    }
  }
}

// fused BN+ReLU+head matmul (Cout=64 -> 4)
__global__ void head_kernel(const float* __restrict__ H, const float* __restrict__ stats,
                            const float* __restrict__ g, const float* __restrict__ b,
                            const float* __restrict__ Wh, const float* __restrict__ bh,
                            int E, float* __restrict__ out)
{
  const int lane = threadIdx.x & 63;
  const int wid = threadIdx.x >> 6;
  const int wpb = blockDim.x >> 6;
  const float invE = 1.0f / (float)E;
  float m = stats[lane] * invE;
  float var = stats[64 + lane] * invE - m * m;
  float inv = rsqrtf(var + BN_EPS_F);
  float gg = g[lane], bb = b[lane];
  float4 w = *(const float4*)&Wh[lane * 4];
  float b0 = bh[0], b1 = bh[1], b2 = bh[2], b3 = bh[3];
  for (int r = (int)blockIdx.x * wpb + wid; r < E; r += (int)gridDim.x * wpb) {
    float v = H[(size_t)r * 64 + lane];
    float o = fmaxf((v - m) * inv * gg + bb, 0.f);
    float a0 = o * w.x, a1 = o * w.y, a2 = o * w.z, a3 = o * w.w;
    #pragma unroll
    for (int s = 32; s > 0; s >>= 1) {
      a0 += __shfl_xor(a0, s, 64);
      a1 += __shfl_xor(a1, s, 64);
      a2 += __shfl_xor(a2, s, 64);
      a3 += __shfl_xor(a3, s, 64);
    }
    if (lane == 0) {
      float4 ov = make_float4(a0 + b0, a1 + b1, a2 + b2, a3 + b3);
      *(float4*)&out[(size_t)r * 4] = ov;
    }
  }
}

// -------------------- pool-1 top-k (radix select on u64 keys) --------------
__global__ void hist_kernel(const u64* __restrict__ keys, int E, u32* __restrict__ hist)
{
  for (int i = (int)blockIdx.x * blockDim.x + threadIdx.x; i < E;
       i += (int)gridDim.x * blockDim.x) {
    u32 bin = (u32)(keys[i] >> 44);
    atomicAdd(&hist[bin], 1u);
  }
}

__global__ void scan_kernel(const u32* __restrict__ hist, int K, u32* __restrict__ sel)
{
  __shared__ u32 csum[1024];
  __shared__ u32 sb2[1024];
  __shared__ int selChunk;
  __shared__ u32 aboveChunk;
  const int tid = threadIdx.x;
  {
    const uint4* hp = (const uint4*)(hist + (size_t)tid * 1024);
    u32 s = 0;
    for (int i = 0; i < 256; i++) {
      uint4 v = hp[i];
      s += v.x + v.y + v.z + v.w;
    }
    csum[tid] = s;
  }
  __syncthreads();
  if (tid == 0) {
    u32 above = 0; int sc = 0; u32 ab = 0;
    for (int t = 1023; t >= 0; t--) {
      if (above + csum[t] >= (u32)K) { sc = t; ab = above; break; }
      above += csum[t];
    }
    selChunk = sc; aboveChunk = ab;
  }
  __syncthreads();
  sb2[tid] = hist[(size_t)selChunk * 1024 + tid];
  __syncthreads();
  if (tid == 0) {
    u32 above = aboveChunk; int sb = 0;
    for (int t = 1023; t >= 0; t--) {
      u32 c = sb2[t];
      if (above + c >= (u32)K) { sb = t; break; }
      above += c;
    }
    sel[0] = (u32)(selChunk * 1024 + sb);
    sel[1] = above;
    sel[2] = (u32)K - above;
  }
}

__global__ void collect_kernel(const u64* __restrict__ keys, int E, const u32* __restrict__ sel,
                               u64* __restrict__ cand, u32* __restrict__ count)
{
  u32 bin = sel[0];
  for (int i = (int)blockIdx.x * blockDim.x + threadIdx.x; i < E;
       i += (int)gridDim.x * blockDim.x) {
    if ((u32)(keys[i] >> 44) == bin) {
      u32 p = atomicAdd(count, 1u);
      if (p < (u32)CAND_CAP) cand[p] = keys[i];
    }
  }
}

__global__ void thresh_kernel(const u64* __restrict__ cand, const u32* __restrict__ count,
                              const u32* __restrict__ sel, u64* __restrict__ thr)
{
  __shared__ u64 sk[CAND_CAP];
  const int tid = threadIdx.x;
  const int nth = blockDim.x;
  int n = (int)(*count > (u32)CAND_CAP ? (u32)CAND_CAP : *count);
  int n2 = 2; while (n2 < n) n2 <<= 1;
  for (int i = tid; i < n2; i += nth) sk[i] = (i < n) ? cand[i] : 0ull;
  __syncthreads();
  for (int k = 2; k <= n2; k <<= 1)
    for (int j = k >> 1; j > 0; j >>= 1) {
      for (int i = tid; i < n2; i += nth) {
        int p = i ^ j;
        if (p > i) {
          u64 a = sk[i], bb = sk[p];
          bool up = ((i & k) == 0);
          bool sw = up ? (a < bb) : (a > bb);
          if (sw) { sk[i] = bb; sk[p] = a; }
        }
      }
      __syncthreads();
    }
  if (tid == 0) {
    int kr = (int)sel[2];
    thr[0] = sk[kr - 1];
  }
}

// -------------------- ordered compaction: count / scan / scatter -----------
__global__ void keep_count_kernel(const u64* __restrict__ keys, int E,
                                  const u64* __restrict__ thrp, u32* __restrict__ bcnt)
{
  const u64 thr = thrp[0];
  const int tid = threadIdx.x;
  int base = (int)blockIdx.x * 1024 + tid * 4;
  u32 c = 0;
  #pragma unroll
  for (int u = 0; u < 4; u++) {
    int i = base + u;
    if (i < E && keys[i] >= thr) c++;
  }
  __shared__ u32 sm[256];
  sm[tid] = c;
  __syncthreads();
  for (int s = 128; s > 0; s >>= 1) {
    if (tid < s) sm[tid] += sm[tid + s];
    __syncthreads();
  }
  if (tid == 0) bcnt[blockIdx.x] = sm[0];
}

__global__ void keep_scan_kernel(const u32* __restrict__ bcnt, int NB, u32* __restrict__ boffs)
{
  __shared__ u32 sm[256];
  const int tid = threadIdx.x;
  u32 v = (tid < NB) ? bcnt[tid] : 0;
  sm[tid] = v;
  __syncthreads();
  for (int off = 1; off < 256; off <<= 1) {
    u32 t = 0;
    if (tid >= off) t = sm[tid - off];
    __syncthreads();
    sm[tid] += t;
    __syncthreads();
  }
  if (tid < NB) boffs[tid] = sm[tid] - v;
}

__global__ void keep_scatter_kernel(const u64* __restrict__ keys, int E,
                                    const u64* __restrict__ thrp, const u32* __restrict__ boffs,
                                    int* __restrict__ keep, int K)
{
  const u64 thr = thrp[0];
  const int tid = threadIdx.x;
  int base = (int)blockIdx.x * 1024 + tid * 4;
  u32 f[4]; u32 c = 0;
  #pragma unroll
  for (int u = 0; u < 4; u++) {
    int i = base + u;
    f[u] = (i < E && keys[i] >= thr) ? 1u : 0u;
    c += f[u];
  }
  __shared__ u32 sm[256];
  sm[tid] = c;
  __syncthreads();
  for (int off = 1; off < 256; off <<= 1) {
    u32 t = 0;
    if (tid >= off) t = sm[tid - off];
    __syncthreads();
    sm[tid] += t;
    __syncthreads();
  }
  u32 pos = boffs[blockIdx.x] + sm[tid] - c;
  #pragma unroll
  for (int u = 0; u < 4; u++) {
    if (f[u]) {
      if (pos < (u32)K) keep[pos] = base + u;
      pos++;
    }
  }
}

// -------------------- pools 2/3: single-block full sort (1024 thr) ----------
template<int NPOW>
__global__ void pool_select_kernel(const u64* __restrict__ keys, int E, int K,
                                   int* __restrict__ keep)
{
  __shared__ u64 sk[NPOW];
  __shared__ int si[NPOW];
  const int tid = threadIdx.x, nth = blockDim.x;
  for (int i = tid; i < NPOW; i += nth) sk[i] = (i < E) ? keys[i] : 0ull;
  __syncthreads();
  for (int k = 2; k <= NPOW; k <<= 1)
    for (int j = k >> 1; j > 0; j >>= 1) {
      for (int i = tid; i < NPOW; i += nth) {
        int p = i ^ j;
        if (p > i) {
          u64 a = sk[i], bb = sk[p];
          bool up = ((i & k) == 0);
          bool sw = up ? (a < bb) : (a > bb);
          if (sw) { sk[i] = bb; sk[p] = a; }
        }
      }
      __syncthreads();
    }
  for (int i = tid; i < NPOW; i += nth)
    si[i] = (i < K) ? (int)(0xFFFFFFFFu - (u32)(sk[i] & 0xFFFFFFFFull)) : 0x7FFFFFFF;
  __syncthreads();
  for (int k = 2; k <= NPOW; k <<= 1)
    for (int j = k >> 1; j > 0; j >>= 1) {
      for (int i = tid; i < NPOW; i += nth) {
        int p = i ^ j;
        if (p > i) {
          int a = si[i], bb = si[p];
          bool up = ((i & k) == 0);
          bool sw = up ? (a > bb) : (a < bb);
          if (sw) { si[i] = bb; si[p] = a; }
        }
      }
      __syncthreads();
    }
  for (int i = tid; i < K; i += nth) keep[i] = si[i];
}

template<int C, bool B16>
__global__ void pool_finish_kernel(const float* __restrict__ Xsrc, const int* __restrict__ nb_src,
                                   const int* __restrict__ keep, int K, int Esrc,
                                   float* __restrict__ Xp, ushort_t* __restrict__ Xpb,
                                   int* __restrict__ nbp)
{
  int total = K * C;
  for (int idx = (int)blockIdx.x * blockDim.x + threadIdx.x; idx < total;
       idx += (int)gridDim.x * blockDim.x) {
    int i = idx / C, c = idx % C;
    float v = Xsrc[(size_t)keep[i] * C + c];
    if constexpr (B16) Xpb[idx] = f2b(v);
    else Xp[idx] = v;
  }
  for (int idx = (int)blockIdx.x * blockDim.x + threadIdx.x; idx < K * 4;
       idx += (int)gridDim.x * blockDim.x) {
    int i = idx >> 2, j = idx & 3;
    int v = nb_src[(size_t)keep[i] * 4 + j];
    v = iclampi(v, 0, Esrc - 1);
    int p = bsearch_eq(keep, K, v);
    nbp[idx] = (p < 0) ? i : p;
  }
}

// unpool (nearest kept) + concat skip -> bf16, 8 cols/thread, 1 binsearch/thread
__global__ void unpool_cat_b16_kernel(const float* __restrict__ Xc, const float* __restrict__ Xs,
                                      const int* __restrict__ keep, int K, int E,
                                      int Cc, int Cs, ushort_t* __restrict__ out)
{
  int Ct = Cc + Cs;
  int Ct8 = Ct >> 3;
  int total = E * Ct8;
  for (int idx = (int)blockIdx.x * blockDim.x + threadIdx.x; idx < total;
       idx += (int)gridDim.x * blockDim.x) {
    int r = idx / Ct8, c = (idx % Ct8) << 3;
    const float* srcp;
    if (c < Cc) { int nn = nearest_keep(keep, K, r); srcp = &Xc[(size_t)nn * Cc + c]; }
    else srcp = &Xs[(size_t)r * Cs + (c - Cc)];
    float4 a = *(const float4*)srcp;
    float4 b = *(const float4*)(srcp + 4);
    ushort_t o[8];
    o[0] = f2b(a.x); o[1] = f2b(a.y); o[2] = f2b(a.z); o[3] = f2b(a.w);
    o[4] = f2b(b.x); o[5] = f2b(b.y); o[6] = f2b(b.z); o[7] = f2b(b.w);
    *(uint4*)&out[(size_t)r * Ct + c] = *(uint4*)o;
  }
}

__global__ void nn_map_kernel(const int* __restrict__ keep, int K, int E, int* __restrict__ nn)
{
  for (int i = (int)blockIdx.x * blockDim.x + threadIdx.x; i < E;
       i += (int)gridDim.x * blockDim.x)
    nn[i] = nearest_keep(keep, K, i);
}

// ---------------------------------------------------------------------------
extern "C" void kernel_launch(void* const* d_in, const int* in_sizes, int n_in,
                              void* d_out, int out_size, void* d_ws, size_t ws_size,
                              hipStream_t stream)
{
  (void)in_sizes; (void)n_in; (void)out_size; (void)ws_size;
  const float* x     = (const float*)d_in[0];
  const int*   nb    = (const int*)d_in[1];
  const float* W_e1  = (const float*)d_in[2];
  const float* g_e1  = (const float*)d_in[3];
  const float* b_e1  = (const float*)d_in[4];
  const float* W_e2  = (const float*)d_in[5];
  const float* g_e2  = (const float*)d_in[6];
  const float* b_e2  = (const float*)d_in[7];
  const float* W_e3  = (const float*)d_in[8];
  const float* g_e3  = (const float*)d_in[9];
  const float* b_e3  = (const float*)d_in[10];
  const float* W_e4  = (const float*)d_in[11];
  const float* g_e4  = (const float*)d_in[12];
  const float* b_e4  = (const float*)d_in[13];
  const float* W_d3  = (const float*)d_in[14];
  const float* g_d3  = (const float*)d_in[15];
  const float* b_d3  = (const float*)d_in[16];
  const float* W_d2  = (const float*)d_in[17];
  const float* g_d2  = (const float*)d_in[18];
  const float* b_d2  = (const float*)d_in[19];
  const float* W_d1  = (const float*)d_in[20];
  const float* g_d1  = (const float*)d_in[21];
  const float* b_d1  = (const float*)d_in[22];
  const float* W_head = (const float*)d_in[23];
  const float* bias_head = (const float*)d_in[24];
  float* out = (float*)d_out;

  char* p = (char*)d_ws;
  auto alloc = [&](size_t bytes) -> char* {
    char* q = p; p += (bytes + 255) & ~(size_t)255; return q;
  };

  // --- zero zone (one memset) ---
  char* zz = p;
  u32*   hist  = (u32*)alloc(sizeof(u32) * (1u << 20));
  float* stats = (float*)alloc(sizeof(float) * 2 * (64 + 128 + 256 + 512 + 256 + 128 + 64));
  u32*   ctrl  = (u32*)alloc(sizeof(u32) * 16);
  u64*   thr   = (u64*)alloc(sizeof(u64) * 2);
  u32*   sel   = (u32*)alloc(sizeof(u32) * 8);
  float* H2    = (float*)alloc(sizeof(float) * T1 * 128);   // split-K -> zeroed
  float* H3    = (float*)alloc(sizeof(float) * T2 * 256);   // split-K -> zeroed
  float* H4    = (float*)alloc(sizeof(float) * T3 * 512);   // split-K -> zeroed
  float* Hd3   = (float*)alloc(sizeof(float) * T2 * 256);   // split-K -> zeroed
  float* Hd2   = (float*)alloc(sizeof(float) * T1 * 128);   // split-K -> zeroed
  size_t zz_bytes = (size_t)(p - zz);
  // --- rest ---
  u32*   bcnt  = (u32*)alloc(sizeof(u32) * 256);
  u32*   boffs = (u32*)alloc(sizeof(u32) * 256);
  float* e1    = (float*)alloc(sizeof(float) * (size_t)E0 * 64);
  u64*   keys1 = (u64*)alloc(sizeof(u64) * E0);
  u64*   cand  = (u64*)alloc(sizeof(u64) * CAND_CAP);
  int*   keep1 = (int*)alloc(sizeof(int) * T1);
  float* e1p   = (float*)alloc(sizeof(float) * T1 * 64);
  int*   nb1   = (int*)alloc(sizeof(int) * T1 * 4);
  float* e2    = (float*)alloc(sizeof(float) * T1 * 128);
  u64*   keys2 = (u64*)alloc(sizeof(u64) * T1);
  int*   keep2 = (int*)alloc(sizeof(int) * T2);
  float* e2p   = (float*)alloc(sizeof(float) * T2 * 128);
  int*   nb2   = (int*)alloc(sizeof(int) * T2 * 4);
  float* e3    = (float*)alloc(sizeof(float) * T2 * 256);
  u64*   keys3 = (u64*)alloc(sizeof(u64) * T2);
  int*   keep3 = (int*)alloc(sizeof(int) * T3);
  ushort_t* e3pb = (ushort_t*)alloc(sizeof(ushort_t) * T3 * 256);
  int*   nb3   = (int*)alloc(sizeof(int) * T3 * 4);
  float* e4    = (float*)alloc(sizeof(float) * T3 * 512);
  ushort_t* d3catb = (ushort_t*)alloc(sizeof(ushort_t) * T2 * 768);
  float* d3    = (float*)alloc(sizeof(float) * T2 * 256);
  ushort_t* d2catb = (ushort_t*)alloc(sizeof(ushort_t) * T1 * 384);
  float* d2    = (float*)alloc(sizeof(float) * T1 * 128);
  int*   nn1   = (int*)alloc(sizeof(int) * E0);
  float* Hd1   = (float*)alloc(sizeof(float) * (size_t)E0 * 64);
  ushort_t* e1b = (ushort_t*)alloc(sizeof(ushort_t) * (size_t)E0 * 64);
  ushort_t* d2b = (ushort_t*)alloc(sizeof(ushort_t) * T1 * 128);
  ushort_t* Wt1 = (ushort_t*)alloc(sizeof(ushort_t) * 5 * 64 * 192);
  ushort_t* Wt4 = (ushort_t*)alloc(sizeof(ushort_t) * 5 * 512 * 256);
  ushort_t* Wtd3 = (ushort_t*)alloc(sizeof(ushort_t) * 5 * 256 * 768);
  ushort_t* Wtd2 = (ushort_t*)alloc(sizeof(ushort_t) * 5 * 128 * 384);

  float* s1  = stats;
  float* s2  = s1 + 2 * 64;
  float* s3  = s2 + 2 * 128;
  float* s4  = s3 + 2 * 256;
  float* sd3 = s4 + 2 * 512;
  float* sd2 = sd3 + 2 * 256;
  float* sd1 = sd2 + 2 * 128;

  hipMemsetAsync(zz, 0, zz_bytes, stream);
  const int PREP_TOTAL = 5 * (192 * 64 + 256 * 512 + 768 * 256 + 384 * 128);
  prep_all_kernel<<<dim3((PREP_TOTAL + 255) / 256), 256, 0, stream>>>(
      W_d1, W_e4, W_d3, W_d2, Wt1, Wt4, Wtd3, Wtd2);

  // ---- encoder 1 (fp32, pool-key-critical) ----
  e1_conv_kernel<<<dim3((E0 + 127) / 128), 256, 0, stream>>>(x, nb, W_e1, e1, s1);
  bn_kernel<64, true, true><<<dim3(8192), 256, 0, stream>>>(e1, s1, g_e1, b_e1, E0, e1, e1b, keys1);

  // ---- pool 1 (top-1500 of 200000) ----
  hist_kernel<<<dim3(782), 256, 0, stream>>>(keys1, E0, hist);
  scan_kernel<<<dim3(1), 1024, 0, stream>>>(hist, T1, sel);
  collect_kernel<<<dim3(782), 256, 0, stream>>>(keys1, E0, sel, cand, ctrl);
  thresh_kernel<<<dim3(1), 1024, 0, stream>>>(cand, ctrl, sel, thr);
  keep_count_kernel<<<dim3(NB_KEEP), 256, 0, stream>>>(keys1, E0, thr, bcnt);
  keep_scan_kernel<<<dim3(1), 256, 0, stream>>>(bcnt, NB_KEEP, boffs);
  keep_scatter_kernel<<<dim3(NB_KEEP), 256, 0, stream>>>(keys1, E0, thr, boffs, keep1, T1);
  pool_finish_kernel<64, false><<<dim3(380), 256, 0, stream>>>(e1, nb, keep1, T1, E0, e1p, nullptr, nb1);

  // ---- encoder 2 (fp32 split-K=2, pool-key-critical) ----
  conv_kernel<64, 128, 32, 64, 8, 2, 4, 2, false>
      <<<dim3((T1 + 31) / 32, 128 / 64, 2), 256, 0, stream>>>(e1p, nb1, T1, W_e2, H2, nullptr);
  stats_kernel<<<dim3((T1 + 63) / 64), 256, 0, stream>>>(H2, T1, 128, s2);
  bn_kernel<128, true, false><<<dim3(512), 256, 0, stream>>>(H2, s2, g_e2, b_e2, T1, e2, nullptr, keys2);
  pool_select_kernel<2048><<<dim3(1), 1024, 0, stream>>>(keys2, T1, T2, keep2);
  pool_finish_kernel<128, false><<<dim3(380), 256, 0, stream>>>(e2, nb1, keep2, T2, T1, e2p, nullptr, nb2);

  // ---- encoder 3 (fp32 split-K=4, pool-key-critical) ----
  conv_kernel<128, 256, 32, 64, 8, 2, 4, 4, false>
      <<<dim3((T2 + 31) / 32, 256 / 64, 4), 256, 0, stream>>>(e2p, nb2, T2, W_e3, H3, nullptr);
  stats_kernel<<<dim3((T2 + 63) / 64), 256, 0, stream>>>(H3, T2, 256, s3);
  bn_kernel<256, true, false><<<dim3(256), 256, 0, stream>>>(H3, s3, g_e3, b_e3, T2, e3, nullptr, keys3);
  pool_select_kernel<1024><<<dim3(1), 1024, 0, stream>>>(keys3, T2, T3, keep3);
  pool_finish_kernel<256, true><<<dim3(380), 256, 0, stream>>>(e3, nb2, keep3, T3, T2, nullptr, e3pb, nb3);

  // ---- encoder 4 (bf16 MFMA split-K=4) ----
  mfma_conv_kernel<256, 512, 4><<<dim3((T3 + 31) / 32, 512 / 64, 4), 128, 0, stream>>>(
      e3pb, nb3, T3, Wt4, H4);
  stats_kernel<<<dim3((T3 + 63) / 64), 256, 0, stream>>>(H4, T3, 512, s4);
  bn_kernel<512, false, false><<<dim3(128), 256, 0, stream>>>(
      H4, s4, g_e4, b_e4, T3, e4, nullptr, nullptr);

  // ---- decoder 3 (bf16 MFMA split-K=6) ----
  unpool_cat_b16_kernel<<<dim3((T2 * 768 / 8 + 255) / 256), 256, 0, stream>>>(
      e4, e3, keep3, T3, T2, 512, 256, d3catb);
  mfma_conv_kernel<768, 256, 6><<<dim3((T2 + 31) / 32, 256 / 64, 6), 128, 0, stream>>>(
      d3catb, nb2, T2, Wtd3, Hd3);
  stats_kernel<<<dim3((T2 + 63) / 64), 256, 0, stream>>>(Hd3, T2, 256, sd3);
  bn_kernel<256, false, false><<<dim3(256), 256, 0, stream>>>(
      Hd3, sd3, g_d3, b_d3, T2, d3, nullptr, nullptr);

  // ---- decoder 2 (bf16 MFMA split-K=3) ----
  unpool_cat_b16_kernel<<<dim3((T1 * 384 / 8 + 255) / 256), 256, 0, stream>>>(
      d3, e2, keep2, T2, T1, 256, 128, d2catb);
  mfma_conv_kernel<384, 128, 3><<<dim3((T1 + 31) / 32, 128 / 64, 3), 128, 0, stream>>>(
      d2catb, nb1, T1, Wtd2, Hd2);
  stats_kernel<<<dim3((T1 + 63) / 64), 256, 0, stream>>>(Hd2, T1, 128, sd2);
  bn_kernel<128, false, true><<<dim3(512), 256, 0, stream>>>(
      Hd2, sd2, g_d2, b_d2, T1, d2, d2b, nullptr);

  // ---- decoder 1 (bf16 MFMA, col-split — fastest measured variant) ----
  nn_map_kernel<<<dim3(782), 256, 0, stream>>>(keep1, T1, E0, nn1);
  d1_mfma_kernel<<<dim3((E0 + 127) / 128), 256, 0, stream>>>(d2b, e1b, nn1, nb, Wt1, Hd1, sd1);

  // ---- head (fused BN+ReLU+matmul) ----
  head_kernel<<<dim3(8192), 256, 0, stream>>>(Hd1, sd1, g_d1, b_d1, W_head, bias_head, E0, out);
}

// Round 11
// 980.187 us; speedup vs baseline: 2.6179x; 1.0077x over previous
//
#include <hip/hip_runtime.h>
#include <stdint.h>

typedef unsigned long long u64;
typedef unsigned int u32;
typedef unsigned short ushort_t;

#define FI __device__ __forceinline__

static constexpr float BN_EPS_F = 1e-5f;
static constexpr int E0 = 200000;
static constexpr int T1 = 1500, T2 = 750, T3 = 375;
static constexpr int CAND_CAP = 4096;
static constexpr int NB_KEEP = (E0 + 1023) / 1024;

typedef __attribute__((ext_vector_type(8))) short short8;
typedef __attribute__((ext_vector_type(4))) float f32x4;

FI int iclampi(int v, int lo, int hi) { return v < lo ? lo : (v > hi ? hi : v); }

FI ushort_t f2b(float f) {
  u32 u = __float_as_uint(f);
  u32 r = (u + 0x7FFFu + ((u >> 16) & 1u)) >> 16;
  return (ushort_t)r;
}

FI float b2f(ushort_t v) { return __uint_as_float(((u32)v) << 16); }

// bf16 >= 0 (post-ReLU) -> u16 order == numeric order
FI void u16minmax(const uint4& va, const uint4& vb, uint4& lo, uint4& hi) {
  const ushort_t* a = (const ushort_t*)&va;
  const ushort_t* b = (const ushort_t*)&vb;
  ushort_t* l = (ushort_t*)&lo;
  ushort_t* h = (ushort_t*)&hi;
  #pragma unroll
  for (int i = 0; i < 8; i++) {
    ushort_t x = a[i], y = b[i];
    l[i] = x < y ? x : y;
    h[i] = x < y ? y : x;
  }
}

FI int nearest_keep(const int* __restrict__ keep, int K, int idx) {
  int lo = 0, hi = K;
  while (lo < hi) { int mid = (lo + hi) >> 1; if (keep[mid] < idx) lo = mid + 1; else hi = mid; }
  int l = lo - 1; l = l < 0 ? 0 : (l > K - 1 ? K - 1 : l);
  int r = lo;     r = r < 0 ? 0 : (r > K - 1 ? K - 1 : r);
  int dl = idx - keep[l]; dl = dl < 0 ? -dl : dl;
  int dr = idx - keep[r]; dr = dr < 0 ? -dr : dr;
  return (dl <= dr) ? l : r;
}

FI int bsearch_eq(const int* __restrict__ keep, int K, int v) {
  int lo = 0, hi = K;
  while (lo < hi) { int mid = (lo + hi) >> 1; if (keep[mid] < v) lo = mid + 1; else hi = mid; }
  if (lo < K && keep[lo] == v) return lo;
  return -1;
}

// ---------------------------------------------------------------------------
// Generic fp32 mesh-conv (split-K) — e2/e3 (pool-key layers).
// ---------------------------------------------------------------------------
template<int C, int Cout, int BR, int BC, int KT, int TR, int TC, int KSPLIT,
         bool FUSE_STATS>
__global__ __launch_bounds__((BR / TR) * (BC / TC))
void conv_kernel(const float* __restrict__ X,
                 const int* __restrict__ nb, int E,
                 const float* __restrict__ W,
                 float* __restrict__ H, float* __restrict__ stats)
{
  constexpr int NTH = (BR / TR) * (BC / TC);
  constexpr int VK = 5 * KT;
  constexpr int KC = C / KSPLIT;
  static_assert(KC % KT == 0, "KC % KT");

  const int row0 = blockIdx.x * BR;
  const int col0 = blockIdx.y * BC;
  const int c_begin = (KSPLIT > 1) ? (int)blockIdx.z * KC : 0;

  __shared__ float As[VK][BR];
  __shared__ float Bs[VK][BC];
  __shared__ int rowsS[5][BR];
  __shared__ float red[FUSE_STATS ? 2 * (BR / TR) * BC : 1];

  const int tid = threadIdx.x;

  for (int q = tid; q < BR; q += NTH) {
    int r = row0 + q;
    int rr[5];
    if (r < E) {
      rr[0] = r;
      #pragma unroll
      for (int j = 0; j < 4; j++) {
        int v = nb[(size_t)r * 4 + j];
        rr[1 + j] = iclampi(v, 0, E - 1);
      }
    } else {
      #pragma unroll
      for (int j = 0; j < 5; j++) rr[j] = -1;
    }
    #pragma unroll
    for (int j = 0; j < 5; j++) rowsS[j][q] = rr[j];
  }

  float acc[TR][TC];
  #pragma unroll
  for (int i = 0; i < TR; i++)
    #pragma unroll
    for (int j = 0; j < TC; j++) acc[i][j] = 0.f;

  const int tr = tid / (BC / TC);
  const int tc = tid % (BC / TC);
  const int rA = tr * TR;
  const int cB = tc * TC;

  for (int c0 = c_begin; c0 < c_begin + KC; c0 += KT) {
    __syncthreads();
    for (int q = tid; q < VK * (BC / 4); q += NTH) {
      int kk = q / (BC / 4);
      int c4 = q % (BC / 4);
      int p = kk / KT, t = kk % KT;
      float4 wv = *(const float4*)&W[(size_t)(p * C + c0 + t) * Cout + col0 + c4 * 4];
      *(float4*)&Bs[kk][c4 * 4] = wv;
    }
    for (int q = tid; q < BR * KT; q += NTH) {
      int t = q % KT, rq = q / KT;
      int c = c0 + t;
      float s0 = 0.f, a1 = 0.f, a2 = 0.f, a3 = 0.f, a4 = 0.f;
      if (rowsS[0][rq] >= 0) {
        float v0, v1, v2, v3;
        s0 = X[(size_t)rowsS[0][rq] * C + c];
        v0 = X[(size_t)rowsS[1][rq] * C + c];
        v1 = X[(size_t)rowsS[2][rq] * C + c];
        v2 = X[(size_t)rowsS[3][rq] * C + c];
        v3 = X[(size_t)rowsS[4][rq] * C + c];
        a1 = fminf(v0, v1); a2 = fmaxf(v0, v1);
        a3 = fminf(v2, v3); a4 = fmaxf(v2, v3);
      }
      As[0 * KT + t][rq] = s0;
      As[1 * KT + t][rq] = a1;
      As[2 * KT + t][rq] = a2;
      As[3 * KT + t][rq] = a3;
      As[4 * KT + t][rq] = a4;
    }
    __syncthreads();

    for (int kk = 0; kk < VK; kk++) {
      float a[TR], b[TC];
      #pragma unroll
      for (int i = 0; i < TR; i++) a[i] = As[kk][rA + i];
      #pragma unroll
      for (int j = 0; j < TC; j++) b[j] = Bs[kk][cB + j];
      #pragma unroll
      for (int i = 0; i < TR; i++)
        #pragma unroll
        for (int j = 0; j < TC; j++)
          acc[i][j] = fmaf(a[i], b[j], acc[i][j]);
    }
  }

  #pragma unroll
  for (int i = 0; i < TR; i++) {
    int r = row0 + rA + i;
    if (r < E) {
      if constexpr (KSPLIT > 1) {
        #pragma unroll
        for (int j = 0; j < TC; j++)
          atomicAdd(&H[(size_t)r * Cout + col0 + cB + j], acc[i][j]);
      } else {
        #pragma unroll
        for (int j = 0; j < TC; j += 4) {
          float4 v = make_float4(acc[i][j], acc[i][j + 1], acc[i][j + 2], acc[i][j + 3]);
          *(float4*)&H[(size_t)r * Cout + col0 + cB + j] = v;
        }
      }
    }
  }

  if constexpr (FUSE_STATS) {
    float s[TC], q2[TC];
    #pragma unroll
    for (int j = 0; j < TC; j++) { s[j] = 0.f; q2[j] = 0.f; }
    #pragma unroll
    for (int i = 0; i < TR; i++) {
      int r = row0 + rA + i;
      if (r < E) {
        #pragma unroll
        for (int j = 0; j < TC; j++) { float v = acc[i][j]; s[j] += v; q2[j] += v * v; }
      }
    }
    __syncthreads();
    float* redS = &red[0];
    float* redQ = &red[(BR / TR) * BC];
    #pragma unroll
    for (int j = 0; j < TC; j++) {
      redS[tr * BC + cB + j] = s[j];
      redQ[tr * BC + cB + j] = q2[j];
    }
    __syncthreads();
    for (int col = tid; col < BC; col += NTH) {
      float ts = 0.f, tq = 0.f;
      for (int g = 0; g < BR / TR; g++) { ts += redS[g * BC + col]; tq += redQ[g * BC + col]; }
      atomicAdd(&stats[col0 + col], ts);
      atomicAdd(&stats[Cout + col0 + col], tq);
    }
  }
}

// ---------------------------------------------------------------------------
// Dedicated e1 conv (C=5, Cout=64): vectorized row gathers, W in LDS, stats.
// ---------------------------------------------------------------------------
__global__ __launch_bounds__(256)
void e1_conv_kernel(const float* __restrict__ X, const int* __restrict__ nb,
                    const float* __restrict__ W,
                    float* __restrict__ H, float* __restrict__ stats)
{
  __shared__ float As[25][128];
  __shared__ float Bs[25][64];
  __shared__ float red[2 * 32 * 64];

  const int tid = threadIdx.x;
  const int row0 = (int)blockIdx.x * 128;

  if (tid < 128) {
    int r = row0 + tid; if (r > E0 - 1) r = E0 - 1;
    int rs[5];
    rs[0] = r;
    #pragma unroll
    for (int j = 0; j < 4; j++) rs[1 + j] = iclampi((int)nb[(size_t)r * 4 + j], 0, E0 - 1);
    float v[5][5];
    #pragma unroll
    for (int j = 0; j < 5; j++) {
      const float* src = &X[(size_t)rs[j] * 5];
      float4 a = *(const float4*)src;
      v[j][0] = a.x; v[j][1] = a.y; v[j][2] = a.z; v[j][3] = a.w;
      v[j][4] = src[4];
    }
    #pragma unroll
    for (int c = 0; c < 5; c++) {
      As[0 * 5 + c][tid] = v[0][c];
      As[1 * 5 + c][tid] = fminf(v[1][c], v[2][c]);
      As[2 * 5 + c][tid] = fmaxf(v[1][c], v[2][c]);
      As[3 * 5 + c][tid] = fminf(v[3][c], v[4][c]);
      As[4 * 5 + c][tid] = fmaxf(v[3][c], v[4][c]);
    }
  } else {
    for (int q = tid - 128; q < 25 * 16; q += 128) {
      int k = q / 16, c4 = q % 16;
      float4 wv = *(const float4*)&W[(size_t)k * 64 + c4 * 4];
      *(float4*)&Bs[k][c4 * 4] = wv;
    }
  }
  __syncthreads();

  const int tr = tid >> 3;
  const int tc = tid & 7;
  const int rA = tr * 4;
  const int cB = tc * 8;

  float acc[4][8];
  #pragma unroll
  for (int i = 0; i < 4; i++)
    #pragma unroll
    for (int j = 0; j < 8; j++) acc[i][j] = 0.f;

  for (int k = 0; k < 25; k++) {
    float a[4], b[8];
    #pragma unroll
    for (int i = 0; i < 4; i++) a[i] = As[k][rA + i];
    #pragma unroll
    for (int j = 0; j < 8; j++) b[j] = Bs[k][cB + j];
    #pragma unroll
    for (int i = 0; i < 4; i++)
      #pragma unroll
      for (int j = 0; j < 8; j++)
        acc[i][j] = fmaf(a[i], b[j], acc[i][j]);
  }

  float s[8], q2[8];
  #pragma unroll
  for (int j = 0; j < 8; j++) { s[j] = 0.f; q2[j] = 0.f; }
  #pragma unroll
  for (int i = 0; i < 4; i++) {
    int r = row0 + rA + i;
    if (r < E0) {
      #pragma unroll
      for (int j = 0; j < 8; j += 4) {
        float4 v = make_float4(acc[i][j], acc[i][j + 1], acc[i][j + 2], acc[i][j + 3]);
        *(float4*)&H[(size_t)r * 64 + cB + j] = v;
      }
      #pragma unroll
      for (int j = 0; j < 8; j++) { float v = acc[i][j]; s[j] += v; q2[j] += v * v; }
    }
  }
  __syncthreads();
  float* redS = &red[0];
  float* redQ = &red[32 * 64];
  #pragma unroll
  for (int j = 0; j < 8; j++) {
    redS[tr * 64 + cB + j] = s[j];
    redQ[tr * 64 + cB + j] = q2[j];
  }
  __syncthreads();
  for (int col = tid; col < 64; col += 256) {
    float ts = 0.f, tq = 0.f;
    for (int g = 0; g < 32; g++) { ts += redS[g * 64 + col]; tq += redQ[g * 64 + col]; }
    atomicAdd(&stats[col], ts);
    atomicAdd(&stats[64 + col], tq);
  }
}

// ---------------------------------------------------------------------------
// Generic bf16 MFMA mesh-conv (e4/d3/d2) — split-K for occupancy.
// ---------------------------------------------------------------------------
template<int C, int Cout, int KSPLIT>
__global__ __launch_bounds__(128)
void mfma_conv_kernel(const ushort_t* __restrict__ src,
                      const int* __restrict__ nb, int E,
                      const ushort_t* __restrict__ Wt,
                      float* __restrict__ H)
{
  constexpr int NCC_T = C / 32;
  constexpr int NCC = NCC_T / KSPLIT;
  static_assert(NCC_T % KSPLIT == 0, "NCC_T % KSPLIT");
  __shared__ int rows[5][32];

  const int tid = threadIdx.x;
  const int lane = tid & 63;
  const int wv = tid >> 6;
  const int l15 = lane & 15;
  const int quad = lane >> 4;
  const int row0 = (int)blockIdx.x * 32;
  const int col0 = (int)blockIdx.y * 64;
  const int cc0 = (KSPLIT > 1) ? (int)blockIdx.z * NCC : 0;

  if (tid < 32) {
    int r = row0 + tid; if (r > E - 1) r = E - 1;
    rows[0][tid] = r;
    #pragma unroll
    for (int j = 0; j < 4; j++) rows[1 + j][tid] = iclampi(nb[(size_t)r * 4 + j], 0, E - 1);
  }
  __syncthreads();

  const int rr = wv * 16 + l15;
  int r5[5];
  #pragma unroll
  for (int j = 0; j < 5; j++) r5[j] = rows[j][rr];

  f32x4 acc[4];
  #pragma unroll
  for (int ni = 0; ni < 4; ni++) acc[ni] = (f32x4){0.f, 0.f, 0.f, 0.f};

  uint4 raw[2][5];
  auto loadcc = [&](int par, int cc2) {
    int cb = (cc0 + cc2) * 32 + quad * 8;
    #pragma unroll
    for (int j = 0; j < 5; j++)
      raw[par][j] = *(const uint4*)&src[(size_t)r5[j] * C + cb];
  };

  loadcc(0, 0);
  #pragma unroll
  for (int cc = 0; cc < NCC; cc++) {
    const int par = cc & 1;
    if (cc + 1 < NCC) loadcc(par ^ 1, cc + 1);
    short8 a[5];
    a[0] = *(short8*)&raw[par][0];
    {
      uint4 lo, hi;
      u16minmax(raw[par][1], raw[par][2], lo, hi);
      a[1] = *(short8*)&lo; a[2] = *(short8*)&hi;
    }
    {
      uint4 lo, hi;
      u16minmax(raw[par][3], raw[par][4], lo, hi);
      a[3] = *(short8*)&lo; a[4] = *(short8*)&hi;
    }
    #pragma unroll
    for (int p = 0; p < 5; p++) {
      #pragma unroll
      for (int ni = 0; ni < 4; ni++) {
        short8 bf = *(const short8*)&Wt[((size_t)(p * Cout + col0 + ni * 16 + l15)) * C + (cc0 + cc) * 32 + quad * 8];
        acc[ni] = __builtin_amdgcn_mfma_f32_16x16x32_bf16(a[p], bf, acc[ni], 0, 0, 0);
      }
    }
  }

  #pragma unroll
  for (int reg = 0; reg < 4; reg++) {
    int r = row0 + wv * 16 + quad * 4 + reg;
    if (r < E) {
      #pragma unroll
      for (int ni = 0; ni < 4; ni++) {
        if constexpr (KSPLIT > 1)
          atomicAdd(&H[(size_t)r * Cout + col0 + ni * 16 + l15], acc[ni][reg]);
        else
          H[(size_t)r * Cout + col0 + ni * 16 + l15] = acc[ni][reg];
      }
    }
  }
}

// ---------------------------------------------------------------------------
// d1 conv via bf16 MFMA — col-split; keep1 staged in LDS, nearest_keep inline;
// Hd1 emitted as bf16 (head-only consumer). Stats from fp32 registers.
// ---------------------------------------------------------------------------
__global__ __launch_bounds__(256, 4)
void d1_mfma_kernel(const ushort_t* __restrict__ d2b, const ushort_t* __restrict__ e1b,
                    const int* __restrict__ keep1, const int* __restrict__ nb,
                    const ushort_t* __restrict__ Wt,
                    ushort_t* __restrict__ Hb, float* __restrict__ stats)
{
  __shared__ int rowsD[5][128];
  __shared__ int rowsS[5][128];
  __shared__ int keepL[T1];

  const int tid = threadIdx.x;
  const int lane = tid & 63;
  const int wv = tid >> 6;          // col-strip
  const int l15 = lane & 15;
  const int quad = lane >> 4;
  const int row0 = (int)blockIdx.x * 128;

  for (int i = tid; i < T1; i += 256) keepL[i] = keep1[i];
  __syncthreads();

  if (tid < 128) {
    int r = row0 + tid; if (r > E0 - 1) r = E0 - 1;
    int rs[5];
    rs[0] = r;
    #pragma unroll
    for (int j = 0; j < 4; j++) rs[1 + j] = iclampi((int)nb[(size_t)r * 4 + j], 0, E0 - 1);
    #pragma unroll
    for (int j = 0; j < 5; j++) {
      rowsS[j][tid] = rs[j];
      rowsD[j][tid] = nearest_keep(keepL, T1, rs[j]);
    }
  }
  __syncthreads();

  f32x4 acc[8];
  #pragma unroll
  for (int mi = 0; mi < 8; mi++) acc[mi] = (f32x4){0.f, 0.f, 0.f, 0.f};

  for (int cc = 0; cc < 6; cc++) {
    const bool fromD = cc < 4;
    const ushort_t* __restrict__ src = fromD ? d2b : e1b;
    const int stride = fromD ? 128 : 64;
    const int cbase = (fromD ? cc * 32 : (cc - 4) * 32) + quad * 8;

    short8 bf[5];
    #pragma unroll
    for (int p = 0; p < 5; p++)
      bf[p] = *(const short8*)&Wt[((size_t)(p * 64 + wv * 16 + l15)) * 192 + cc * 32 + quad * 8];

    #pragma unroll 2
    for (int mi = 0; mi < 8; mi++) {
      int rr = mi * 16 + l15;
      int r0, r1, r2, r3, r4;
      if (fromD) {
        r0 = rowsD[0][rr]; r1 = rowsD[1][rr]; r2 = rowsD[2][rr];
        r3 = rowsD[3][rr]; r4 = rowsD[4][rr];
      } else {
        r0 = rowsS[0][rr]; r1 = rowsS[1][rr]; r2 = rowsS[2][rr];
        r3 = rowsS[3][rr]; r4 = rowsS[4][rr];
      }
      uint4 v0 = *(const uint4*)&src[(size_t)r0 * stride + cbase];
      uint4 v1 = *(const uint4*)&src[(size_t)r1 * stride + cbase];
      uint4 v2 = *(const uint4*)&src[(size_t)r2 * stride + cbase];
      uint4 v3 = *(const uint4*)&src[(size_t)r3 * stride + cbase];
      uint4 v4 = *(const uint4*)&src[(size_t)r4 * stride + cbase];

      uint4 lo12, hi12, lo34, hi34;
      u16minmax(v1, v2, lo12, hi12);
      u16minmax(v3, v4, lo34, hi34);

      acc[mi] = __builtin_amdgcn_mfma_f32_16x16x32_bf16(*(short8*)&v0,   bf[0], acc[mi], 0, 0, 0);
      acc[mi] = __builtin_amdgcn_mfma_f32_16x16x32_bf16(*(short8*)&lo12, bf[1], acc[mi], 0, 0, 0);
      acc[mi] = __builtin_amdgcn_mfma_f32_16x16x32_bf16(*(short8*)&hi12, bf[2], acc[mi], 0, 0, 0);
      acc[mi] = __builtin_amdgcn_mfma_f32_16x16x32_bf16(*(short8*)&lo34, bf[3], acc[mi], 0, 0, 0);
      acc[mi] = __builtin_amdgcn_mfma_f32_16x16x32_bf16(*(short8*)&hi34, bf[4], acc[mi], 0, 0, 0);
    }
  }

  const int col = wv * 16 + l15;
  float s = 0.f, q = 0.f;
  #pragma unroll
  for (int mi = 0; mi < 8; mi++) {
    #pragma unroll
    for (int reg = 0; reg < 4; reg++) {
      int r = row0 + mi * 16 + quad * 4 + reg;
      if (r < E0) {
        float v = acc[mi][reg];
        Hb[(size_t)r * 64 + col] = f2b(v);
        s += v; q += v * v;
      }
    }
  }
  s += __shfl_xor(s, 16); q += __shfl_xor(q, 16);
  s += __shfl_xor(s, 32); q += __shfl_xor(q, 32);
  if (quad == 0) {
    atomicAdd(&stats[col], s);
    atomicAdd(&stats[64 + col], q);
  }
}

// All weight transposes in one kernel: W (5C x Cout fp32) -> Wt bf16 [(p*Cout+n)][C]
FI void prep_one(const float* __restrict__ W, ushort_t* __restrict__ Wt,
                 int C, int Cout, int i)
{
  int n = i % Cout;
  int k = i / Cout;
  int p = k / C, c = k % C;
  Wt[((size_t)(p * Cout + n)) * C + c] = f2b(W[(size_t)k * Cout + n]);
}

__global__ void prep_all_kernel(const float* __restrict__ W1, const float* __restrict__ W4,
                                const float* __restrict__ Wd3, const float* __restrict__ Wd2,
                                ushort_t* __restrict__ Wt1, ushort_t* __restrict__ Wt4,
                                ushort_t* __restrict__ Wtd3, ushort_t* __restrict__ Wtd2)
{
  int idx = (int)blockIdx.x * 256 + threadIdx.x;
  const int S1 = 5 * 192 * 64, S4 = 5 * 256 * 512, Sd3 = 5 * 768 * 256, Sd2 = 5 * 384 * 128;
  if (idx < S1) { prep_one(W1, Wt1, 192, 64, idx); return; }
  idx -= S1;
  if (idx < S4) { prep_one(W4, Wt4, 256, 512, idx); return; }
  idx -= S4;
  if (idx < Sd3) { prep_one(Wd3, Wtd3, 768, 256, idx); return; }
  idx -= Sd3;
  if (idx < Sd2) { prep_one(Wd2, Wtd2, 384, 128, idx); return; }
}

// column sum/sumsq for split-K layers
__global__ void stats_kernel(const float* __restrict__ H, int E, int Cout,
                             float* __restrict__ stats)
{
  const int RB = 64;
  int r0 = (int)blockIdx.x * RB;
  int rend = r0 + RB; if (rend > E) rend = E;
  for (int col = threadIdx.x; col < Cout; col += blockDim.x) {
    float s = 0.f, q = 0.f;
    for (int r = r0; r < rend; r++) { float v = H[(size_t)r * Cout + col]; s += v; q += v * v; }
    atomicAdd(&stats[col], s);
    atomicAdd(&stats[Cout + col], q);
  }
}

// BN(training stats) + ReLU; optional pooling key; optional fp32/bf16 outputs
template<int Cout, bool KEYS, bool F32, bool B16>
__global__ void bn_kernel(const float* __restrict__ H, const float* __restrict__ stats,
                          const float* __restrict__ g, const float* __restrict__ b,
                          int E, float* __restrict__ Out, ushort_t* __restrict__ Outb,
                          u64* __restrict__ keys)
{
  constexpr int CPL = Cout / 64;
  const int lane = threadIdx.x & 63;
  const int wid = threadIdx.x >> 6;
  const int wpb = blockDim.x >> 6;
  const float invE = 1.0f / (float)E;
  float mu[CPL], inv[CPL], gg[CPL], bb[CPL];
  #pragma unroll
  for (int u = 0; u < CPL; u++) {
    int c = lane + u * 64;
    float m = stats[c] * invE;
    float var = stats[Cout + c] * invE - m * m;
    mu[u] = m;
    inv[u] = rsqrtf(var + BN_EPS_F);
    gg[u] = g[c]; bb[u] = b[c];
  }
  for (int r = (int)blockIdx.x * wpb + wid; r < E; r += (int)gridDim.x * wpb) {
    float ss = 0.f;
    #pragma unroll
    for (int u = 0; u < CPL; u++) {
      int c = lane + u * 64;
      float v = H[(size_t)r * Cout + c];
      float o = (v - mu[u]) * inv[u] * gg[u] + bb[u];
      o = fmaxf(o, 0.f);
      if constexpr (F32) Out[(size_t)r * Cout + c] = o;
      if constexpr (B16) Outb[(size_t)r * Cout + c] = f2b(o);
      ss += o * o;
    }
    if constexpr (KEYS) {
      #pragma unroll
      for (int s = 32; s > 0; s >>= 1) ss += __shfl_xor(ss, s, 64);
      if (lane == 0) {
        float sc = sqrtf(ss);
        u32 sb = __float_as_uint(sc);
        keys[r] = ((u64)sb << 32) | (u64)(0xFFFFFFFFu - (u32)r);
      }
    }
  }
}

// fused BN+ReLU+head matmul (bf16 Hd1 -> 4 fp32)
__global__ void head_kernel(const ushort_t* __restrict__ Hb, const float* __restrict__ stats,
                            const float* __restrict__ g, const float* __restrict__ b,
                            const float* __restrict__ Wh, const float* __restrict__ bh,
                            int E, float* __restrict__ out)
{
  const int lane = threadIdx.x & 63;
  const int wid = threadIdx.x >> 6;
  const int wpb = blockDim.x >> 6;
  const float invE = 1.0f / (float)E;
  float m = stats[lane] * invE;
  float var = stats[64 + lane] * invE - m * m;
  float inv = rsqrtf(var + BN_EPS_F);
  float gg = g[lane], bb = b[lane];
  float4 w = *(const float4*)&Wh[lane * 4];
  float b0 = bh[0], b1 = bh[1], b2 = bh[2], b3 = bh[3];
  for (int r = (int)blockIdx.x * wpb + wid; r < E; r += (int)gridDim.x * wpb) {
    float v = b2f(Hb[(size_t)r * 64 + lane]);
    float o = fmaxf((v - m) * inv * gg + bb, 0.f);
    float a0 = o * w.x, a1 = o * w.y, a2 = o * w.z, a3 = o * w.w;
    #pragma unroll
    for (int s = 32; s > 0; s >>= 1) {
      a0 += __shfl_xor(a0, s, 64);
      a1 += __shfl_xor(a1, s, 64);
      a2 += __shfl_xor(a2, s, 64);
      a3 += __shfl_xor(a3, s, 64);
    }
    if (lane == 0) {
      float4 ov = make_float4(a0 + b0, a1 + b1, a2 + b2, a3 + b3);
      *(float4*)&out[(size_t)r * 4] = ov;
    }
  }
}

// -------------------- pool-1 top-k (radix select on u64 keys) --------------
__global__ void hist_kernel(const u64* __restrict__ keys, int E, u32* __restrict__ hist)
{
  for (int i = (int)blockIdx.x * blockDim.x + threadIdx.x; i < E;
       i += (int)gridDim.x * blockDim.x) {
    u32 bin = (u32)(keys[i] >> 44);
    atomicAdd(&hist[bin], 1u);
  }
}

__global__ void scan_kernel(const u32* __restrict__ hist, int K, u32* __restrict__ sel)
{
  __shared__ u32 csum[1024];
  __shared__ u32 sb2[1024];
  __shared__ int selChunk;
  __shared__ u32 aboveChunk;
  const int tid = threadIdx.x;
  {
    const uint4* hp = (const uint4*)(hist + (size_t)tid * 1024);
    u32 s = 0;
    for (int i = 0; i < 256; i++) {
      uint4 v = hp[i];
      s += v.x + v.y + v.z + v.w;
    }
    csum[tid] = s;
  }
  __syncthreads();
  if (tid == 0) {
    u32 above = 0; int sc = 0; u32 ab = 0;
    for (int t = 1023; t >= 0; t--) {
      if (above + csum[t] >= (u32)K) { sc = t; ab = above; break; }
      above += csum[t];
    }
    selChunk = sc; aboveChunk = ab;
  }
  __syncthreads();
  sb2[tid] = hist[(size_t)selChunk * 1024 + tid];
  __syncthreads();
  if (tid == 0) {
    u32 above = aboveChunk; int sb = 0;
    for (int t = 1023; t >= 0; t--) {
      u32 c = sb2[t];
      if (above + c >= (u32)K) { sb = t; break; }
      above += c;
    }
    sel[0] = (u32)(selChunk * 1024 + sb);
    sel[1] = above;
    sel[2] = (u32)K - above;
  }
}

__global__ void collect_kernel(const u64* __restrict__ keys, int E, const u32* __restrict__ sel,
                               u64* __restrict__ cand, u32* __restrict__ count)
{
  u32 bin = sel[0];
  for (int i = (int)blockIdx.x * blockDim.x + threadIdx.x; i < E;
       i += (int)gridDim.x * blockDim.x) {
    if ((u32)(keys[i] >> 44) == bin) {
      u32 p = atomicAdd(count, 1u);
      if (p < (u32)CAND_CAP) cand[p] = keys[i];
    }
  }
}

__global__ void thresh_kernel(const u64* __restrict__ cand, const u32* __restrict__ count,
                              const u32* __restrict__ sel, u64* __restrict__ thr)
{
  __shared__ u64 sk[CAND_CAP];
  const int tid = threadIdx.x;
  const int nth = blockDim.x;
  int n = (int)(*count > (u32)CAND_CAP ? (u32)CAND_CAP : *count);
  int n2 = 2; while (n2 < n) n2 <<= 1;
  for (int i = tid; i < n2; i += nth) sk[i] = (i < n) ? cand[i] : 0ull;
  __syncthreads();
  for (int k = 2; k <= n2; k <<= 1)
    for (int j = k >> 1; j > 0; j >>= 1) {
      for (int i = tid; i < n2; i += nth) {
        int p = i ^ j;
        if (p > i) {
          u64 a = sk[i], bb = sk[p];
          bool up = ((i & k) == 0);
          bool sw = up ? (a < bb) : (a > bb);
          if (sw) { sk[i] = bb; sk[p] = a; }
        }
      }
      __syncthreads();
    }
  if (tid == 0) {
    int kr = (int)sel[2];
    thr[0] = sk[kr - 1];
  }
}

// -------------------- ordered compaction: count / scatter(own-scan) --------
__global__ void keep_count_kernel(const u64* __restrict__ keys, int E,
                                  const u64* __restrict__ thrp, u32* __restrict__ bcnt)
{
  const u64 thr = thrp[0];
  const int tid = threadIdx.x;
  int base = (int)blockIdx.x * 1024 + tid * 4;
  u32 c = 0;
  #pragma unroll
  for (int u = 0; u < 4; u++) {
    int i = base + u;
    if (i < E && keys[i] >= thr) c++;
  }
  __shared__ u32 sm[256];
  sm[tid] = c;
  __syncthreads();
  for (int s = 128; s > 0; s >>= 1) {
    if (tid < s) sm[tid] += sm[tid + s];
    __syncthreads();
  }
  if (tid == 0) bcnt[blockIdx.x] = sm[0];
}

__global__ void keep_scatter_kernel(const u64* __restrict__ keys, int E,
                                    const u64* __restrict__ thrp, const u32* __restrict__ bcnt,
                                    int NB, int* __restrict__ keep, int K)
{
  const u64 thr = thrp[0];
  const int tid = threadIdx.x;

  // exclusive prefix of bcnt over blocks (computed per-block from tiny array)
  __shared__ u32 pre[256];
  __shared__ u32 base0;
  u32 bv = (tid < NB) ? bcnt[tid] : 0;
  pre[tid] = bv;
  __syncthreads();
  for (int off = 1; off < 256; off <<= 1) {
    u32 t = 0;
    if (tid >= off) t = pre[tid - off];
    __syncthreads();
    pre[tid] += t;
    __syncthreads();
  }
  if (tid == 0) base0 = (blockIdx.x == 0) ? 0u : pre[blockIdx.x - 1];
  __syncthreads();

  int base = (int)blockIdx.x * 1024 + tid * 4;
  u32 f[4]; u32 c = 0;
  #pragma unroll
  for (int u = 0; u < 4; u++) {
    int i = base + u;
    f[u] = (i < E && keys[i] >= thr) ? 1u : 0u;
    c += f[u];
  }
  __shared__ u32 sm[256];
  sm[tid] = c;
  __syncthreads();
  for (int off = 1; off < 256; off <<= 1) {
    u32 t = 0;
    if (tid >= off) t = sm[tid - off];
    __syncthreads();
    sm[tid] += t;
    __syncthreads();
  }
  u32 pos = base0 + sm[tid] - c;
  #pragma unroll
  for (int u = 0; u < 4; u++) {
    if (f[u]) {
      if (pos < (u32)K) keep[pos] = base + u;
      pos++;
    }
  }
}

// -------------------- pools 2/3: single-block full sort (1024 thr) ----------
template<int NPOW>
__global__ void pool_select_kernel(const u64* __restrict__ keys, int E, int K,
                                   int* __restrict__ keep)
{
  __shared__ u64 sk[NPOW];
  __shared__ int si[NPOW];
  const int tid = threadIdx.x, nth = blockDim.x;
  for (int i = tid; i < NPOW; i += nth) sk[i] = (i < E) ? keys[i] : 0ull;
  __syncthreads();
  for (int k = 2; k <= NPOW; k <<= 1)
    for (int j = k >> 1; j > 0; j >>= 1) {
      for (int i = tid; i < NPOW; i += nth) {
        int p = i ^ j;
        if (p > i) {
          u64 a = sk[i], bb = sk[p];
          bool up = ((i & k) == 0);
          bool sw = up ? (a < bb) : (a > bb);
          if (sw) { sk[i] = bb; sk[p] = a; }
        }
      }
      __syncthreads();
    }
  for (int i = tid; i < NPOW; i += nth)
    si[i] = (i < K) ? (int)(0xFFFFFFFFu - (u32)(sk[i] & 0xFFFFFFFFull)) : 0x7FFFFFFF;
  __syncthreads();
  for (int k = 2; k <= NPOW; k <<= 1)
    for (int j = k >> 1; j > 0; j >>= 1) {
      for (int i = tid; i < NPOW; i += nth) {
        int p = i ^ j;
        if (p > i) {
          int a = si[i], bb = si[p];
          bool up = ((i & k) == 0);
          bool sw = up ? (a > bb) : (a < bb);
          if (sw) { si[i] = bb; si[p] = a; }
        }
      }
      __syncthreads();
    }
  for (int i = tid; i < K; i += nth) keep[i] = si[i];
}

// pool-1 finish with inline BN (e1 fp32 never materialized): reads pre-BN H.
__global__ void pool_finish_bn_kernel(const float* __restrict__ H, const float* __restrict__ stats,
                                      const float* __restrict__ g, const float* __restrict__ b,
                                      const int* __restrict__ nb_src,
                                      const int* __restrict__ keep, int K, int Esrc,
                                      float* __restrict__ Xp, int* __restrict__ nbp)
{
  const float invE = 1.0f / (float)Esrc;
  int total = K * 64;
  for (int idx = (int)blockIdx.x * blockDim.x + threadIdx.x; idx < total;
       idx += (int)gridDim.x * blockDim.x) {
    int i = idx >> 6, c = idx & 63;
    float m = stats[c] * invE;
    float var = stats[64 + c] * invE - m * m;
    float inv = rsqrtf(var + BN_EPS_F);
    float v = H[(size_t)keep[i] * 64 + c];
    float o = (v - m) * inv * g[c] + b[c];
    Xp[idx] = fmaxf(o, 0.f);
  }
  for (int idx = (int)blockIdx.x * blockDim.x + threadIdx.x; idx < K * 4;
       idx += (int)gridDim.x * blockDim.x) {
    int i = idx >> 2, j = idx & 3;
    int v = nb_src[(size_t)keep[i] * 4 + j];
    v = iclampi(v, 0, Esrc - 1);
    int p = bsearch_eq(keep, K, v);
    nbp[idx] = (p < 0) ? i : p;
  }
}

template<int C, bool B16>
__global__ void pool_finish_kernel(const float* __restrict__ Xsrc, const int* __restrict__ nb_src,
                                   const int* __restrict__ keep, int K, int Esrc,
                                   float* __restrict__ Xp, ushort_t* __restrict__ Xpb,
                                   int* __restrict__ nbp)
{
  int total = K * C;
  for (int idx = (int)blockIdx.x * blockDim.x + threadIdx.x; idx < total;
       idx += (int)gridDim.x * blockDim.x) {
    int i = idx / C, c = idx % C;
    float v = Xsrc[(size_t)keep[i] * C + c];
    if constexpr (B16) Xpb[idx] = f2b(v);
    else Xp[idx] = v;
  }
  for (int idx = (int)blockIdx.x * blockDim.x + threadIdx.x; idx < K * 4;
       idx += (int)gridDim.x * blockDim.x) {
    int i = idx >> 2, j = idx & 3;
    int v = nb_src[(size_t)keep[i] * 4 + j];
    v = iclampi(v, 0, Esrc - 1);
    int p = bsearch_eq(keep, K, v);
    nbp[idx] = (p < 0) ? i : p;
  }
}

// unpool (nearest kept) + concat skip -> bf16, 8 cols/thread, 1 binsearch/thread
__global__ void unpool_cat_b16_kernel(const float* __restrict__ Xc, const float* __restrict__ Xs,
                                      const int* __restrict__ keep, int K, int E,
                                      int Cc, int Cs, ushort_t* __restrict__ out)
{
  int Ct = Cc + Cs;
  int Ct8 = Ct >> 3;
  int total = E * Ct8;
  for (int idx = (int)blockIdx.x * blockDim.x + threadIdx.x; idx < total;
       idx += (int)gridDim.x * blockDim.x) {
    int r = idx / Ct8, c = (idx % Ct8) << 3;
    const float* srcp;
    if (c < Cc) { int nn = nearest_keep(keep, K, r); srcp = &Xc[(size_t)nn * Cc + c]; }
    else srcp = &Xs[(size_t)r * Cs + (c - Cc)];
    float4 a = *(const float4*)srcp;
    float4 b = *(const float4*)(srcp + 4);
    ushort_t o[8];
    o[0] = f2b(a.x); o[1] = f2b(a.y); o[2] = f2b(a.z); o[3] = f2b(a.w);
    o[4] = f2b(b.x); o[5] = f2b(b.y); o[6] = f2b(b.z); o[7] = f2b(b.w);
    *(uint4*)&out[(size_t)r * Ct + c] = *(uint4*)o;
  }
}

// ---------------------------------------------------------------------------
extern "C" void kernel_launch(void* const* d_in, const int* in_sizes, int n_in,
                              void* d_out, int out_size, void* d_ws, size_t ws_size,
                              hipStream_t stream)
{
  (void)in_sizes; (void)n_in; (void)out_size; (void)ws_size;
  const float* x     = (const float*)d_in[0];
  const int*   nb    = (const int*)d_in[1];
  const float* W_e1  = (const float*)d_in[2];
  const float* g_e1  = (const float*)d_in[3];
  const float* b_e1  = (const float*)d_in[4];
  const float* W_e2  = (const float*)d_in[5];
  const float* g_e2  = (const float*)d_in[6];
  const float* b_e2  = (const float*)d_in[7];
  const float* W_e3  = (const float*)d_in[8];
  const float* g_e3  = (const float*)d_in[9];
  const float* b_e3  = (const float*)d_in[10];
  const float* W_e4  = (const float*)d_in[11];
  const float* g_e4  = (const float*)d_in[12];
  const float* b_e4  = (const float*)d_in[13];
  const float* W_d3  = (const float*)d_in[14];
  const float* g_d3  = (const float*)d_in[15];
  const float* b_d3  = (const float*)d_in[16];
  const float* W_d2  = (const float*)d_in[17];
  const float* g_d2  = (const float*)d_in[18];
  const float* b_d2  = (const float*)d_in[19];
  const float* W_d1  = (const float*)d_in[20];
  const float* g_d1  = (const float*)d_in[21];
  const float* b_d1  = (const float*)d_in[22];
  const float* W_head = (const float*)d_in[23];
  const float* bias_head = (const float*)d_in[24];
  float* out = (float*)d_out;

  char* p = (char*)d_ws;
  auto alloc = [&](size_t bytes) -> char* {
    char* q = p; p += (bytes + 255) & ~(size_t)255; return q;
  };

  // --- zero zone (one memset) ---
  char* zz = p;
  u32*   hist  = (u32*)alloc(sizeof(u32) * (1u << 20));
  float* stats = (float*)alloc(sizeof(float) * 2 * (64 + 128 + 256 + 512 + 256 + 128 + 64));
  u32*   ctrl  = (u32*)alloc(sizeof(u32) * 16);
  u64*   thr   = (u64*)alloc(sizeof(u64) * 2);
  u32*   sel   = (u32*)alloc(sizeof(u32) * 8);
  float* H2    = (float*)alloc(sizeof(float) * T1 * 128);   // split-K -> zeroed
  float* H3    = (float*)alloc(sizeof(float) * T2 * 256);   // split-K -> zeroed
  float* H4    = (float*)alloc(sizeof(float) * T3 * 512);   // split-K -> zeroed
  float* Hd3   = (float*)alloc(sizeof(float) * T2 * 256);   // split-K -> zeroed
  float* Hd2   = (float*)alloc(sizeof(float) * T1 * 128);   // split-K -> zeroed
  size_t zz_bytes = (size_t)(p - zz);
  // --- rest ---
  u32*   bcnt  = (u32*)alloc(sizeof(u32) * 256);
  float* He1   = (float*)alloc(sizeof(float) * (size_t)E0 * 64);
  u64*   keys1 = (u64*)alloc(sizeof(u64) * E0);
  u64*   cand  = (u64*)alloc(sizeof(u64) * CAND_CAP);
  int*   keep1 = (int*)alloc(sizeof(int) * T1);
  float* e1p   = (float*)alloc(sizeof(float) * T1 * 64);
  int*   nb1   = (int*)alloc(sizeof(int) * T1 * 4);
  float* e2    = (float*)alloc(sizeof(float) * T1 * 128);
  u64*   keys2 = (u64*)alloc(sizeof(u64) * T1);
  int*   keep2 = (int*)alloc(sizeof(int) * T2);
  float* e2p   = (float*)alloc(sizeof(float) * T2 * 128);
  int*   nb2   = (int*)alloc(sizeof(int) * T2 * 4);
  float* e3    = (float*)alloc(sizeof(float) * T2 * 256);
  u64*   keys3 = (u64*)alloc(sizeof(u64) * T2);
  int*   keep3 = (int*)alloc(sizeof(int) * T3);
  ushort_t* e3pb = (ushort_t*)alloc(sizeof(ushort_t) * T3 * 256);
  int*   nb3   = (int*)alloc(sizeof(int) * T3 * 4);
  float* e4    = (float*)alloc(sizeof(float) * T3 * 512);
  ushort_t* d3catb = (ushort_t*)alloc(sizeof(ushort_t) * T2 * 768);
  float* d3    = (float*)alloc(sizeof(float) * T2 * 256);
  ushort_t* d2catb = (ushort_t*)alloc(sizeof(ushort_t) * T1 * 384);
  float* d2    = (float*)alloc(sizeof(float) * T1 * 128);
  ushort_t* Hd1b = (ushort_t*)alloc(sizeof(ushort_t) * (size_t)E0 * 64);
  ushort_t* e1b = (ushort_t*)alloc(sizeof(ushort_t) * (size_t)E0 * 64);
  ushort_t* d2b = (ushort_t*)alloc(sizeof(ushort_t) * T1 * 128);
  ushort_t* Wt1 = (ushort_t*)alloc(sizeof(ushort_t) * 5 * 64 * 192);
  ushort_t* Wt4 = (ushort_t*)alloc(sizeof(ushort_t) * 5 * 512 * 256);
  ushort_t* Wtd3 = (ushort_t*)alloc(sizeof(ushort_t) * 5 * 256 * 768);
  ushort_t* Wtd2 = (ushort_t*)alloc(sizeof(ushort_t) * 5 * 128 * 384);

  float* s1  = stats;
  float* s2  = s1 + 2 * 64;
  float* s3  = s2 + 2 * 128;
  float* s4  = s3 + 2 * 256;
  float* sd3 = s4 + 2 * 512;
  float* sd2 = sd3 + 2 * 256;
  float* sd1 = sd2 + 2 * 128;

  hipMemsetAsync(zz, 0, zz_bytes, stream);
  const int PREP_TOTAL = 5 * (192 * 64 + 256 * 512 + 768 * 256 + 384 * 128);
  prep_all_kernel<<<dim3((PREP_TOTAL + 255) / 256), 256, 0, stream>>>(
      W_d1, W_e4, W_d3, W_d2, Wt1, Wt4, Wtd3, Wtd2);

  // ---- encoder 1 (fp32, pool-key-critical; e1 fp32 never materialized) ----
  e1_conv_kernel<<<dim3((E0 + 127) / 128), 256, 0, stream>>>(x, nb, W_e1, He1, s1);
  bn_kernel<64, true, false, true><<<dim3(8192), 256, 0, stream>>>(
      He1, s1, g_e1, b_e1, E0, nullptr, e1b, keys1);

  // ---- pool 1 (top-1500 of 200000) ----
  hist_kernel<<<dim3(782), 256, 0, stream>>>(keys1, E0, hist);
  scan_kernel<<<dim3(1), 1024, 0, stream>>>(hist, T1, sel);
  collect_kernel<<<dim3(782), 256, 0, stream>>>(keys1, E0, sel, cand, ctrl);
  thresh_kernel<<<dim3(1), 1024, 0, stream>>>(cand, ctrl, sel, thr);
  keep_count_kernel<<<dim3(NB_KEEP), 256, 0, stream>>>(keys1, E0, thr, bcnt);
  keep_scatter_kernel<<<dim3(NB_KEEP), 256, 0, stream>>>(keys1, E0, thr, bcnt, NB_KEEP, keep1, T1);
  pool_finish_bn_kernel<<<dim3(380), 256, 0, stream>>>(
      He1, s1, g_e1, b_e1, nb, keep1, T1, E0, e1p, nb1);

  // ---- encoder 2 (fp32 split-K=2, pool-key-critical) ----
  conv_kernel<64, 128, 32, 64, 8, 2, 4, 2, false>
      <<<dim3((T1 + 31) / 32, 128 / 64, 2), 256, 0, stream>>>(e1p, nb1, T1, W_e2, H2, nullptr);
  stats_kernel<<<dim3((T1 + 63) / 64), 256, 0, stream>>>(H2, T1, 128, s2);
  bn_kernel<128, true, true, false><<<dim3(512), 256, 0, stream>>>(
      H2, s2, g_e2, b_e2, T1, e2, nullptr, keys2);
  pool_select_kernel<2048><<<dim3(1), 1024, 0, stream>>>(keys2, T1, T2, keep2);
  pool_finish_kernel<128, false><<<dim3(380), 256, 0, stream>>>(e2, nb1, keep2, T2, T1, e2p, nullptr, nb2);

  // ---- encoder 3 (fp32 split-K=4, pool-key-critical) ----
  conv_kernel<128, 256, 32, 64, 8, 2, 4, 4, false>
      <<<dim3((T2 + 31) / 32, 256 / 64, 4), 256, 0, stream>>>(e2p, nb2, T2, W_e3, H3, nullptr);
  stats_kernel<<<dim3((T2 + 63) / 64), 256, 0, stream>>>(H3, T2, 256, s3);
  bn_kernel<256, true, true, false><<<dim3(256), 256, 0, stream>>>(
      H3, s3, g_e3, b_e3, T2, e3, nullptr, keys3);
  pool_select_kernel<1024><<<dim3(1), 1024, 0, stream>>>(keys3, T2, T3, keep3);
  pool_finish_kernel<256, true><<<dim3(380), 256, 0, stream>>>(e3, nb2, keep3, T3, T2, nullptr, e3pb, nb3);

  // ---- encoder 4 (bf16 MFMA split-K=4) ----
  mfma_conv_kernel<256, 512, 4><<<dim3((T3 + 31) / 32, 512 / 64, 4), 128, 0, stream>>>(
      e3pb, nb3, T3, Wt4, H4);
  stats_kernel<<<dim3((T3 + 63) / 64), 256, 0, stream>>>(H4, T3, 512, s4);
  bn_kernel<512, false, true, false><<<dim3(128), 256, 0, stream>>>(
      H4, s4, g_e4, b_e4, T3, e4, nullptr, nullptr);

  // ---- decoder 3 (bf16 MFMA split-K=6) ----
  unpool_cat_b16_kernel<<<dim3((T2 * 768 / 8 + 255) / 256), 256, 0, stream>>>(
      e4, e3, keep3, T3, T2, 512, 256, d3catb);
  mfma_conv_kernel<768, 256, 6><<<dim3((T2 + 31) / 32, 256 / 64, 6), 128, 0, stream>>>(
      d3catb, nb2, T2, Wtd3, Hd3);
  stats_kernel<<<dim3((T2 + 63) / 64), 256, 0, stream>>>(Hd3, T2, 256, sd3);
  bn_kernel<256, false, true, false><<<dim3(256), 256, 0, stream>>>(
      Hd3, sd3, g_d3, b_d3, T2, d3, nullptr, nullptr);

  // ---- decoder 2 (bf16 MFMA split-K=3) ----
  unpool_cat_b16_kernel<<<dim3((T1 * 384 / 8 + 255) / 256), 256, 0, stream>>>(
      d3, e2, keep2, T2, T1, 256, 128, d2catb);
  mfma_conv_kernel<384, 128, 3><<<dim3((T1 + 31) / 32, 128 / 64, 3), 128, 0, stream>>>(
      d2catb, nb1, T1, Wtd2, Hd2);
  stats_kernel<<<dim3((T1 + 63) / 64), 256, 0, stream>>>(Hd2, T1, 128, sd2);
  bn_kernel<128, false, true, true><<<dim3(512), 256, 0, stream>>>(
      Hd2, sd2, g_d2, b_d2, T1, d2, d2b, nullptr);

  // ---- decoder 1 (bf16 MFMA col-split; keep1 in LDS; bf16 out) ----
  d1_mfma_kernel<<<dim3((E0 + 127) / 128), 256, 0, stream>>>(d2b, e1b, keep1, nb, Wt1, Hd1b, sd1);

  // ---- head (fused BN+ReLU+matmul, bf16 in) ----
  head_kernel<<<dim3(8192), 256, 0, stream>>>(Hd1b, sd1, g_d1, b_d1, W_head, bias_head, E0, out);
}